// Round 6
// baseline (461.220 us; speedup 1.0000x reference)
//
#include <hip/hip_runtime.h>
#include <hip/hip_bf16.h>
#include <math.h>

#define CDIM 512
#define LV 196
#define BV 64
#define BT 32
#define NW 24
#define NKEEP 98
#define NNON 98      // LV - NKEEP
#define KEEPED 49
#define HID 102
#define LAMBDA_ 4.0f
#define LN_EPS_ 1e-5f

// ws layout (float offsets)
#define WS_CAPNORM 0
#define WS_CAPGLO  (WS_CAPNORM + BT*NW*CDIM)     // 393216
#define WS_IMGGLO  (WS_CAPGLO + BT*CDIM)         // +16384
#define WS_INVN    (WS_IMGGLO + BV*CDIM)         // +32768
#define WS_WLOG    (WS_INVN + BV*LV)             // +12544
#define WS_SCORE   (WS_WLOG + BV*LV*KEEPED)      // +614656
#define WS_END     (WS_SCORE + BT*BV*LV)         // 1470976 floats = 5.88 MB
// imgT (big path only): bf16 [64][512][224] appended after WS_END
#define WS_IMGT_B  ((size_t)WS_END * 4)          // byte offset 5883904
#define TOKPAD 224
#define WS_NEED_B  (WS_IMGT_B + (size_t)BV * CDIM * TOKPAD * 2)   // 20563968 B
// W1T/W2T (bf16) live in the WS_SCORE region: written by k5_prep, read by k2,
// then SCORE is overwritten by k3 (stream-ordered). 129 KB << 1.6 MB region.
#define WS_W1T_B   ((size_t)WS_SCORE * 4)
#define WS_W2T_B   (WS_W1T_B + (size_t)112 * 512 * 2)

typedef short v8s __attribute__((ext_vector_type(8)));   // 8 bf16 (4 VGPR)
typedef float v4f __attribute__((ext_vector_type(4)));
#define MFMA16(a, b, c) __builtin_amdgcn_mfma_f32_16x16x32_bf16((a), (b), (c), 0, 0, 0)

// LDS strides (elements), padded for bank behavior + alignment:
#define WA_STR 232    // A matrix rows (464 B, 16-aligned, 2-way banks)
#define TOK_STR 40    // token K-tile rows (80 B, 16-aligned)
#define SEL_STR 520   // sel rows (1040 B, 16-aligned, 2-way banks) [fallback k4]
#define G_STR 66      // Gram rows (f32)
#define XN_STR 520    // k2 xn rows (bf16)
#define HB_STR 136    // k2 hbuf rows (bf16; 136=2-way banks, not pow2)

// k4_big LDS plan (R13, total 54272 B -> 3 blk/CU if regs allow):
// R2 [0, 19216): s_w fp32 19208 (P3->P4) THEN sel quarter bf16 [64][136]=17408
// R1 [19216, 48912): s_wa [64][232]=29696 (P4 -> end of quarter loop);
//   rows 50..63 (from 42416) overlaid by capq during the loop (P5 reads of
//   rows 50..63 then see finite bf16 garbage -> sel rows 50..63 garbage,
//   consumed only by dead outputs: sims cols>=50 zeroed in P8, G rows/cols
//   >=50 multiplied by ev=0 in P10).
// capq [32][136]=8704 at 42416..51120 (rows 24..31 zero-filled once ->
//   sims rows 24..31 = 0, never read).
// After loop: sims f32 [32][64]=8192 @19216 + G f32 [64][66]=16896 @27408
//   (overlay s_wa+capq, both dead).
// Registers: P5 fused per-quarter (acc[4]=16f32) + sa(4) + ga(8) ~= 28 accum
// regs vs 64 before -> (512,6) budget (~84) fits WITHOUT spill -> 3 blk/CU.
// r5 evidence: 64 VGPR + 64 AGPR = 128 unified regs was the 2-block limiter.
#define SELQ_STR 136  // 272 B rows
#define CAPQ_STR 136
#define K4_SMEM   54272
#define OFF_SEL   0
#define OFF_WA    19216
#define OFF_CAPQ  42416    // = OFF_WA + 50*464
#define OFF_SIMS  19216
#define OFF_G     27408    // ends 44304
#define OFF_SC    51120
#define OFF_KIDX  51904
#define OFF_NIDX  52296
#define OFF_CNT   52688
#define OFF_WK    52696
#define OFF_RED   53088
#define OFF_POOL2 53600
#define OFF_INV   53856    // ends 54112

__device__ __forceinline__ ushort bfb(float f) {
  __hip_bfloat16 h = __float2bfloat16(f);
  union { __hip_bfloat16 h; ushort u; } cv; cv.h = h; return cv.u;
}

// ---------------------------------------------------------------------------
// K0 (big path only): imgT[v][c][tok] bf16, tok padded 196->224 with zeros.
// ---------------------------------------------------------------------------
__global__ __launch_bounds__(512) void k0_prep(const float* __restrict__ img,
                                               float* __restrict__ ws) {
  int v = blockIdx.x, kt = blockIdx.y, c = threadIdx.x;
  float x[32];
  #pragma unroll
  for (int kk = 0; kk < 32; ++kk) {
    int tok = kt * 32 + kk;
    x[kk] = (tok < LV) ? img[((size_t)v * LV + tok) * CDIM + c] : 0.f;
  }
  __hip_bfloat16* imgT = (__hip_bfloat16*)((char*)ws + WS_IMGT_B);
  uint* dst = (uint*)(imgT + ((size_t)v * CDIM + c) * TOKPAD + kt * 32);
  #pragma unroll
  for (int g = 0; g < 4; ++g) {
    uint4 u;
    u.x = (uint)bfb(x[g*8+0]) | ((uint)bfb(x[g*8+1]) << 16);
    u.y = (uint)bfb(x[g*8+2]) | ((uint)bfb(x[g*8+3]) << 16);
    u.z = (uint)bfb(x[g*8+4]) | ((uint)bfb(x[g*8+5]) << 16);
    u.w = (uint)bfb(x[g*8+6]) | ((uint)bfb(x[g*8+7]) << 16);
    *(uint4*)(dst + g * 4) = u;
  }
}

// ---------------------------------------------------------------------------
// K5: transpose W1 -> W1T bf16 [112 h][512 k], W2 -> W2T bf16 [64 p][128 h]
// ---------------------------------------------------------------------------
__global__ __launch_bounds__(512) void k5_prep(const float* __restrict__ W1,
                                               const float* __restrict__ W2,
                                               float* __restrict__ ws) {
  int b = blockIdx.x, tid = threadIdx.x;
  if (b < 112) {
    int h = b;
    float val = (h < HID) ? W1[(size_t)tid * HID + h] : 0.f;
    ((ushort*)((char*)ws + WS_W1T_B))[(size_t)h * 512 + tid] = bfb(val);
  } else {
    int p = b - 112;
    if (tid < 128) {
      int h = tid;
      float val = (p < KEEPED && h < HID) ? W2[(size_t)h * KEEPED + p] : 0.f;
      ((ushort*)((char*)ws + WS_W2T_B))[(size_t)p * 128 + h] = bfb(val);
    }
  }
}

// ---------------------------------------------------------------------------
// K1: cap_norm + cap_glo (blocks 0..31), img_glo (blocks 32..95). 256 thr.
// ---------------------------------------------------------------------------
__global__ __launch_bounds__(256) void k1_glo(const float* __restrict__ img,
                                              const float* __restrict__ cap,
                                              float* __restrict__ ws) {
  __shared__ float red[256];
  __shared__ float s_part[4 * CDIM];   // per-wave raw-sum partials
  __shared__ float s_glo[CDIM];
  int b = blockIdx.x, tid = threadIdx.x;
  if (b < BT) {
    int t = b;
    int wv = tid >> 6, lane = tid & 63;
    int cb = lane * 8;
    float4 sA = make_float4(0.f,0.f,0.f,0.f), sB = make_float4(0.f,0.f,0.f,0.f);
    for (int w = wv; w < NW; w += 4) {
      const float* p = cap + ((size_t)t * NW + w) * CDIM + cb;
      float4 xa = *(const float4*)p;
      float4 xb = *(const float4*)(p + 4);
      float ss = xa.x*xa.x + xa.y*xa.y + xa.z*xa.z + xa.w*xa.w
               + xb.x*xb.x + xb.y*xb.y + xb.z*xb.z + xb.w*xb.w;
      #pragma unroll
      for (int off = 32; off > 0; off >>= 1) ss += __shfl_xor(ss, off, 64);
      float inv = 1.f / fmaxf(sqrtf(ss), 1e-12f);
      float* q = ws + WS_CAPNORM + ((size_t)t * NW + w) * CDIM + cb;
      *(float4*)q       = make_float4(xa.x*inv, xa.y*inv, xa.z*inv, xa.w*inv);
      *(float4*)(q + 4) = make_float4(xb.x*inv, xb.y*inv, xb.z*inv, xb.w*inv);
      sA.x += xa.x; sA.y += xa.y; sA.z += xa.z; sA.w += xa.w;
      sB.x += xb.x; sB.y += xb.y; sB.z += xb.z; sB.w += xb.w;
    }
    *(float4*)&s_part[wv * CDIM + cb]     = sA;
    *(float4*)&s_part[wv * CDIM + cb + 4] = sB;
    __syncthreads();
    if (tid < 128) {
      float4 g = make_float4(0.f, 0.f, 0.f, 0.f);
      #pragma unroll
      for (int w2 = 0; w2 < 4; ++w2) {
        float4 pv = *(const float4*)&s_part[w2 * CDIM + tid * 4];
        g.x += pv.x; g.y += pv.y; g.z += pv.z; g.w += pv.w;
      }
      g.x /= (float)NW; g.y /= (float)NW; g.z /= (float)NW; g.w /= (float)NW;
      *(float4*)&s_glo[tid * 4] = g;
      red[tid] = g.x*g.x + g.y*g.y + g.z*g.z + g.w*g.w;
    }
    __syncthreads();
    for (int off = 64; off > 0; off >>= 1) {
      if (tid < off) red[tid] += red[tid + off];
      __syncthreads();
    }
    float inv = 1.f / fmaxf(sqrtf(red[0]), 1e-12f);
    if (tid < 128) {
      float4 g = *(const float4*)&s_glo[tid * 4];
      *(float4*)(ws + WS_CAPGLO + (size_t)t * CDIM + tid * 4) =
          make_float4(g.x*inv, g.y*inv, g.z*inv, g.w*inv);
    }
  } else {
    int c0 = tid, c1 = tid + 256;
    int v = b - BT;
    float s0 = 0.f, s1 = 0.f;
    const float* base = img + (size_t)v * LV * CDIM;
    for (int l = 0; l < LV; ++l) { s0 += base[l * CDIM + c0]; s1 += base[l * CDIM + c1]; }
    float g0 = s0 / (float)LV, g1 = s1 / (float)LV;
    red[tid] = g0 * g0 + g1 * g1;
    __syncthreads();
    for (int off = 128; off > 0; off >>= 1) {
      if (tid < off) red[tid] += red[tid + off];
      __syncthreads();
    }
    float inv = 1.f / fmaxf(sqrtf(red[0]), 1e-12f);
    float* q = ws + WS_IMGGLO + (size_t)v * CDIM;
    q[c0] = g0 * inv; q[c1] = g1 * inv;
  }
}

// ---------------------------------------------------------------------------
// K2: MFMA MLP. grid (64 v, 7 segs of 28 tokens), 512 thr (8 waves).
// LDS [32][520] bf16 = 33,280 B -> full-GPU grid + multi-block/CU.
// ---------------------------------------------------------------------------
__global__ __launch_bounds__(512, 4) void k2_mlp(const float* __restrict__ img,
                                                 const float* __restrict__ gamma,
                                                 const float* __restrict__ beta,
                                                 const float* __restrict__ b1,
                                                 const float* __restrict__ b2,
                                                 float* __restrict__ ws) {
  __shared__ __align__(16) __hip_bfloat16 s_xn[32 * XN_STR];  // 33,280 B
  __hip_bfloat16* s_hb = s_xn;                                // overlay after GEMM1

  int v = blockIdx.x, seg = blockIdx.y;
  int l0 = seg * 28;
  int tid = threadIdx.x, wv = tid >> 6, lane = tid & 63;
  int quad = lane >> 4, l15 = lane & 15, koff = quad * 8;
  const __hip_bfloat16* W1T = (const __hip_bfloat16*)((const char*)ws + WS_W1T_B);
  const __hip_bfloat16* W2T = (const __hip_bfloat16*)((const char*)ws + WS_W2T_B);

  // ---- Phase A: LN -> xn bf16 (28 tokens) ----
  int cb = lane * 8;
  float4 g4a = *(const float4*)(gamma + cb);
  float4 g4b = *(const float4*)(gamma + cb + 4);
  float4 b4a = *(const float4*)(beta + cb);
  float4 b4b = *(const float4*)(beta + cb + 4);
  for (int tok = wv; tok < 28; tok += 8) {
    const float* p = img + ((size_t)v * LV + l0 + tok) * CDIM + cb;
    float4 xa = *(const float4*)p;
    float4 xb = *(const float4*)(p + 4);
    float s  = xa.x + xa.y + xa.z + xa.w + xb.x + xb.y + xb.z + xb.w;
    float sq = xa.x*xa.x + xa.y*xa.y + xa.z*xa.z + xa.w*xa.w
             + xb.x*xb.x + xb.y*xb.y + xb.z*xb.z + xb.w*xb.w;
    #pragma unroll
    for (int off = 32; off > 0; off >>= 1) { s += __shfl_xor(s, off, 64); sq += __shfl_xor(sq, off, 64); }
    float mean = s / (float)CDIM;
    float var = sq / (float)CDIM - mean * mean;
    float rstd = 1.f / sqrtf(var + LN_EPS_);
    if (lane == 0) ws[WS_INVN + (size_t)v * LV + l0 + tok] = 1.f / fmaxf(sqrtf(sq), 1e-12f);
    float f[8];
    f[0] = (xa.x - mean) * rstd * g4a.x + b4a.x;
    f[1] = (xa.y - mean) * rstd * g4a.y + b4a.y;
    f[2] = (xa.z - mean) * rstd * g4a.z + b4a.z;
    f[3] = (xa.w - mean) * rstd * g4a.w + b4a.w;
    f[4] = (xb.x - mean) * rstd * g4b.x + b4b.x;
    f[5] = (xb.y - mean) * rstd * g4b.y + b4b.y;
    f[6] = (xb.z - mean) * rstd * g4b.z + b4b.z;
    f[7] = (xb.w - mean) * rstd * g4b.w + b4b.w;
    uint4 u;
    u.x = (uint)bfb(f[0]) | ((uint)bfb(f[1]) << 16);
    u.y = (uint)bfb(f[2]) | ((uint)bfb(f[3]) << 16);
    u.z = (uint)bfb(f[4]) | ((uint)bfb(f[5]) << 16);
    u.w = (uint)bfb(f[6]) | ((uint)bfb(f[7]) << 16);
    *(uint4*)(s_xn + (size_t)tok * XN_STR + cb) = u;
  }
  __syncthreads();

  // ---- GEMM1: C[32 tok][112 h], 2x7 = 14 tiles over 8 waves ----
  v4f c1[2];
  int mt_[2], nt_[2];
  #pragma unroll
  for (int i = 0; i < 2; ++i) {
    int idx = wv + 8 * i; if (idx > 13) idx = 13;   // clamp: keep reads in-bounds
    mt_[i] = idx / 7; nt_[i] = idx % 7;
    c1[i] = (v4f){0.f, 0.f, 0.f, 0.f};
  }
  for (int ks = 0; ks < 16; ++ks) {
    #pragma unroll
    for (int i = 0; i < 2; ++i) {
      v8s a  = *(const v8s*)(s_xn + (size_t)(mt_[i] * 16 + l15) * XN_STR + ks * 32 + koff);
      v8s bb = *(const v8s*)(W1T + (size_t)(nt_[i] * 16 + l15) * 512 + ks * 32 + koff);
      c1[i] = MFMA16(a, bb, c1[i]);
    }
  }
  __syncthreads();   // all xn reads complete before hbuf overlay

  // ---- gelu + bias -> hbuf [32][136] ----
  #pragma unroll
  for (int i = 0; i < 2; ++i) {
    int idx = wv + 8 * i;
    if (idx < 14) {
      int h = nt_[i] * 16 + l15;
      float bias = (h < HID) ? b1[h] : 0.f;
      #pragma unroll
      for (int reg = 0; reg < 4; ++reg) {
        int row = mt_[i] * 16 + quad * 4 + reg;
        float x = c1[i][reg] + bias;
        float gl = (h < HID) ? 0.5f * x * (1.f + erff(x * 0.70710678118654752f)) : 0.f;
        s_hb[(size_t)row * HB_STR + h] = __float2bfloat16(gl);
      }
    }
  }
  for (int i = tid; i < 32 * 16; i += 512)   // zero cols 112..127 (K pad)
    s_hb[(size_t)(i >> 4) * HB_STR + 112 + (i & 15)] = __float2bfloat16(0.f);
  __syncthreads();

  // ---- GEMM2: C[32 tok][64 p], 2x4 = 8 tiles = 1/wave, K=128 ----
  int m2 = wv >> 2, n2 = wv & 3;
  v4f c2 = (v4f){0.f, 0.f, 0.f, 0.f};
  for (int ks = 0; ks < 4; ++ks) {
    v8s a  = *(const v8s*)(s_hb + (size_t)(m2 * 16 + l15) * HB_STR + ks * 32 + koff);
    v8s bb = *(const v8s*)(W2T + (size_t)(n2 * 16 + l15) * 128 + ks * 32 + koff);
    c2 = MFMA16(a, bb, c2);
  }
  {
    int p = n2 * 16 + l15;
    if (p < KEEPED) {
      float bias = b2[p];
      #pragma unroll
      for (int reg = 0; reg < 4; ++reg) {
        int tok = m2 * 16 + quad * 4 + reg;
        if (tok < 28)
          ws[WS_WLOG + ((size_t)v * LV + l0 + tok) * KEEPED + p] = c2[reg] + bias;
      }
    }
  }
}

// ---------------------------------------------------------------------------
// K3: scores. (verbatim)
// ---------------------------------------------------------------------------
__global__ __launch_bounds__(256) void k3_score(const float* __restrict__ img,
                                                float* __restrict__ ws) {
  __shared__ float qt[33 * 64];
  __shared__ float xt[64 * 65];
  __shared__ float dself[64];
  int v = blockIdx.x;
  int t0 = blockIdx.y * 64;
  int tid = threadIdx.x;
  int tloc = tid & 63, qg = tid >> 6;
  float acc[9];
  #pragma unroll
  for (int i = 0; i < 9; ++i) acc[i] = 0.f;
  const float* capglo = ws + WS_CAPGLO;
  const float* imgglo = ws + WS_IMGGLO + (size_t)v * CDIM;

  for (int ct = 0; ct < 8; ++ct) {
    for (int i = tid; i < 33 * 64; i += 256) {
      int q = i >> 6, cc = i & 63;
      qt[i] = (q < 32) ? capglo[(size_t)q * CDIM + ct * 64 + cc] : imgglo[ct * 64 + cc];
    }
    for (int i = tid; i < 64 * 64; i += 256) {
      int tok = i >> 6, cc = i & 63;
      int l = t0 + tok;
      xt[tok * 65 + cc] = (l < LV) ? img[((size_t)v * LV + l) * CDIM + ct * 64 + cc] : 0.f;
    }
    __syncthreads();
    for (int cc = 0; cc < 64; ++cc) {
      float xv = xt[tloc * 65 + cc];
      #pragma unroll
      for (int qi = 0; qi < 9; ++qi) {
        int q = qg + 4 * qi;
        if (q < 33) acc[qi] += qt[q * 64 + cc] * xv;
      }
    }
    __syncthreads();
  }
  if (qg == 0) dself[tloc] = acc[8];
  __syncthreads();
  int l = t0 + tloc;
  if (l < LV) {
    float invn = ws[WS_INVN + (size_t)v * LV + l];
    float ds = dself[tloc];
    #pragma unroll
    for (int qi = 0; qi < 9; ++qi) {
      int q = qg + 4 * qi;
      if (q < 32) ws[WS_SCORE + ((size_t)q * BV + v) * LV + l] = (acc[qi] + ds) * invn;
    }
  }
}

// ---------------------------------------------------------------------------
// K4 fallback (small ws): verbatim old template, only <0> instantiated.
// ---------------------------------------------------------------------------
template<int USE_IMGT>
__global__ __launch_bounds__(512, 2) void k4_main(const float* __restrict__ img,
                                                  const float* __restrict__ scale_p,
                                                  const float* __restrict__ ws,
                                                  float* __restrict__ out) {
  __shared__ float s_sc[LV];
  __shared__ int   s_kidx[NKEEP];
  __shared__ int   s_nidx[NNON];
  __shared__ int   s_cnt[2];
  __shared__ float s_wk[NNON];
  __shared__ float s_red[128];
  __shared__ float s_pool2[64];
  __shared__ float s_inv[64];
  __shared__ __align__(16) __hip_bfloat16 s_selh[64 * SEL_STR];
  __shared__ __align__(16) __hip_bfloat16 s_wa[64 * WA_STR];
  __shared__ __align__(16) __hip_bfloat16 s_dyn[512 * TOK_STR];

  float* s_w = (float*)s_dyn;
  __hip_bfloat16* s_tok = s_dyn;
  __hip_bfloat16* s_cap = s_dyn;
  float* s_sims = (float*)s_wa;
  float* s_G = (float*)((char*)s_wa + 8192);

  int b = blockIdx.x;
  int v = b >> 5, t = b & 31;
  int tid = threadIdx.x;
  int wv = tid >> 6, lane = tid & 63;
  int quad = lane >> 4, l15 = lane & 15;
  int koff = quad * 8;

  if (tid < 2) s_cnt[tid] = 0;
  if (tid < 64) s_pool2[tid] = 0.f;
  if (tid < LV) s_sc[tid] = ws[WS_SCORE + ((size_t)t * BV + v) * LV + tid];
  {
    uint* za = (uint*)s_wa;
    for (int i = tid; i < 64 * WA_STR / 2; i += 512) za[i] = 0u;
    uint* zs = (uint*)(s_selh + 50 * SEL_STR);
    for (int i = tid; i < 14 * SEL_STR / 2; i += 512) zs[i] = 0u;
  }
  __syncthreads();

  if (tid < LV) {
    float my = s_sc[tid];
    int cnt = 0;
    for (int j = 0; j < LV; ++j) {
      float sj = s_sc[j];
      cnt += (sj > my) || (sj == my && j < tid);
    }
    bool keep = cnt < NKEEP;
    out[BV * BT + ((size_t)t * BV + v) * LV + tid] = keep ? 1.f : 0.f;
    if (keep) { int p = atomicAdd(&s_cnt[0], 1); s_kidx[p] = tid; }
    else      { int p = atomicAdd(&s_cnt[1], 1); s_nidx[p] = tid; }
  }
  __syncthreads();

  if (tid < 128) s_red[tid] = (tid < NNON) ? s_sc[s_nidx[tid]] : -3.0e38f;
  __syncthreads();
  for (int off = 64; off > 0; off >>= 1) {
    if (tid < off) s_red[tid] = fmaxf(s_red[tid], s_red[tid + off]);
    __syncthreads();
  }
  float nm = s_red[0];
  __syncthreads();
  float e0 = 0.f;
  if (tid < NNON) e0 = expf(s_sc[s_nidx[tid]] - nm);
  if (tid < 128) s_red[tid] = (tid < NNON) ? e0 : 0.f;
  __syncthreads();
  for (int off = 64; off > 0; off >>= 1) {
    if (tid < off) s_red[tid] += s_red[tid + off];
    __syncthreads();
  }
  float nS = s_red[0];
  __syncthreads();
  if (tid < NNON) s_wk[tid] = e0 / nS;
  __syncthreads();

  float scale_val = scale_p[0];
  for (int i = tid; i < KEEPED * NKEEP; i += 512) {
    int k = i / KEEPED, p = i - k * KEEPED;
    s_w[p * NKEEP + k] = ws[WS_WLOG + ((size_t)v * LV + s_kidx[k]) * KEEPED + p] * scale_val;
  }
  __syncthreads();
  if (tid < KEEPED * 8) {
    int p = tid >> 3, g = tid & 7;
    float mm = -3e38f;
    for (int k = g; k < NKEEP; k += 8) mm = fmaxf(mm, s_w[p * NKEEP + k]);
    #pragma unroll
    for (int off = 4; off > 0; off >>= 1) mm = fmaxf(mm, __shfl_xor(mm, off, 8));
    float ss = 0.f;
    for (int k = g; k < NKEEP; k += 8) {
      float ee = expf(s_w[p * NKEEP + k] - mm);
      s_w[p * NKEEP + k] = ee;
      ss += ee;
    }
    #pragma unroll
    for (int off = 4; off > 0; off >>= 1) ss += __shfl_xor(ss, off, 8);
    float rs = 1.f / ss;
    for (int k = g; k < NKEEP; k += 8) s_w[p * NKEEP + k] *= rs;
  }
  __syncthreads();

  for (int i = tid; i < KEEPED * NKEEP; i += 512) {
    int p = i / NKEEP, r = i - p * NKEEP;
    s_wa[p * WA_STR + s_kidx[r]] = __float2bfloat16(s_w[p * NKEEP + r]);
  }
  if (tid < NNON) s_wa[49 * WA_STR + s_nidx[tid]] = __float2bfloat16(s_wk[tid]);
  __syncthreads();

  v4f acc[4][4];
  #pragma unroll
  for (int m = 0; m < 4; ++m)
    #pragma unroll
    for (int j = 0; j < 4; ++j) acc[m][j] = (v4f){0.f, 0.f, 0.f, 0.f};

  if (USE_IMGT) {
    const __hip_bfloat16* imgTv =
        (const __hip_bfloat16*)((const char*)ws + WS_IMGT_B) + (size_t)v * CDIM * TOKPAD;
    for (int ks = 0; ks < 7; ++ks) {
      v8s bfr[4];
      #pragma unroll
      for (int j = 0; j < 4; ++j)
        bfr[j] = *(const v8s*)(imgTv + (size_t)(wv * 64 + j * 16 + l15) * TOKPAD + ks * 32 + koff);
      #pragma unroll
      for (int m = 0; m < 4; ++m) {
        v8s af = *(const v8s*)(s_wa + (m * 16 + l15) * WA_STR + ks * 32 + koff);
        #pragma unroll
        for (int j = 0; j < 4; ++j) acc[m][j] = MFMA16(af, bfr[j], acc[m][j]);
      }
    }
  } else {
    for (int ks = 0; ks < 7; ++ks) {
      #pragma unroll
      for (int it = 0; it < 8; ++it) {
        int k0 = ks * 32 + it * 4;
        if (k0 < LV) {
          const float* gp = img + ((size_t)v * LV + k0) * CDIM + tid;
          float x0 = gp[0], x1 = gp[CDIM], x2 = gp[2 * CDIM], x3 = gp[3 * CDIM];
          union { __hip_bfloat16 h[4]; uint2 u; } pk;
          pk.h[0] = __float2bfloat16(x0); pk.h[1] = __float2bfloat16(x1);
          pk.h[2] = __float2bfloat16(x2); pk.h[3] = __float2bfloat16(x3);
          *(uint2*)(s_tok + tid * TOK_STR + it * 4) = pk.u;
        }
      }
      __syncthreads();
      v8s bfr[4];
      #pragma unroll
      for (int j = 0; j < 4; ++j)
        bfr[j] = *(const v8s*)(s_tok + (wv * 64 + j * 16 + l15) * TOK_STR + koff);
      #pragma unroll
      for (int m = 0; m < 4; ++m) {
        v8s af = *(const v8s*)(s_wa + (m * 16 + l15) * WA_STR + ks * 32 + koff);
        #pragma unroll
        for (int j = 0; j < 4; ++j) acc[m][j] = MFMA16(af, bfr[j], acc[m][j]);
      }
      __syncthreads();
    }
  }

  if (!USE_IMGT) __syncthreads();
  for (int i = tid; i < NW * 128; i += 512) {
    int w = i >> 7, cq = i & 127;
    const float4 xv = *(const float4*)(ws + WS_CAPNORM + ((size_t)t * NW + w) * CDIM + cq * 4);
    union { __hip_bfloat16 h[4]; uint2 u; } pk;
    pk.h[0] = __float2bfloat16(xv.x); pk.h[1] = __float2bfloat16(xv.y);
    pk.h[2] = __float2bfloat16(xv.z); pk.h[3] = __float2bfloat16(xv.w);
    *(uint2*)(s_cap + w * SEL_STR + cq * 4) = pk.u;
  }
  {
    uint* zc = (uint*)(s_cap + 24 * SEL_STR);
    for (int i = tid; i < 8 * SEL_STR / 2; i += 512) zc[i] = 0u;
  }
  #pragma unroll
  for (int m = 0; m < 4; ++m) {
    #pragma unroll
    for (int reg = 0; reg < 4; ++reg) {
      float ss = acc[m][0][reg] * acc[m][0][reg] + acc[m][1][reg] * acc[m][1][reg]
               + acc[m][2][reg] * acc[m][2][reg] + acc[m][3][reg] * acc[m][3][reg];
      #pragma unroll
      for (int off = 8; off > 0; off >>= 1) ss += __shfl_xor(ss, off, 64);
      if (l15 == 0) atomicAdd(&s_pool2[m * 16 + quad * 4 + reg], ss);
    }
  }
  __syncthreads();
  if (tid < 64) s_inv[tid] = 1.f / fmaxf(sqrtf(s_pool2[tid]), 1e-12f);
  __syncthreads();
  #pragma unroll
  for (int m = 0; m < 4; ++m) {
    #pragma unroll
    for (int reg = 0; reg < 4; ++reg) {
      int p = m * 16 + quad * 4 + reg;
      if (p < 50) {
        float iv = s_inv[p];
        #pragma unroll
        for (int j = 0; j < 4; ++j)
          s_selh[p * SEL_STR + wv * 64 + j * 16 + l15] = __float2bfloat16(acc[m][j][reg] * iv);
      }
    }
  }
  __syncthreads();

  {
    int mt = wv >> 2, nt = wv & 3;
    v4f sa = (v4f){0.f, 0.f, 0.f, 0.f};
    for (int ks = 0; ks < 16; ++ks) {
      v8s a = *(const v8s*)(s_cap + (mt * 16 + l15) * SEL_STR + ks * 32 + koff);
      v8s bb = *(const v8s*)(s_selh + (nt * 16 + l15) * SEL_STR + ks * 32 + koff);
      sa = MFMA16(a, bb, sa);
    }
    #pragma unroll
    for (int reg = 0; reg < 4; ++reg)
      s_sims[(mt * 16 + quad * 4 + reg) * 64 + nt * 16 + l15] = sa[reg];
  }
  __syncthreads();

  if (tid < NW * 8) {
    int w = tid >> 3, g = tid & 7;
    float* row = s_sims + w * 64;
    float mm = -3e38f;
    for (int p = g; p < 50; p += 8) mm = fmaxf(mm, row[p]);
    #pragma unroll
    for (int off = 4; off > 0; off >>= 1) mm = fmaxf(mm, __shfl_xor(mm, off, 8));
    float num = 0.f;
    for (int p = g; p < 64; p += 8) {
      if (p < 50) {
        float s = row[p];
        float ee = expf(LAMBDA_ * (s - mm));
        num += ee * s;
        row[p] = ee;
      } else row[p] = 0.f;
    }
    #pragma unroll
    for (int off = 4; off > 0; off >>= 1) num += __shfl_xor(num, off, 8);
    if (g == 0) s_red[w] = num;
  }
  __syncthreads();

  #pragma unroll
  for (int i2 = 0; i2 < 2; ++i2) {
    int idx = wv * 2 + i2;
    int gm = idx >> 2, gn = idx & 3;
    v4f ga = (v4f){0.f, 0.f, 0.f, 0.f};
    for (int ks = 0; ks < 16; ++ks) {
      v8s a = *(const v8s*)(s_selh + (gm * 16 + l15) * SEL_STR + ks * 32 + koff);
      v8s bb = *(const v8s*)(s_selh + (gn * 16 + l15) * SEL_STR + ks * 32 + koff);
      ga = MFMA16(a, bb, ga);
    }
    #pragma unroll
    for (int reg = 0; reg < 4; ++reg)
      s_G[(gm * 16 + quad * 4 + reg) * G_STR + gn * 16 + l15] = ga[reg];
  }
  __syncthreads();

  float wacc = 0.f;
  for (int w = wv; w < NW; w += 8) {
    const float* ev = s_sims + w * 64;
    float tl = 0.f;
    for (int q = 0; q < 50; ++q) tl += s_G[q * G_STR + lane] * ev[q];
    float ql = ev[lane] * tl;
    #pragma unroll
    for (int off = 32; off > 0; off >>= 1) ql += __shfl_xor(ql, off, 64);
    if (lane == 0) wacc += s_red[w] / fmaxf(sqrtf(ql), 1e-20f);
  }
  if (lane == 0) s_red[64 + wv] = wacc;
  __syncthreads();
  if (tid == 0) {
    float s = 0.f;
    #pragma unroll
    for (int i = 0; i < 8; ++i) s += s_red[64 + i];
    out[(size_t)v * BT + t] = s / (float)NW;
  }
}

// ---------------------------------------------------------------------------
// K4 big path (R13): P5 fused into the quarter loop -> accumulator state
// 64 -> 28 regs; deferred l2-normalization (scale sims by iv[col], G by
// iv[row]*iv[col] after the loop). (512,6) now fits without spill -> 3 blk/CU.
// ---------------------------------------------------------------------------
__global__ __launch_bounds__(512, 6) void k4_big(const float* __restrict__ img,
                                                 const float* __restrict__ scale_p,
                                                 const float* __restrict__ ws,
                                                 float* __restrict__ out) {
  __shared__ __align__(16) char smem[K4_SMEM];
  __hip_bfloat16* s_sel = (__hip_bfloat16*)(smem + OFF_SEL);   // [64][136] quarter
  float*          s_w   = (float*)(smem + OFF_SEL);            // overlay, P3/P4 only
  __hip_bfloat16* s_wa  = (__hip_bfloat16*)(smem + OFF_WA);    // [64][232]
  __hip_bfloat16* s_capq= (__hip_bfloat16*)(smem + OFF_CAPQ);  // [32][136] loop only
  float*          s_sims= (float*)(smem + OFF_SIMS);           // [32][64] after loop
  float*          s_G   = (float*)(smem + OFF_G);              // [64][66] after loop
  float* s_sc    = (float*)(smem + OFF_SC);
  int*   s_kidx  = (int*)(smem + OFF_KIDX);
  int*   s_nidx  = (int*)(smem + OFF_NIDX);
  int*   s_cnt   = (int*)(smem + OFF_CNT);
  float* s_wk    = (float*)(smem + OFF_WK);
  float* s_red   = (float*)(smem + OFF_RED);
  float* s_pool2 = (float*)(smem + OFF_POOL2);
  float* s_inv   = (float*)(smem + OFF_INV);

  int b = blockIdx.x;
  int v = b >> 5, t = b & 31;
  int tid = threadIdx.x;
  int wv = tid >> 6, lane = tid & 63;
  int quad = lane >> 4, l15 = lane & 15;
  int koff = quad * 8;

  // ---- P0: loads + zero-init ----
  if (tid < 2) s_cnt[tid] = 0;
  if (tid < 64) s_pool2[tid] = 0.f;
  if (tid < LV) s_sc[tid] = ws[WS_SCORE + ((size_t)t * BV + v) * LV + tid];
  {
    uint* za = (uint*)s_wa;
    for (int i = tid; i < 64 * WA_STR / 2; i += 512) za[i] = 0u;
  }
  __syncthreads();

  // ---- P1: rank & partition ----
  if (tid < LV) {
    float my = s_sc[tid];
    int cnt = 0;
    for (int j = 0; j < LV; ++j) {
      float sj = s_sc[j];
      cnt += (sj > my) || (sj == my && j < tid);
    }
    bool keep = cnt < NKEEP;
    out[BV * BT + ((size_t)t * BV + v) * LV + tid] = keep ? 1.f : 0.f;
    if (keep) { int p = atomicAdd(&s_cnt[0], 1); s_kidx[p] = tid; }
    else      { int p = atomicAdd(&s_cnt[1], 1); s_nidx[p] = tid; }
  }
  __syncthreads();

  // ---- P2: softmax over non-kept scores -> s_wk ----
  if (tid < 128) s_red[tid] = (tid < NNON) ? s_sc[s_nidx[tid]] : -3.0e38f;
  __syncthreads();
  for (int off = 64; off > 0; off >>= 1) {
    if (tid < off) s_red[tid] = fmaxf(s_red[tid], s_red[tid + off]);
    __syncthreads();
  }
  float nm = s_red[0];
  __syncthreads();
  float e0 = 0.f;
  if (tid < NNON) e0 = expf(s_sc[s_nidx[tid]] - nm);
  if (tid < 128) s_red[tid] = (tid < NNON) ? e0 : 0.f;
  __syncthreads();
  for (int off = 64; off > 0; off >>= 1) {
    if (tid < off) s_red[tid] += s_red[tid + off];
    __syncthreads();
  }
  float nS = s_red[0];
  __syncthreads();
  if (tid < NNON) s_wk[tid] = e0 / nS;
  __syncthreads();

  // ---- P3: wlog gather -> s_w[p][r] fp32 (overlays sel region), softmax ----
  float scale_val = scale_p[0];
  for (int i = tid; i < KEEPED * NKEEP; i += 512) {
    int k = i / KEEPED, p = i - k * KEEPED;
    s_w[p * NKEEP + k] = ws[WS_WLOG + ((size_t)v * LV + s_kidx[k]) * KEEPED + p] * scale_val;
  }
  __syncthreads();
  if (tid < KEEPED * 8) {
    int p = tid >> 3, g = tid & 7;
    float mm = -3e38f;
    for (int k = g; k < NKEEP; k += 8) mm = fmaxf(mm, s_w[p * NKEEP + k]);
    #pragma unroll
    for (int off = 4; off > 0; off >>= 1) mm = fmaxf(mm, __shfl_xor(mm, off, 8));
    float ss = 0.f;
    for (int k = g; k < NKEEP; k += 8) {
      float ee = expf(s_w[p * NKEEP + k] - mm);
      s_w[p * NKEEP + k] = ee;
      ss += ee;
    }
    #pragma unroll
    for (int off = 4; off > 0; off >>= 1) ss += __shfl_xor(ss, off, 8);
    float rs = 1.f / ss;
    for (int k = g; k < NKEEP; k += 8) s_w[p * NKEEP + k] *= rs;
  }
  __syncthreads();

  // ---- P4: scatter A = s_wa (bf16): kept weights + wk row 49 ----
  for (int i = tid; i < KEEPED * NKEEP; i += 512) {
    int p = i / NKEEP, r = i - p * NKEEP;
    s_wa[p * WA_STR + s_kidx[r]] = __float2bfloat16(s_w[p * NKEEP + r]);
  }
  if (tid < NNON) s_wa[49 * WA_STR + s_nidx[tid]] = __float2bfloat16(s_wk[tid]);
  // one-time: zero capq rows 24..31 (region past s_wa; sims rows 24..31 = 0)
  {
    uint* zc = (uint*)(s_capq + 24 * CAPQ_STR);
    for (int i = tid; i < 8 * CAPQ_STR / 2; i += 512) zc[i] = 0u;
  }
  __syncthreads();

  // ---- fused quarter loop: per q stage cap + compute sel quarter (P5) +
  // pool2 partials + P7/P9 partial MFMAs. sel stored UNNORMALIZED bf16;
  // normalization deferred to the sims/G writes (scaling commutes).
  const __hip_bfloat16* imgTv =
      (const __hip_bfloat16*)((const char*)ws + WS_IMGT_B) + (size_t)v * CDIM * TOKPAD;
  ushort* selw = (ushort*)s_sel;
  int mt = wv >> 2, nt = wv & 3;
  v4f sa = (v4f){0.f, 0.f, 0.f, 0.f};
  v4f ga[2];
  ga[0] = (v4f){0.f, 0.f, 0.f, 0.f};
  ga[1] = (v4f){0.f, 0.f, 0.f, 0.f};

  for (int q = 0; q < 4; ++q) {
    // stage cap quarter rows 0..23 (overwrites s_wa rows 50..63 -> P5 reads
    // of those A-rows see finite bf16 garbage; contaminates only sel rows
    // 50..63, whose downstream consumers are masked/zeroed)
    for (int i = tid; i < 24 * 32; i += 512) {
      int w = i >> 5, c4 = i & 31;
      float4 xv = *(const float4*)(ws + WS_CAPNORM + ((size_t)t * NW + w) * CDIM
                                   + q * 128 + c4 * 4);
      union { __hip_bfloat16 hh[4]; uint2 u; } pc;
      pc.hh[0] = __float2bfloat16(xv.x); pc.hh[1] = __float2bfloat16(xv.y);
      pc.hh[2] = __float2bfloat16(xv.z); pc.hh[3] = __float2bfloat16(xv.w);
      *(uint2*)(s_capq + w * CAPQ_STR + c4 * 4) = pc.u;
    }
    __syncthreads();

    // P5 quarter: wave wv owns j-tile cols q*128 + wv*16 + (0..15)
    v4f acc[4];
    #pragma unroll
    for (int m = 0; m < 4; ++m) acc[m] = (v4f){0.f, 0.f, 0.f, 0.f};
    {
      const __hip_bfloat16* bp = imgTv + (size_t)(q * 128 + wv * 16 + l15) * TOKPAD;
      for (int ks = 0; ks < 7; ++ks) {
        v8s bfr = *(const v8s*)(bp + ks * 32 + koff);
        #pragma unroll
        for (int m = 0; m < 4; ++m) {
          v8s af = *(const v8s*)(s_wa + (m * 16 + l15) * WA_STR + ks * 32 + koff);
          acc[m] = MFMA16(af, bfr, acc[m]);
        }
      }
    }
    // pool2 partials (width-16 shuffle over the 16 cols of this j-tile) +
    // pack unnormalized bf16 into sel quarter
    #pragma unroll
    for (int m = 0; m < 4; ++m) {
      #pragma unroll
      for (int reg = 0; reg < 4; ++reg) {
        float val = acc[m][reg];
        float ss = val * val;
        #pragma unroll
        for (int off = 8; off > 0; off >>= 1) ss += __shfl_xor(ss, off, 16);
        int p = m * 16 + quad * 4 + reg;
        if (l15 == 0) atomicAdd(&s_pool2[p], ss);
        selw[p * SELQ_STR + wv * 16 + l15] = bfb(val);
      }
    }
    __syncthreads();

    // P7 partial: sims += cap_quarter . sel_quarter^T (unnormalized)
    #pragma unroll
    for (int ks = 0; ks < 4; ++ks) {
      v8s a  = *(const v8s*)(s_capq + (mt * 16 + l15) * CAPQ_STR + ks * 32 + koff);
      v8s bb = *(const v8s*)(s_sel + (nt * 16 + l15) * SELQ_STR + ks * 32 + koff);
      sa = MFMA16(a, bb, sa);
    }
    // P9 partial: G += sel_quarter . sel_quarter^T (unnormalized)
    #pragma unroll
    for (int i2 = 0; i2 < 2; ++i2) {
      int idx = wv * 2 + i2;
      int gm = idx >> 2, gn = idx & 3;
      #pragma unroll
      for (int ks = 0; ks < 4; ++ks) {
        v8s a  = *(const v8s*)(s_sel + (gm * 16 + l15) * SELQ_STR + ks * 32 + koff);
        v8s bb = *(const v8s*)(s_sel + (gn * 16 + l15) * SELQ_STR + ks * 32 + koff);
        ga[i2] = MFMA16(a, bb, ga[i2]);
      }
    }
    __syncthreads();   // before next quarter overwrites capq/sel
  }

  // ---- deferred normalization + write sims/G (overlay s_wa/capq, dead) ----
  if (tid < 64) s_inv[tid] = 1.f / fmaxf(sqrtf(s_pool2[tid]), 1e-12f);
  __syncthreads();
  {
    float ivc = s_inv[nt * 16 + l15];
    #pragma unroll
    for (int reg = 0; reg < 4; ++reg)
      s_sims[(mt * 16 + quad * 4 + reg) * 64 + nt * 16 + l15] = sa[reg] * ivc;
  }
  #pragma unroll
  for (int i2 = 0; i2 < 2; ++i2) {
    int idx = wv * 2 + i2;
    int gm = idx >> 2, gn = idx & 3;
    float ivc = s_inv[gn * 16 + l15];
    #pragma unroll
    for (int reg = 0; reg < 4; ++reg) {
      int row = gm * 16 + quad * 4 + reg;
      s_G[row * G_STR + gn * 16 + l15] = ga[i2][reg] * s_inv[row] * ivc;
    }
  }
  __syncthreads();

  // ---- P8: per-word softmax (unnormalized e) + num = sum e*s ----
  if (tid < NW * 8) {
    int w = tid >> 3, g = tid & 7;
    float* row = s_sims + w * 64;
    float mm = -3e38f;
    for (int p = g; p < 50; p += 8) mm = fmaxf(mm, row[p]);
    #pragma unroll
    for (int off = 4; off > 0; off >>= 1) mm = fmaxf(mm, __shfl_xor(mm, off, 8));
    float num = 0.f;
    for (int p = g; p < 64; p += 8) {
      if (p < 50) {
        float s = row[p];
        float ee = expf(LAMBDA_ * (s - mm));
        num += ee * s;
        row[p] = ee;
      } else row[p] = 0.f;
    }
    #pragma unroll
    for (int off = 4; off > 0; off >>= 1) num += __shfl_xor(num, off, 8);
    if (g == 0) s_red[w] = num;
  }
  __syncthreads();

  // ---- P10: word_sim = num / sqrt(e^T G e); mean over words ----
  float wacc = 0.f;
  for (int w = wv; w < NW; w += 8) {
    const float* ev = s_sims + w * 64;
    float tl = 0.f;
    for (int q = 0; q < 50; ++q) tl += s_G[q * G_STR + lane] * ev[q];
    float ql = ev[lane] * tl;
    #pragma unroll
    for (int off = 32; off > 0; off >>= 1) ql += __shfl_xor(ql, off, 64);
    if (lane == 0) wacc += s_red[w] / fmaxf(sqrtf(ql), 1e-20f);
  }
  if (lane == 0) s_red[64 + wv] = wacc;
  __syncthreads();
  if (tid == 0) {
    float s = 0.f;
    #pragma unroll
    for (int i = 0; i < 8; ++i) s += s_red[64 + i];
    out[(size_t)v * BT + t] = s / (float)NW;
  }
}

// ---------------------------------------------------------------------------
extern "C" void kernel_launch(void* const* d_in, const int* in_sizes, int n_in,
                              void* d_out, int out_size, void* d_ws, size_t ws_size,
                              hipStream_t stream) {
  const float* img   = (const float*)d_in[0];
  const float* cap   = (const float*)d_in[1];
  // d_in[2] = cap_lens (unused by forward)
  const float* gamma = (const float*)d_in[3];
  const float* beta  = (const float*)d_in[4];
  const float* W1    = (const float*)d_in[5];
  const float* b1    = (const float*)d_in[6];
  const float* W2    = (const float*)d_in[7];
  const float* b2    = (const float*)d_in[8];
  const float* scale = (const float*)d_in[9];
  float* ws  = (float*)d_ws;
  float* out = (float*)d_out;

  const bool big = (ws_size >= WS_NEED_B);   // constant across calls -> graph-safe

  if (big) k0_prep<<<dim3(BV, 7), dim3(512), 0, stream>>>(img, ws);
  k5_prep<<<dim3(176), dim3(512), 0, stream>>>(W1, W2, ws);
  k1_glo <<<dim3(BT + BV), dim3(256), 0, stream>>>(img, cap, ws);
  k2_mlp <<<dim3(BV, 7), dim3(512), 0, stream>>>(img, gamma, beta, b1, b2, ws);
  k3_score<<<dim3(BV, 4), dim3(256), 0, stream>>>(img, ws);
  if (big) k4_big<<<dim3(BV * BT), dim3(512), 0, stream>>>(img, scale, ws, out);
  else     k4_main<0><<<dim3(BV * BT), dim3(512), 0, stream>>>(img, scale, ws, out);
}

// Round 7
// 351.821 us; speedup vs baseline: 1.3110x; 1.3110x over previous
//
#include <hip/hip_runtime.h>
#include <hip/hip_bf16.h>
#include <math.h>

#define CDIM 512
#define LV 196
#define BV 64
#define BT 32
#define NW 24
#define NKEEP 98
#define NNON 98      // LV - NKEEP
#define KEEPED 49
#define HID 102
#define LAMBDA_ 4.0f
#define LN_EPS_ 1e-5f

// ws layout (float offsets)
#define WS_CAPNORM 0
#define WS_CAPGLO  (WS_CAPNORM + BT*NW*CDIM)     // 393216
#define WS_IMGGLO  (WS_CAPGLO + BT*CDIM)         // +16384
#define WS_INVN    (WS_IMGGLO + BV*CDIM)         // +32768
#define WS_WLOG    (WS_INVN + BV*LV)             // +12544
#define WS_SCORE   (WS_WLOG + BV*LV*KEEPED)      // +614656
#define WS_END     (WS_SCORE + BT*BV*LV)         // 1470976 floats = 5.88 MB
// imgT (big path only): bf16 [64][512][224] appended after WS_END
#define WS_IMGT_B  ((size_t)WS_END * 4)          // byte offset 5883904
#define TOKPAD 224
#define WS_NEED_B  (WS_IMGT_B + (size_t)BV * CDIM * TOKPAD * 2)   // 20563968 B
// W1T/W2T (bf16) live in the WS_SCORE region: written by k5_prep, read by k2,
// then SCORE is overwritten by k3 (stream-ordered). 129 KB << 1.6 MB region.
#define WS_W1T_B   ((size_t)WS_SCORE * 4)
#define WS_W2T_B   (WS_W1T_B + (size_t)112 * 512 * 2)

typedef short v8s __attribute__((ext_vector_type(8)));   // 8 bf16 (4 VGPR)
typedef float v4f __attribute__((ext_vector_type(4)));
#define MFMA16(a, b, c) __builtin_amdgcn_mfma_f32_16x16x32_bf16((a), (b), (c), 0, 0, 0)

// LDS strides (elements), padded for bank behavior + alignment:
#define WA_STR 232    // A matrix rows (464 B, 16-aligned, 2-way banks)
#define TOK_STR 40    // token K-tile rows (80 B, 16-aligned)
#define SEL_STR 520   // sel rows (1040 B, 16-aligned, 2-way banks) [fallback k4]
#define G_STR 66      // Gram rows (f32)
#define XN_STR 520    // k2 xn rows (bf16)
#define HB_STR 136    // k2 hbuf rows (bf16; 136=2-way banks, not pow2)

// k4_big LDS plan (R12/r5, total 51968 B; measured 155 us, VGPR 64, no spill):
// R2 [0, 19216): s_w fp32 19208 (P3->P4) THEN sel quarter bf16 [64][136]=17408
// R1 [19216, 48912): wa bf16 [64][232]=29696 (P4->P5);
//   THEN cap quarter bf16 [24][136]=6528 (quarter loop; garbage reads to row 31
//        stay inside R1)
//   THEN sims f32 [32][64]=8192 + G f32 [64][66]=16896 (after quarter loop)
// Occupancy note (r5/r6 evidence): unified VGPR+AGPR file -> 64 VGPR + 64 AGPR
// acc = 128 regs/thread = 2 blocks/CU. (512,6) reg-cap spills (r3/r4: 780+ MB
// scratch); fusing P5 to shrink acc (r6) added barriers + bank conflicts and
// LOST 56 us with no occupancy gain. 2 blocks/CU is the settled point.
#define SELQ_STR 136  // 272 B rows
#define CAPQ_STR 136
#define K4_SMEM   51968
#define OFF_SEL   0
#define OFF_WA    19216
#define OFF_CAPQ  19216
#define OFF_SIMS  19216
#define OFF_G     27408    // ends 44304 (<= 48912)
#define OFF_SC    48912
#define OFF_KIDX  49696
#define OFF_NIDX  50088
#define OFF_CNT   50480
#define OFF_WK    50496
#define OFF_RED   50896
#define OFF_POOL2 51408
#define OFF_INV   51664    // ends 51920

__device__ __forceinline__ ushort bfb(float f) {
  __hip_bfloat16 h = __float2bfloat16(f);
  union { __hip_bfloat16 h; ushort u; } cv; cv.h = h; return cv.u;
}

// ---------------------------------------------------------------------------
// K0 (big path only): imgT[v][c][tok] bf16, tok padded 196->224 with zeros.
// ---------------------------------------------------------------------------
__global__ __launch_bounds__(512) void k0_prep(const float* __restrict__ img,
                                               float* __restrict__ ws) {
  int v = blockIdx.x, kt = blockIdx.y, c = threadIdx.x;
  float x[32];
  #pragma unroll
  for (int kk = 0; kk < 32; ++kk) {
    int tok = kt * 32 + kk;
    x[kk] = (tok < LV) ? img[((size_t)v * LV + tok) * CDIM + c] : 0.f;
  }
  __hip_bfloat16* imgT = (__hip_bfloat16*)((char*)ws + WS_IMGT_B);
  uint* dst = (uint*)(imgT + ((size_t)v * CDIM + c) * TOKPAD + kt * 32);
  #pragma unroll
  for (int g = 0; g < 4; ++g) {
    uint4 u;
    u.x = (uint)bfb(x[g*8+0]) | ((uint)bfb(x[g*8+1]) << 16);
    u.y = (uint)bfb(x[g*8+2]) | ((uint)bfb(x[g*8+3]) << 16);
    u.z = (uint)bfb(x[g*8+4]) | ((uint)bfb(x[g*8+5]) << 16);
    u.w = (uint)bfb(x[g*8+6]) | ((uint)bfb(x[g*8+7]) << 16);
    *(uint4*)(dst + g * 4) = u;
  }
}

// ---------------------------------------------------------------------------
// K5: transpose W1 -> W1T bf16 [112 h][512 k], W2 -> W2T bf16 [64 p][128 h]
// ---------------------------------------------------------------------------
__global__ __launch_bounds__(512) void k5_prep(const float* __restrict__ W1,
                                               const float* __restrict__ W2,
                                               float* __restrict__ ws) {
  int b = blockIdx.x, tid = threadIdx.x;
  if (b < 112) {
    int h = b;
    float val = (h < HID) ? W1[(size_t)tid * HID + h] : 0.f;
    ((ushort*)((char*)ws + WS_W1T_B))[(size_t)h * 512 + tid] = bfb(val);
  } else {
    int p = b - 112;
    if (tid < 128) {
      int h = tid;
      float val = (p < KEEPED && h < HID) ? W2[(size_t)h * KEEPED + p] : 0.f;
      ((ushort*)((char*)ws + WS_W2T_B))[(size_t)p * 128 + h] = bfb(val);
    }
  }
}

// ---------------------------------------------------------------------------
// K1: cap_norm + cap_glo (blocks 0..31), img_glo (blocks 32..95). 256 thr.
// R14: img branch wave-sliced — each of 4 waves sums a 49-row slice for all
// 512 cols (8 cols/lane, float4 pairs) into s_part; 4x the ILP of the old
// 196-deep serial per-thread loop at identical load count.
// ---------------------------------------------------------------------------
__global__ __launch_bounds__(256) void k1_glo(const float* __restrict__ img,
                                              const float* __restrict__ cap,
                                              float* __restrict__ ws) {
  __shared__ float red[256];
  __shared__ float s_part[4 * CDIM];   // per-wave raw-sum partials
  __shared__ float s_glo[CDIM];
  int b = blockIdx.x, tid = threadIdx.x;
  if (b < BT) {
    int t = b;
    int wv = tid >> 6, lane = tid & 63;
    int cb = lane * 8;
    float4 sA = make_float4(0.f,0.f,0.f,0.f), sB = make_float4(0.f,0.f,0.f,0.f);
    for (int w = wv; w < NW; w += 4) {
      const float* p = cap + ((size_t)t * NW + w) * CDIM + cb;
      float4 xa = *(const float4*)p;
      float4 xb = *(const float4*)(p + 4);
      float ss = xa.x*xa.x + xa.y*xa.y + xa.z*xa.z + xa.w*xa.w
               + xb.x*xb.x + xb.y*xb.y + xb.z*xb.z + xb.w*xb.w;
      #pragma unroll
      for (int off = 32; off > 0; off >>= 1) ss += __shfl_xor(ss, off, 64);
      float inv = 1.f / fmaxf(sqrtf(ss), 1e-12f);
      float* q = ws + WS_CAPNORM + ((size_t)t * NW + w) * CDIM + cb;
      *(float4*)q       = make_float4(xa.x*inv, xa.y*inv, xa.z*inv, xa.w*inv);
      *(float4*)(q + 4) = make_float4(xb.x*inv, xb.y*inv, xb.z*inv, xb.w*inv);
      sA.x += xa.x; sA.y += xa.y; sA.z += xa.z; sA.w += xa.w;
      sB.x += xb.x; sB.y += xb.y; sB.z += xb.z; sB.w += xb.w;
    }
    *(float4*)&s_part[wv * CDIM + cb]     = sA;
    *(float4*)&s_part[wv * CDIM + cb + 4] = sB;
    __syncthreads();
    if (tid < 128) {
      float4 g = make_float4(0.f, 0.f, 0.f, 0.f);
      #pragma unroll
      for (int w2 = 0; w2 < 4; ++w2) {
        float4 pv = *(const float4*)&s_part[w2 * CDIM + tid * 4];
        g.x += pv.x; g.y += pv.y; g.z += pv.z; g.w += pv.w;
      }
      g.x /= (float)NW; g.y /= (float)NW; g.z /= (float)NW; g.w /= (float)NW;
      *(float4*)&s_glo[tid * 4] = g;
      red[tid] = g.x*g.x + g.y*g.y + g.z*g.z + g.w*g.w;
    }
    __syncthreads();
    for (int off = 64; off > 0; off >>= 1) {
      if (tid < off) red[tid] += red[tid + off];
      __syncthreads();
    }
    float inv = 1.f / fmaxf(sqrtf(red[0]), 1e-12f);
    if (tid < 128) {
      float4 g = *(const float4*)&s_glo[tid * 4];
      *(float4*)(ws + WS_CAPGLO + (size_t)t * CDIM + tid * 4) =
          make_float4(g.x*inv, g.y*inv, g.z*inv, g.w*inv);
    }
  } else {
    int v = b - BT;
    int wv = tid >> 6, lane = tid & 63;
    int cb = lane * 8;
    const float* base = img + (size_t)v * LV * CDIM;
    float4 sA = make_float4(0.f,0.f,0.f,0.f), sB = make_float4(0.f,0.f,0.f,0.f);
    int l0 = wv * 49;                         // 4 waves x 49 rows = 196
    for (int l = l0; l < l0 + 49; ++l) {
      const float* p = base + (size_t)l * CDIM + cb;
      float4 xa = *(const float4*)p;
      float4 xb = *(const float4*)(p + 4);
      sA.x += xa.x; sA.y += xa.y; sA.z += xa.z; sA.w += xa.w;
      sB.x += xb.x; sB.y += xb.y; sB.z += xb.z; sB.w += xb.w;
    }
    *(float4*)&s_part[wv * CDIM + cb]     = sA;
    *(float4*)&s_part[wv * CDIM + cb + 4] = sB;
    __syncthreads();
    if (tid < 128) {
      float4 g = make_float4(0.f, 0.f, 0.f, 0.f);
      #pragma unroll
      for (int w2 = 0; w2 < 4; ++w2) {
        float4 pv = *(const float4*)&s_part[w2 * CDIM + tid * 4];
        g.x += pv.x; g.y += pv.y; g.z += pv.z; g.w += pv.w;
      }
      g.x /= (float)LV; g.y /= (float)LV; g.z /= (float)LV; g.w /= (float)LV;
      *(float4*)&s_glo[tid * 4] = g;
      red[tid] = g.x*g.x + g.y*g.y + g.z*g.z + g.w*g.w;
    }
    __syncthreads();
    for (int off = 64; off > 0; off >>= 1) {
      if (tid < off) red[tid] += red[tid + off];
      __syncthreads();
    }
    float inv = 1.f / fmaxf(sqrtf(red[0]), 1e-12f);
    if (tid < 128) {
      float4 g = *(const float4*)&s_glo[tid * 4];
      *(float4*)(ws + WS_IMGGLO + (size_t)v * CDIM + tid * 4) =
          make_float4(g.x*inv, g.y*inv, g.z*inv, g.w*inv);
    }
  }
}

// ---------------------------------------------------------------------------
// K2: MFMA MLP. grid (64 v, 7 segs of 28 tokens), 512 thr (8 waves).
// LDS [32][520] bf16 = 33,280 B -> full-GPU grid + multi-block/CU.
// ---------------------------------------------------------------------------
__global__ __launch_bounds__(512, 4) void k2_mlp(const float* __restrict__ img,
                                                 const float* __restrict__ gamma,
                                                 const float* __restrict__ beta,
                                                 const float* __restrict__ b1,
                                                 const float* __restrict__ b2,
                                                 float* __restrict__ ws) {
  __shared__ __align__(16) __hip_bfloat16 s_xn[32 * XN_STR];  // 33,280 B
  __hip_bfloat16* s_hb = s_xn;                                // overlay after GEMM1

  int v = blockIdx.x, seg = blockIdx.y;
  int l0 = seg * 28;
  int tid = threadIdx.x, wv = tid >> 6, lane = tid & 63;
  int quad = lane >> 4, l15 = lane & 15, koff = quad * 8;
  const __hip_bfloat16* W1T = (const __hip_bfloat16*)((const char*)ws + WS_W1T_B);
  const __hip_bfloat16* W2T = (const __hip_bfloat16*)((const char*)ws + WS_W2T_B);

  // ---- Phase A: LN -> xn bf16 (28 tokens) ----
  int cb = lane * 8;
  float4 g4a = *(const float4*)(gamma + cb);
  float4 g4b = *(const float4*)(gamma + cb + 4);
  float4 b4a = *(const float4*)(beta + cb);
  float4 b4b = *(const float4*)(beta + cb + 4);
  for (int tok = wv; tok < 28; tok += 8) {
    const float* p = img + ((size_t)v * LV + l0 + tok) * CDIM + cb;
    float4 xa = *(const float4*)p;
    float4 xb = *(const float4*)(p + 4);
    float s  = xa.x + xa.y + xa.z + xa.w + xb.x + xb.y + xb.z + xb.w;
    float sq = xa.x*xa.x + xa.y*xa.y + xa.z*xa.z + xa.w*xa.w
             + xb.x*xb.x + xb.y*xb.y + xb.z*xb.z + xb.w*xb.w;
    #pragma unroll
    for (int off = 32; off > 0; off >>= 1) { s += __shfl_xor(s, off, 64); sq += __shfl_xor(sq, off, 64); }
    float mean = s / (float)CDIM;
    float var = sq / (float)CDIM - mean * mean;
    float rstd = 1.f / sqrtf(var + LN_EPS_);
    if (lane == 0) ws[WS_INVN + (size_t)v * LV + l0 + tok] = 1.f / fmaxf(sqrtf(sq), 1e-12f);
    float f[8];
    f[0] = (xa.x - mean) * rstd * g4a.x + b4a.x;
    f[1] = (xa.y - mean) * rstd * g4a.y + b4a.y;
    f[2] = (xa.z - mean) * rstd * g4a.z + b4a.z;
    f[3] = (xa.w - mean) * rstd * g4a.w + b4a.w;
    f[4] = (xb.x - mean) * rstd * g4b.x + b4b.x;
    f[5] = (xb.y - mean) * rstd * g4b.y + b4b.y;
    f[6] = (xb.z - mean) * rstd * g4b.z + b4b.z;
    f[7] = (xb.w - mean) * rstd * g4b.w + b4b.w;
    uint4 u;
    u.x = (uint)bfb(f[0]) | ((uint)bfb(f[1]) << 16);
    u.y = (uint)bfb(f[2]) | ((uint)bfb(f[3]) << 16);
    u.z = (uint)bfb(f[4]) | ((uint)bfb(f[5]) << 16);
    u.w = (uint)bfb(f[6]) | ((uint)bfb(f[7]) << 16);
    *(uint4*)(s_xn + (size_t)tok * XN_STR + cb) = u;
  }
  __syncthreads();

  // ---- GEMM1: C[32 tok][112 h], 2x7 = 14 tiles over 8 waves ----
  v4f c1[2];
  int mt_[2], nt_[2];
  #pragma unroll
  for (int i = 0; i < 2; ++i) {
    int idx = wv + 8 * i; if (idx > 13) idx = 13;   // clamp: keep reads in-bounds
    mt_[i] = idx / 7; nt_[i] = idx % 7;
    c1[i] = (v4f){0.f, 0.f, 0.f, 0.f};
  }
  for (int ks = 0; ks < 16; ++ks) {
    #pragma unroll
    for (int i = 0; i < 2; ++i) {
      v8s a  = *(const v8s*)(s_xn + (size_t)(mt_[i] * 16 + l15) * XN_STR + ks * 32 + koff);
      v8s bb = *(const v8s*)(W1T + (size_t)(nt_[i] * 16 + l15) * 512 + ks * 32 + koff);
      c1[i] = MFMA16(a, bb, c1[i]);
    }
  }
  __syncthreads();   // all xn reads complete before hbuf overlay

  // ---- gelu + bias -> hbuf [32][136] ----
  #pragma unroll
  for (int i = 0; i < 2; ++i) {
    int idx = wv + 8 * i;
    if (idx < 14) {
      int h = nt_[i] * 16 + l15;
      float bias = (h < HID) ? b1[h] : 0.f;
      #pragma unroll
      for (int reg = 0; reg < 4; ++reg) {
        int row = mt_[i] * 16 + quad * 4 + reg;
        float x = c1[i][reg] + bias;
        float gl = (h < HID) ? 0.5f * x * (1.f + erff(x * 0.70710678118654752f)) : 0.f;
        s_hb[(size_t)row * HB_STR + h] = __float2bfloat16(gl);
      }
    }
  }
  for (int i = tid; i < 32 * 16; i += 512)   // zero cols 112..127 (K pad)
    s_hb[(size_t)(i >> 4) * HB_STR + 112 + (i & 15)] = __float2bfloat16(0.f);
  __syncthreads();

  // ---- GEMM2: C[32 tok][64 p], 2x4 = 8 tiles = 1/wave, K=128 ----
  int m2 = wv >> 2, n2 = wv & 3;
  v4f c2 = (v4f){0.f, 0.f, 0.f, 0.f};
  for (int ks = 0; ks < 4; ++ks) {
    v8s a  = *(const v8s*)(s_hb + (size_t)(m2 * 16 + l15) * HB_STR + ks * 32 + koff);
    v8s bb = *(const v8s*)(W2T + (size_t)(n2 * 16 + l15) * 128 + ks * 32 + koff);
    c2 = MFMA16(a, bb, c2);
  }
  {
    int p = n2 * 16 + l15;
    if (p < KEEPED) {
      float bias = b2[p];
      #pragma unroll
      for (int reg = 0; reg < 4; ++reg) {
        int tok = m2 * 16 + quad * 4 + reg;
        if (tok < 28)
          ws[WS_WLOG + ((size_t)v * LV + l0 + tok) * KEEPED + p] = c2[reg] + bias;
      }
    }
  }
}

// ---------------------------------------------------------------------------
// K3: scores. R14: 512 threads (8 waves vs 4) — queries split 8-way
// (q = qg + 8*qi, qi<5), halving per-thread serial FMA/LDS work. Per-(q,l)
// accumulation order unchanged -> bitwise-identical scores.
// ---------------------------------------------------------------------------
__global__ __launch_bounds__(512) void k3_score(const float* __restrict__ img,
                                                float* __restrict__ ws) {
  __shared__ float qt[33 * 64];
  __shared__ float xt[64 * 65];
  __shared__ float dself[64];
  int v = blockIdx.x;
  int t0 = blockIdx.y * 64;
  int tid = threadIdx.x;
  int tloc = tid & 63, qg = tid >> 6;   // qg 0..7
  float acc[5];
  #pragma unroll
  for (int i = 0; i < 5; ++i) acc[i] = 0.f;
  const float* capglo = ws + WS_CAPGLO;
  const float* imgglo = ws + WS_IMGGLO + (size_t)v * CDIM;

  for (int ct = 0; ct < 8; ++ct) {
    for (int i = tid; i < 33 * 64; i += 512) {
      int q = i >> 6, cc = i & 63;
      qt[i] = (q < 32) ? capglo[(size_t)q * CDIM + ct * 64 + cc] : imgglo[ct * 64 + cc];
    }
    for (int i = tid; i < 64 * 64; i += 512) {
      int tok = i >> 6, cc = i & 63;
      int l = t0 + tok;
      xt[tok * 65 + cc] = (l < LV) ? img[((size_t)v * LV + l) * CDIM + ct * 64 + cc] : 0.f;
    }
    __syncthreads();
    for (int cc = 0; cc < 64; ++cc) {
      float xv = xt[tloc * 65 + cc];
      #pragma unroll
      for (int qi = 0; qi < 5; ++qi) {
        int q = qg + 8 * qi;
        if (q < 33) acc[qi] += qt[q * 64 + cc] * xv;
      }
    }
    __syncthreads();
  }
  if (qg == 0) dself[tloc] = acc[4];    // q = 0 + 8*4 = 32 (self query)
  __syncthreads();
  int l = t0 + tloc;
  if (l < LV) {
    float invn = ws[WS_INVN + (size_t)v * LV + l];
    float ds = dself[tloc];
    #pragma unroll
    for (int qi = 0; qi < 5; ++qi) {
      int q = qg + 8 * qi;
      if (q < 32) ws[WS_SCORE + ((size_t)q * BV + v) * LV + l] = (acc[qi] + ds) * invn;
    }
  }
}

// ---------------------------------------------------------------------------
// K4 fallback (small ws): verbatim old template, only <0> instantiated.
// ---------------------------------------------------------------------------
template<int USE_IMGT>
__global__ __launch_bounds__(512, 2) void k4_main(const float* __restrict__ img,
                                                  const float* __restrict__ scale_p,
                                                  const float* __restrict__ ws,
                                                  float* __restrict__ out) {
  __shared__ float s_sc[LV];
  __shared__ int   s_kidx[NKEEP];
  __shared__ int   s_nidx[NNON];
  __shared__ int   s_cnt[2];
  __shared__ float s_wk[NNON];
  __shared__ float s_red[128];
  __shared__ float s_pool2[64];
  __shared__ float s_inv[64];
  __shared__ __align__(16) __hip_bfloat16 s_selh[64 * SEL_STR];
  __shared__ __align__(16) __hip_bfloat16 s_wa[64 * WA_STR];
  __shared__ __align__(16) __hip_bfloat16 s_dyn[512 * TOK_STR];

  float* s_w = (float*)s_dyn;
  __hip_bfloat16* s_tok = s_dyn;
  __hip_bfloat16* s_cap = s_dyn;
  float* s_sims = (float*)s_wa;
  float* s_G = (float*)((char*)s_wa + 8192);

  int b = blockIdx.x;
  int v = b >> 5, t = b & 31;
  int tid = threadIdx.x;
  int wv = tid >> 6, lane = tid & 63;
  int quad = lane >> 4, l15 = lane & 15;
  int koff = quad * 8;

  if (tid < 2) s_cnt[tid] = 0;
  if (tid < 64) s_pool2[tid] = 0.f;
  if (tid < LV) s_sc[tid] = ws[WS_SCORE + ((size_t)t * BV + v) * LV + tid];
  {
    uint* za = (uint*)s_wa;
    for (int i = tid; i < 64 * WA_STR / 2; i += 512) za[i] = 0u;
    uint* zs = (uint*)(s_selh + 50 * SEL_STR);
    for (int i = tid; i < 14 * SEL_STR / 2; i += 512) zs[i] = 0u;
  }
  __syncthreads();

  if (tid < LV) {
    float my = s_sc[tid];
    int cnt = 0;
    for (int j = 0; j < LV; ++j) {
      float sj = s_sc[j];
      cnt += (sj > my) || (sj == my && j < tid);
    }
    bool keep = cnt < NKEEP;
    out[BV * BT + ((size_t)t * BV + v) * LV + tid] = keep ? 1.f : 0.f;
    if (keep) { int p = atomicAdd(&s_cnt[0], 1); s_kidx[p] = tid; }
    else      { int p = atomicAdd(&s_cnt[1], 1); s_nidx[p] = tid; }
  }
  __syncthreads();

  if (tid < 128) s_red[tid] = (tid < NNON) ? s_sc[s_nidx[tid]] : -3.0e38f;
  __syncthreads();
  for (int off = 64; off > 0; off >>= 1) {
    if (tid < off) s_red[tid] = fmaxf(s_red[tid], s_red[tid + off]);
    __syncthreads();
  }
  float nm = s_red[0];
  __syncthreads();
  float e0 = 0.f;
  if (tid < NNON) e0 = expf(s_sc[s_nidx[tid]] - nm);
  if (tid < 128) s_red[tid] = (tid < NNON) ? e0 : 0.f;
  __syncthreads();
  for (int off = 64; off > 0; off >>= 1) {
    if (tid < off) s_red[tid] += s_red[tid + off];
    __syncthreads();
  }
  float nS = s_red[0];
  __syncthreads();
  if (tid < NNON) s_wk[tid] = e0 / nS;
  __syncthreads();

  float scale_val = scale_p[0];
  for (int i = tid; i < KEEPED * NKEEP; i += 512) {
    int k = i / KEEPED, p = i - k * KEEPED;
    s_w[p * NKEEP + k] = ws[WS_WLOG + ((size_t)v * LV + s_kidx[k]) * KEEPED + p] * scale_val;
  }
  __syncthreads();
  if (tid < KEEPED * 8) {
    int p = tid >> 3, g = tid & 7;
    float mm = -3e38f;
    for (int k = g; k < NKEEP; k += 8) mm = fmaxf(mm, s_w[p * NKEEP + k]);
    #pragma unroll
    for (int off = 4; off > 0; off >>= 1) mm = fmaxf(mm, __shfl_xor(mm, off, 8));
    float ss = 0.f;
    for (int k = g; k < NKEEP; k += 8) {
      float ee = expf(s_w[p * NKEEP + k] - mm);
      s_w[p * NKEEP + k] = ee;
      ss += ee;
    }
    #pragma unroll
    for (int off = 4; off > 0; off >>= 1) ss += __shfl_xor(ss, off, 8);
    float rs = 1.f / ss;
    for (int k = g; k < NKEEP; k += 8) s_w[p * NKEEP + k] *= rs;
  }
  __syncthreads();

  for (int i = tid; i < KEEPED * NKEEP; i += 512) {
    int p = i / NKEEP, r = i - p * NKEEP;
    s_wa[p * WA_STR + s_kidx[r]] = __float2bfloat16(s_w[p * NKEEP + r]);
  }
  if (tid < NNON) s_wa[49 * WA_STR + s_nidx[tid]] = __float2bfloat16(s_wk[tid]);
  __syncthreads();

  v4f acc[4][4];
  #pragma unroll
  for (int m = 0; m < 4; ++m)
    #pragma unroll
    for (int j = 0; j < 4; ++j) acc[m][j] = (v4f){0.f, 0.f, 0.f, 0.f};

  if (USE_IMGT) {
    const __hip_bfloat16* imgTv =
        (const __hip_bfloat16*)((const char*)ws + WS_IMGT_B) + (size_t)v * CDIM * TOKPAD;
    for (int ks = 0; ks < 7; ++ks) {
      v8s bfr[4];
      #pragma unroll
      for (int j = 0; j < 4; ++j)
        bfr[j] = *(const v8s*)(imgTv + (size_t)(wv * 64 + j * 16 + l15) * TOKPAD + ks * 32 + koff);
      #pragma unroll
      for (int m = 0; m < 4; ++m) {
        v8s af = *(const v8s*)(s_wa + (m * 16 + l15) * WA_STR + ks * 32 + koff);
        #pragma unroll
        for (int j = 0; j < 4; ++j) acc[m][j] = MFMA16(af, bfr[j], acc[m][j]);
      }
    }
  } else {
    for (int ks = 0; ks < 7; ++ks) {
      #pragma unroll
      for (int it = 0; it < 8; ++it) {
        int k0 = ks * 32 + it * 4;
        if (k0 < LV) {
          const float* gp = img + ((size_t)v * LV + k0) * CDIM + tid;
          float x0 = gp[0], x1 = gp[CDIM], x2 = gp[2 * CDIM], x3 = gp[3 * CDIM];
          union { __hip_bfloat16 h[4]; uint2 u; } pk;
          pk.h[0] = __float2bfloat16(x0); pk.h[1] = __float2bfloat16(x1);
          pk.h[2] = __float2bfloat16(x2); pk.h[3] = __float2bfloat16(x3);
          *(uint2*)(s_tok + tid * TOK_STR + it * 4) = pk.u;
        }
      }
      __syncthreads();
      v8s bfr[4];
      #pragma unroll
      for (int j = 0; j < 4; ++j)
        bfr[j] = *(const v8s*)(s_tok + (wv * 64 + j * 16 + l15) * TOK_STR + koff);
      #pragma unroll
      for (int m = 0; m < 4; ++m) {
        v8s af = *(const v8s*)(s_wa + (m * 16 + l15) * WA_STR + ks * 32 + koff);
        #pragma unroll
        for (int j = 0; j < 4; ++j) acc[m][j] = MFMA16(af, bfr[j], acc[m][j]);
      }
      __syncthreads();
    }
  }

  if (!USE_IMGT) __syncthreads();
  for (int i = tid; i < NW * 128; i += 512) {
    int w = i >> 7, cq = i & 127;
    const float4 xv = *(const float4*)(ws + WS_CAPNORM + ((size_t)t * NW + w) * CDIM + cq * 4);
    union { __hip_bfloat16 h[4]; uint2 u; } pk;
    pk.h[0] = __float2bfloat16(xv.x); pk.h[1] = __float2bfloat16(xv.y);
    pk.h[2] = __float2bfloat16(xv.z); pk.h[3] = __float2bfloat16(xv.w);
    *(uint2*)(s_cap + w * SEL_STR + cq * 4) = pk.u;
  }
  {
    uint* zc = (uint*)(s_cap + 24 * SEL_STR);
    for (int i = tid; i < 8 * SEL_STR / 2; i += 512) zc[i] = 0u;
  }
  #pragma unroll
  for (int m = 0; m < 4; ++m) {
    #pragma unroll
    for (int reg = 0; reg < 4; ++reg) {
      float ss = acc[m][0][reg] * acc[m][0][reg] + acc[m][1][reg] * acc[m][1][reg]
               + acc[m][2][reg] * acc[m][2][reg] + acc[m][3][reg] * acc[m][3][reg];
      #pragma unroll
      for (int off = 8; off > 0; off >>= 1) ss += __shfl_xor(ss, off, 64);
      if (l15 == 0) atomicAdd(&s_pool2[m * 16 + quad * 4 + reg], ss);
    }
  }
  __syncthreads();
  if (tid < 64) s_inv[tid] = 1.f / fmaxf(sqrtf(s_pool2[tid]), 1e-12f);
  __syncthreads();
  #pragma unroll
  for (int m = 0; m < 4; ++m) {
    #pragma unroll
    for (int reg = 0; reg < 4; ++reg) {
      int p = m * 16 + quad * 4 + reg;
      if (p < 50) {
        float iv = s_inv[p];
        #pragma unroll
        for (int j = 0; j < 4; ++j)
          s_selh[p * SEL_STR + wv * 64 + j * 16 + l15] = __float2bfloat16(acc[m][j][reg] * iv);
      }
    }
  }
  __syncthreads();

  {
    int mt = wv >> 2, nt = wv & 3;
    v4f sa = (v4f){0.f, 0.f, 0.f, 0.f};
    for (int ks = 0; ks < 16; ++ks) {
      v8s a = *(const v8s*)(s_cap + (mt * 16 + l15) * SEL_STR + ks * 32 + koff);
      v8s bb = *(const v8s*)(s_selh + (nt * 16 + l15) * SEL_STR + ks * 32 + koff);
      sa = MFMA16(a, bb, sa);
    }
    #pragma unroll
    for (int reg = 0; reg < 4; ++reg)
      s_sims[(mt * 16 + quad * 4 + reg) * 64 + nt * 16 + l15] = sa[reg];
  }
  __syncthreads();

  if (tid < NW * 8) {
    int w = tid >> 3, g = tid & 7;
    float* row = s_sims + w * 64;
    float mm = -3e38f;
    for (int p = g; p < 50; p += 8) mm = fmaxf(mm, row[p]);
    #pragma unroll
    for (int off = 4; off > 0; off >>= 1) mm = fmaxf(mm, __shfl_xor(mm, off, 8));
    float num = 0.f;
    for (int p = g; p < 64; p += 8) {
      if (p < 50) {
        float s = row[p];
        float ee = expf(LAMBDA_ * (s - mm));
        num += ee * s;
        row[p] = ee;
      } else row[p] = 0.f;
    }
    #pragma unroll
    for (int off = 4; off > 0; off >>= 1) num += __shfl_xor(num, off, 8);
    if (g == 0) s_red[w] = num;
  }
  __syncthreads();

  #pragma unroll
  for (int i2 = 0; i2 < 2; ++i2) {
    int idx = wv * 2 + i2;
    int gm = idx >> 2, gn = idx & 3;
    v4f ga = (v4f){0.f, 0.f, 0.f, 0.f};
    for (int ks = 0; ks < 16; ++ks) {
      v8s a = *(const v8s*)(s_selh + (gm * 16 + l15) * SEL_STR + ks * 32 + koff);
      v8s bb = *(const v8s*)(s_selh + (gn * 16 + l15) * SEL_STR + ks * 32 + koff);
      ga = MFMA16(a, bb, ga);
    }
    #pragma unroll
    for (int reg = 0; reg < 4; ++reg)
      s_G[(gm * 16 + quad * 4 + reg) * G_STR + gn * 16 + l15] = ga[reg];
  }
  __syncthreads();

  float wacc = 0.f;
  for (int w = wv; w < NW; w += 8) {
    const float* ev = s_sims + w * 64;
    float tl = 0.f;
    for (int q = 0; q < 50; ++q) tl += s_G[q * G_STR + lane] * ev[q];
    float ql = ev[lane] * tl;
    #pragma unroll
    for (int off = 32; off > 0; off >>= 1) ql += __shfl_xor(ql, off, 64);
    if (lane == 0) wacc += s_red[w] / fmaxf(sqrtf(ql), 1e-20f);
  }
  if (lane == 0) s_red[64 + wv] = wacc;
  __syncthreads();
  if (tid == 0) {
    float s = 0.f;
    #pragma unroll
    for (int i = 0; i < 8; ++i) s += s_red[64 + i];
    out[(size_t)v * BT + t] = s / (float)NW;
  }
}

// ---------------------------------------------------------------------------
// K4 big path (R12 verbatim, 155 us measured): quarter-loop body, (512,4).
// 51,968 B LDS; natural 64-VGPR + 64-AGPR allocation -> 2 blk/CU, no spill.
// sel AND cap staged per 128-col quarter in LDS; P7/P9 read from LDS;
// sims/Gram accumulate across quarters in registers.
// ---------------------------------------------------------------------------
__global__ __launch_bounds__(512, 4) void k4_big(const float* __restrict__ img,
                                                 const float* __restrict__ scale_p,
                                                 const float* __restrict__ ws,
                                                 float* __restrict__ out) {
  __shared__ __align__(16) char smem[K4_SMEM];
  __hip_bfloat16* s_sel = (__hip_bfloat16*)(smem + OFF_SEL);   // [64][136] quarter
  float*          s_w   = (float*)(smem + OFF_SEL);            // overlay, P3/P4 only
  __hip_bfloat16* s_wa  = (__hip_bfloat16*)(smem + OFF_WA);    // [64][232] P4->P5
  __hip_bfloat16* s_capq= (__hip_bfloat16*)(smem + OFF_CAPQ);  // [24][136] loop only
  float*          s_sims= (float*)(smem + OFF_SIMS);           // [32][64] after loop
  float*          s_G   = (float*)(smem + OFF_G);              // [64][66] after loop
  float* s_sc    = (float*)(smem + OFF_SC);
  int*   s_kidx  = (int*)(smem + OFF_KIDX);
  int*   s_nidx  = (int*)(smem + OFF_NIDX);
  int*   s_cnt   = (int*)(smem + OFF_CNT);
  float* s_wk    = (float*)(smem + OFF_WK);
  float* s_red   = (float*)(smem + OFF_RED);
  float* s_pool2 = (float*)(smem + OFF_POOL2);
  float* s_inv   = (float*)(smem + OFF_INV);

  int b = blockIdx.x;
  int v = b >> 5, t = b & 31;
  int tid = threadIdx.x;
  int wv = tid >> 6, lane = tid & 63;
  int quad = lane >> 4, l15 = lane & 15;
  int koff = quad * 8;

  // ---- P0: loads + zero-init ----
  if (tid < 2) s_cnt[tid] = 0;
  if (tid < 64) s_pool2[tid] = 0.f;
  if (tid < LV) s_sc[tid] = ws[WS_SCORE + ((size_t)t * BV + v) * LV + tid];
  {
    uint* za = (uint*)s_wa;
    for (int i = tid; i < 64 * WA_STR / 2; i += 512) za[i] = 0u;
  }
  __syncthreads();

  // ---- P1: rank & partition ----
  if (tid < LV) {
    float my = s_sc[tid];
    int cnt = 0;
    for (int j = 0; j < LV; ++j) {
      float sj = s_sc[j];
      cnt += (sj > my) || (sj == my && j < tid);
    }
    bool keep = cnt < NKEEP;
    out[BV * BT + ((size_t)t * BV + v) * LV + tid] = keep ? 1.f : 0.f;
    if (keep) { int p = atomicAdd(&s_cnt[0], 1); s_kidx[p] = tid; }
    else      { int p = atomicAdd(&s_cnt[1], 1); s_nidx[p] = tid; }
  }
  __syncthreads();

  // ---- P2: softmax over non-kept scores -> s_wk ----
  if (tid < 128) s_red[tid] = (tid < NNON) ? s_sc[s_nidx[tid]] : -3.0e38f;
  __syncthreads();
  for (int off = 64; off > 0; off >>= 1) {
    if (tid < off) s_red[tid] = fmaxf(s_red[tid], s_red[tid + off]);
    __syncthreads();
  }
  float nm = s_red[0];
  __syncthreads();
  float e0 = 0.f;
  if (tid < NNON) e0 = expf(s_sc[s_nidx[tid]] - nm);
  if (tid < 128) s_red[tid] = (tid < NNON) ? e0 : 0.f;
  __syncthreads();
  for (int off = 64; off > 0; off >>= 1) {
    if (tid < off) s_red[tid] += s_red[tid + off];
    __syncthreads();
  }
  float nS = s_red[0];
  __syncthreads();
  if (tid < NNON) s_wk[tid] = e0 / nS;
  __syncthreads();

  // ---- P3: wlog gather -> s_w[p][r] fp32 (overlays sel region), softmax ----
  float scale_val = scale_p[0];
  for (int i = tid; i < KEEPED * NKEEP; i += 512) {
    int k = i / KEEPED, p = i - k * KEEPED;
    s_w[p * NKEEP + k] = ws[WS_WLOG + ((size_t)v * LV + s_kidx[k]) * KEEPED + p] * scale_val;
  }
  __syncthreads();
  if (tid < KEEPED * 8) {
    int p = tid >> 3, g = tid & 7;
    float mm = -3e38f;
    for (int k = g; k < NKEEP; k += 8) mm = fmaxf(mm, s_w[p * NKEEP + k]);
    #pragma unroll
    for (int off = 4; off > 0; off >>= 1) mm = fmaxf(mm, __shfl_xor(mm, off, 8));
    float ss = 0.f;
    for (int k = g; k < NKEEP; k += 8) {
      float ee = expf(s_w[p * NKEEP + k] - mm);
      s_w[p * NKEEP + k] = ee;
      ss += ee;
    }
    #pragma unroll
    for (int off = 4; off > 0; off >>= 1) ss += __shfl_xor(ss, off, 8);
    float rs = 1.f / ss;
    for (int k = g; k < NKEEP; k += 8) s_w[p * NKEEP + k] *= rs;
  }
  __syncthreads();

  // ---- P4: scatter A = s_wa (bf16): kept weights + wk row 49 ----
  for (int i = tid; i < KEEPED * NKEEP; i += 512) {
    int p = i / NKEEP, r = i - p * NKEEP;
    s_wa[p * WA_STR + s_kidx[r]] = __float2bfloat16(s_w[p * NKEEP + r]);
  }
  if (tid < NNON) s_wa[49 * WA_STR + s_nidx[tid]] = __float2bfloat16(s_wk[tid]);
  __syncthreads();

  // zero sel-quarter rows 50..63 (s_w dead after the barrier above; rows stay
  // zero across all four quarters — nobody writes p >= 50)
  {
    uint* zq = (uint*)(s_sel + 50 * SELQ_STR);
    for (int i = tid; i < 14 * SELQ_STR / 2; i += 512) zq[i] = 0u;
  }

  // ---- P5: aggr GEMM, B from global imgT ----
  v4f acc[4][4];
  #pragma unroll
  for (int m = 0; m < 4; ++m)
    #pragma unroll
    for (int j = 0; j < 4; ++j) acc[m][j] = (v4f){0.f, 0.f, 0.f, 0.f};

  {
    const __hip_bfloat16* imgTv =
        (const __hip_bfloat16*)((const char*)ws + WS_IMGT_B) + (size_t)v * CDIM * TOKPAD;
    for (int ks = 0; ks < 7; ++ks) {
      v8s bfr[4];
      #pragma unroll
      for (int j = 0; j < 4; ++j)
        bfr[j] = *(const v8s*)(imgTv + (size_t)(wv * 64 + j * 16 + l15) * TOKPAD + ks * 32 + koff);
      #pragma unroll
      for (int m = 0; m < 4; ++m) {
        v8s af = *(const v8s*)(s_wa + (m * 16 + l15) * WA_STR + ks * 32 + koff);
        #pragma unroll
        for (int j = 0; j < 4; ++j) acc[m][j] = MFMA16(af, bfr[j], acc[m][j]);
      }
    }
  }

  // ---- P6: pool l2norm (atomics into zeroed s_pool2) ----
  #pragma unroll
  for (int m = 0; m < 4; ++m) {
    #pragma unroll
    for (int reg = 0; reg < 4; ++reg) {
      float ss = acc[m][0][reg] * acc[m][0][reg] + acc[m][1][reg] * acc[m][1][reg]
               + acc[m][2][reg] * acc[m][2][reg] + acc[m][3][reg] * acc[m][3][reg];
      #pragma unroll
      for (int off = 8; off > 0; off >>= 1) ss += __shfl_xor(ss, off, 64);
      if (l15 == 0) atomicAdd(&s_pool2[m * 16 + quad * 4 + reg], ss);
    }
  }
  __syncthreads();
  if (tid < 64) s_inv[tid] = 1.f / fmaxf(sqrtf(s_pool2[tid]), 1e-12f);
  __syncthreads();

  // ---- pack normalized sel fragments: 64 f32 -> 32 uints (bf16 pairs) ----
  uint pk[4][4][2];
  #pragma unroll
  for (int m = 0; m < 4; ++m) {
    #pragma unroll
    for (int rp = 0; rp < 2; ++rp) {
      int p0 = m * 16 + quad * 4 + rp * 2;
      float iv0 = s_inv[p0], iv1 = s_inv[p0 + 1];
      #pragma unroll
      for (int j = 0; j < 4; ++j)
        pk[m][j][rp] = (uint)bfb(acc[m][j][2 * rp] * iv0)
                     | ((uint)bfb(acc[m][j][2 * rp + 1] * iv1) << 16);
    }
  }

  // ---- quarter loop: stage sel cols [q*128, q*128+128) (waves 2q,2q+1) and
  // cap quarter [24][128] (other 6 waves) in LDS; accumulate P7+P9.
  // capq garbage rows 24..31 (stale wa bf16, finite) feed sims rows 24..31,
  // which are never read (P8/P10 use w < 24 only).
  v4f sa = (v4f){0.f, 0.f, 0.f, 0.f};
  v4f ga[2];
  ga[0] = (v4f){0.f, 0.f, 0.f, 0.f};
  ga[1] = (v4f){0.f, 0.f, 0.f, 0.f};
  ushort* selw = (ushort*)s_sel;
  int mt = wv >> 2, nt = wv & 3;
  for (int q = 0; q < 4; ++q) {
    if ((wv >> 1) == q) {               // waves 2q, 2q+1 own cols q*128..+127
      int base = (wv & 1) * 64;
      #pragma unroll
      for (int m = 0; m < 4; ++m) {
        #pragma unroll
        for (int reg = 0; reg < 4; ++reg) {
          int p = m * 16 + quad * 4 + reg;
          if (p < 50) {
            #pragma unroll
            for (int j = 0; j < 4; ++j) {
              uint u = pk[m][j][reg >> 1];
              ushort val = (reg & 1) ? (ushort)(u >> 16) : (ushort)(u & 0xffffu);
              selw[p * SELQ_STR + base + j * 16 + l15] = val;
            }
          }
        }
      }
    } else {
      int rank = wv - (wv > 2 * q + 1 ? 2 : 0);   // 0..5 among 6 staging waves
      int lt = rank * 64 + lane;                  // 0..383
      for (int i = lt; i < NW * 32; i += 384) {
        int w = i >> 5, c4 = i & 31;
        float4 xv = *(const float4*)(ws + WS_CAPNORM + ((size_t)t * NW + w) * CDIM
                                     + q * 128 + c4 * 4);
        union { __hip_bfloat16 hh[4]; uint2 u; } pc;
        pc.hh[0] = __float2bfloat16(xv.x); pc.hh[1] = __float2bfloat16(xv.y);
        pc.hh[2] = __float2bfloat16(xv.z); pc.hh[3] = __float2bfloat16(xv.w);
        *(uint2*)(s_capq + w * CAPQ_STR + c4 * 4) = pc.u;
      }
    }
    __syncthreads();
    // P7 partial: sims += cap_quarter . sel_quarter^T
    #pragma unroll
    for (int ks = 0; ks < 4; ++ks) {
      v8s a  = *(const v8s*)(s_capq + (mt * 16 + l15) * CAPQ_STR + ks * 32 + koff);
      v8s bb = *(const v8s*)(s_sel + (nt * 16 + l15) * SELQ_STR + ks * 32 + koff);
      sa = MFMA16(a, bb, sa);
    }
    // P9 partial: G += sel_quarter . sel_quarter^T
    #pragma unroll
    for (int i2 = 0; i2 < 2; ++i2) {
      int idx = wv * 2 + i2;
      int gm = idx >> 2, gn = idx & 3;
      #pragma unroll
      for (int ks = 0; ks < 4; ++ks) {
        v8s a  = *(const v8s*)(s_sel + (gm * 16 + l15) * SELQ_STR + ks * 32 + koff);
        v8s bb = *(const v8s*)(s_sel + (gn * 16 + l15) * SELQ_STR + ks * 32 + koff);
        ga[i2] = MFMA16(a, bb, ga[i2]);
      }
    }
    __syncthreads();
  }

  // ---- write sims + G (overwrites capq/wa region, both dead now) ----
  #pragma unroll
  for (int reg = 0; reg < 4; ++reg)
    s_sims[(mt * 16 + quad * 4 + reg) * 64 + nt * 16 + l15] = sa[reg];
  #pragma unroll
  for (int i2 = 0; i2 < 2; ++i2) {
    int idx = wv * 2 + i2;
    int gm = idx >> 2, gn = idx & 3;
    #pragma unroll
    for (int reg = 0; reg < 4; ++reg)
      s_G[(gm * 16 + quad * 4 + reg) * G_STR + gn * 16 + l15] = ga[i2][reg];
  }
  __syncthreads();

  // ---- P8: per-word softmax (unnormalized e) + num = sum e*s ----
  if (tid < NW * 8) {
    int w = tid >> 3, g = tid & 7;
    float* row = s_sims + w * 64;
    float mm = -3e38f;
    for (int p = g; p < 50; p += 8) mm = fmaxf(mm, row[p]);
    #pragma unroll
    for (int off = 4; off > 0; off >>= 1) mm = fmaxf(mm, __shfl_xor(mm, off, 8));
    float num = 0.f;
    for (int p = g; p < 64; p += 8) {
      if (p < 50) {
        float s = row[p];
        float ee = expf(LAMBDA_ * (s - mm));
        num += ee * s;
        row[p] = ee;
      } else row[p] = 0.f;
    }
    #pragma unroll
    for (int off = 4; off > 0; off >>= 1) num += __shfl_xor(num, off, 8);
    if (g == 0) s_red[w] = num;
  }
  __syncthreads();

  // ---- P10: word_sim = num / sqrt(e^T G e); mean over words ----
  float wacc = 0.f;
  for (int w = wv; w < NW; w += 8) {
    const float* ev = s_sims + w * 64;
    float tl = 0.f;
    for (int q = 0; q < 50; ++q) tl += s_G[q * G_STR + lane] * ev[q];
    float ql = ev[lane] * tl;
    #pragma unroll
    for (int off = 32; off > 0; off >>= 1) ql += __shfl_xor(ql, off, 64);
    if (lane == 0) wacc += s_red[w] / fmaxf(sqrtf(ql), 1e-20f);
  }
  if (lane == 0) s_red[64 + wv] = wacc;
  __syncthreads();
  if (tid == 0) {
    float s = 0.f;
    #pragma unroll
    for (int i = 0; i < 8; ++i) s += s_red[64 + i];
    out[(size_t)v * BT + t] = s / (float)NW;
  }
}

// ---------------------------------------------------------------------------
extern "C" void kernel_launch(void* const* d_in, const int* in_sizes, int n_in,
                              void* d_out, int out_size, void* d_ws, size_t ws_size,
                              hipStream_t stream) {
  const float* img   = (const float*)d_in[0];
  const float* cap   = (const float*)d_in[1];
  // d_in[2] = cap_lens (unused by forward)
  const float* gamma = (const float*)d_in[3];
  const float* beta  = (const float*)d_in[4];
  const float* W1    = (const float*)d_in[5];
  const float* b1    = (const float*)d_in[6];
  const float* W2    = (const float*)d_in[7];
  const float* b2    = (const float*)d_in[8];
  const float* scale = (const float*)d_in[9];
  float* ws  = (float*)d_ws;
  float* out = (float*)d_out;

  const bool big = (ws_size >= WS_NEED_B);   // constant across calls -> graph-safe

  if (big) k0_prep<<<dim3(BV, 7), dim3(512), 0, stream>>>(img, ws);
  k5_prep<<<dim3(176), dim3(512), 0, stream>>>(W1, W2, ws);
  k1_glo <<<dim3(BT + BV), dim3(256), 0, stream>>>(img, cap, ws);
  k2_mlp <<<dim3(BV, 7), dim3(512), 0, stream>>>(img, gamma, beta, b1, b2, ws);
  k3_score<<<dim3(BV, 4), dim3(512), 0, stream>>>(img, ws);
  if (big) k4_big<<<dim3(BV * BT), dim3(512), 0, stream>>>(img, scale, ws, out);
  else     k4_main<0><<<dim3(BV * BT), dim3(512), 0, stream>>>(img, scale, ws, out);
}

// Round 8
// 347.046 us; speedup vs baseline: 1.3290x; 1.0138x over previous
//
#include <hip/hip_runtime.h>
#include <hip/hip_bf16.h>
#include <math.h>

#define CDIM 512
#define LV 196
#define BV 64
#define BT 32
#define NW 24
#define NKEEP 98
#define NNON 98      // LV - NKEEP
#define KEEPED 49
#define HID 102
#define LAMBDA_ 4.0f
#define LN_EPS_ 1e-5f

// ws layout (float offsets)
#define WS_CAPNORM 0
#define WS_CAPGLO  (WS_CAPNORM + BT*NW*CDIM)     // 393216
#define WS_IMGGLO  (WS_CAPGLO + BT*CDIM)         // +16384
#define WS_INVN    (WS_IMGGLO + BV*CDIM)         // +32768
#define WS_WLOG    (WS_INVN + BV*LV)             // +12544
#define WS_SCORE   (WS_WLOG + BV*LV*KEEPED)      // +614656
#define WS_END     (WS_SCORE + BT*BV*LV)         // 1470976 floats = 5.88 MB
// imgT (big path only): bf16 [64][512][224] appended after WS_END
#define WS_IMGT_B  ((size_t)WS_END * 4)          // byte offset 5883904
#define TOKPAD 224
#define WS_NEED_B  (WS_IMGT_B + (size_t)BV * CDIM * TOKPAD * 2)   // 20563968 B
// W1T/W2T (bf16) live in the WS_SCORE region: written by k0 plane 7 (big) or
// k5_prep (small), read by k2, then SCORE is overwritten by k3.
#define WS_W1T_B   ((size_t)WS_SCORE * 4)
#define WS_W2T_B   (WS_W1T_B + (size_t)112 * 512 * 2)

typedef short v8s __attribute__((ext_vector_type(8)));   // 8 bf16 (4 VGPR)
typedef float v4f __attribute__((ext_vector_type(4)));
#define MFMA16(a, b, c) __builtin_amdgcn_mfma_f32_16x16x32_bf16((a), (b), (c), 0, 0, 0)

// LDS strides (elements), padded for bank behavior + alignment:
#define WA_STR 232    // A matrix rows (464 B, 16-aligned, 2-way banks)
#define TOK_STR 40    // token K-tile rows (80 B, 16-aligned)
#define SEL_STR 520   // sel rows (1040 B, 16-aligned, 2-way banks) [fallback k4]
#define G_STR 66      // Gram rows (f32)
#define XN_STR 520    // k2 xn rows (bf16)
#define HB_STR 136    // k2 hbuf rows (bf16; 136=2-way banks, not pow2)

// k4_big LDS plan (R12/r5, total 51968 B; measured 155 us, VGPR 64, no spill):
// R2 [0, 19216): s_w fp32 19208 (P3->P4) THEN sel quarter bf16 [64][136]=17408
// R1 [19216, 48912): wa bf16 [64][232]=29696 (P4->P5);
//   THEN cap quarter bf16 [24][136]=6528 (quarter loop; garbage reads to row 31
//        stay inside R1)
//   THEN sims f32 [32][64]=8192 + G f32 [64][66]=16896 (after quarter loop)
// Occupancy note (r5/r6 evidence): unified VGPR+AGPR file -> 64 VGPR + 64 AGPR
// acc = 128 regs/thread = 2 blocks/CU. (512,6) reg-cap spills (r3/r4: 780+ MB
// scratch); fusing P5 to shrink acc (r6) added barriers + bank conflicts and
// LOST 56 us with no occupancy gain. 2 blocks/CU is the settled point.
#define SELQ_STR 136  // 272 B rows
#define CAPQ_STR 136
#define K4_SMEM   51968
#define OFF_SEL   0
#define OFF_WA    19216
#define OFF_CAPQ  19216
#define OFF_SIMS  19216
#define OFF_G     27408    // ends 44304 (<= 48912)
#define OFF_SC    48912
#define OFF_KIDX  49696
#define OFF_NIDX  50088
#define OFF_CNT   50480
#define OFF_WK    50496
#define OFF_RED   50896
#define OFF_POOL2 51408
#define OFF_INV   51664    // ends 51920

__device__ __forceinline__ ushort bfb(float f) {
  __hip_bfloat16 h = __float2bfloat16(f);
  union { __hip_bfloat16 h; ushort u; } cv; cv.h = h; return cv.u;
}

// ---------------------------------------------------------------------------
// K0 (big path only): grid (BV, 8).
// planes 0..6: imgT[v][c][tok] bf16, tok padded 196->224 with zeros.
// plane 7 (R15): k5's W1T/W2T transpose folded in (one fewer launch) —
//   v<56: W1T rows 2v, 2v+1; v>=56: W2T 1024 elems per block.
// ---------------------------------------------------------------------------
__global__ __launch_bounds__(512) void k0_prep(const float* __restrict__ img,
                                               const float* __restrict__ W1,
                                               const float* __restrict__ W2,
                                               float* __restrict__ ws) {
  int v = blockIdx.x, kt = blockIdx.y, c = threadIdx.x;
  if (kt == 7) {
    if (v < 56) {
      #pragma unroll
      for (int r = 0; r < 2; ++r) {
        int h = v * 2 + r;
        float val = (h < HID) ? W1[(size_t)c * HID + h] : 0.f;
        ((ushort*)((char*)ws + WS_W1T_B))[(size_t)h * 512 + c] = bfb(val);
      }
    } else {
      for (int e = c; e < 1024; e += 512) {
        int idx = (v - 56) * 1024 + e;
        int p = idx >> 7, h = idx & 127;
        float val = (p < KEEPED && h < HID) ? W2[(size_t)h * KEEPED + p] : 0.f;
        ((ushort*)((char*)ws + WS_W2T_B))[(size_t)p * 128 + h] = bfb(val);
      }
    }
    return;
  }
  float x[32];
  #pragma unroll
  for (int kk = 0; kk < 32; ++kk) {
    int tok = kt * 32 + kk;
    x[kk] = (tok < LV) ? img[((size_t)v * LV + tok) * CDIM + c] : 0.f;
  }
  __hip_bfloat16* imgT = (__hip_bfloat16*)((char*)ws + WS_IMGT_B);
  uint* dst = (uint*)(imgT + ((size_t)v * CDIM + c) * TOKPAD + kt * 32);
  #pragma unroll
  for (int g = 0; g < 4; ++g) {
    uint4 u;
    u.x = (uint)bfb(x[g*8+0]) | ((uint)bfb(x[g*8+1]) << 16);
    u.y = (uint)bfb(x[g*8+2]) | ((uint)bfb(x[g*8+3]) << 16);
    u.z = (uint)bfb(x[g*8+4]) | ((uint)bfb(x[g*8+5]) << 16);
    u.w = (uint)bfb(x[g*8+6]) | ((uint)bfb(x[g*8+7]) << 16);
    *(uint4*)(dst + g * 4) = u;
  }
}

// ---------------------------------------------------------------------------
// K5 (small path only): transpose W1 -> W1T, W2 -> W2T.
// ---------------------------------------------------------------------------
__global__ __launch_bounds__(512) void k5_prep(const float* __restrict__ W1,
                                               const float* __restrict__ W2,
                                               float* __restrict__ ws) {
  int b = blockIdx.x, tid = threadIdx.x;
  if (b < 112) {
    int h = b;
    float val = (h < HID) ? W1[(size_t)tid * HID + h] : 0.f;
    ((ushort*)((char*)ws + WS_W1T_B))[(size_t)h * 512 + tid] = bfb(val);
  } else {
    int p = b - 112;
    if (tid < 128) {
      int h = tid;
      float val = (p < KEEPED && h < HID) ? W2[(size_t)h * KEEPED + p] : 0.f;
      ((ushort*)((char*)ws + WS_W2T_B))[(size_t)p * 128 + h] = bfb(val);
    }
  }
}

// ---------------------------------------------------------------------------
// K1: cap_norm + cap_glo (blocks 0..31), img_glo (blocks 32..95). 256 thr.
// img branch wave-sliced (r7: 4 waves x 49-row slices into s_part).
// ---------------------------------------------------------------------------
__global__ __launch_bounds__(256) void k1_glo(const float* __restrict__ img,
                                              const float* __restrict__ cap,
                                              float* __restrict__ ws) {
  __shared__ float red[256];
  __shared__ float s_part[4 * CDIM];   // per-wave raw-sum partials
  __shared__ float s_glo[CDIM];
  int b = blockIdx.x, tid = threadIdx.x;
  if (b < BT) {
    int t = b;
    int wv = tid >> 6, lane = tid & 63;
    int cb = lane * 8;
    float4 sA = make_float4(0.f,0.f,0.f,0.f), sB = make_float4(0.f,0.f,0.f,0.f);
    for (int w = wv; w < NW; w += 4) {
      const float* p = cap + ((size_t)t * NW + w) * CDIM + cb;
      float4 xa = *(const float4*)p;
      float4 xb = *(const float4*)(p + 4);
      float ss = xa.x*xa.x + xa.y*xa.y + xa.z*xa.z + xa.w*xa.w
               + xb.x*xb.x + xb.y*xb.y + xb.z*xb.z + xb.w*xb.w;
      #pragma unroll
      for (int off = 32; off > 0; off >>= 1) ss += __shfl_xor(ss, off, 64);
      float inv = 1.f / fmaxf(sqrtf(ss), 1e-12f);
      float* q = ws + WS_CAPNORM + ((size_t)t * NW + w) * CDIM + cb;
      *(float4*)q       = make_float4(xa.x*inv, xa.y*inv, xa.z*inv, xa.w*inv);
      *(float4*)(q + 4) = make_float4(xb.x*inv, xb.y*inv, xb.z*inv, xb.w*inv);
      sA.x += xa.x; sA.y += xa.y; sA.z += xa.z; sA.w += xa.w;
      sB.x += xb.x; sB.y += xb.y; sB.z += xb.z; sB.w += xb.w;
    }
    *(float4*)&s_part[wv * CDIM + cb]     = sA;
    *(float4*)&s_part[wv * CDIM + cb + 4] = sB;
    __syncthreads();
    if (tid < 128) {
      float4 g = make_float4(0.f, 0.f, 0.f, 0.f);
      #pragma unroll
      for (int w2 = 0; w2 < 4; ++w2) {
        float4 pv = *(const float4*)&s_part[w2 * CDIM + tid * 4];
        g.x += pv.x; g.y += pv.y; g.z += pv.z; g.w += pv.w;
      }
      g.x /= (float)NW; g.y /= (float)NW; g.z /= (float)NW; g.w /= (float)NW;
      *(float4*)&s_glo[tid * 4] = g;
      red[tid] = g.x*g.x + g.y*g.y + g.z*g.z + g.w*g.w;
    }
    __syncthreads();
    for (int off = 64; off > 0; off >>= 1) {
      if (tid < off) red[tid] += red[tid + off];
      __syncthreads();
    }
    float inv = 1.f / fmaxf(sqrtf(red[0]), 1e-12f);
    if (tid < 128) {
      float4 g = *(const float4*)&s_glo[tid * 4];
      *(float4*)(ws + WS_CAPGLO + (size_t)t * CDIM + tid * 4) =
          make_float4(g.x*inv, g.y*inv, g.z*inv, g.w*inv);
    }
  } else {
    int v = b - BT;
    int wv = tid >> 6, lane = tid & 63;
    int cb = lane * 8;
    const float* base = img + (size_t)v * LV * CDIM;
    float4 sA = make_float4(0.f,0.f,0.f,0.f), sB = make_float4(0.f,0.f,0.f,0.f);
    int l0 = wv * 49;                         // 4 waves x 49 rows = 196
    for (int l = l0; l < l0 + 49; ++l) {
      const float* p = base + (size_t)l * CDIM + cb;
      float4 xa = *(const float4*)p;
      float4 xb = *(const float4*)(p + 4);
      sA.x += xa.x; sA.y += xa.y; sA.z += xa.z; sA.w += xa.w;
      sB.x += xb.x; sB.y += xb.y; sB.z += xb.z; sB.w += xb.w;
    }
    *(float4*)&s_part[wv * CDIM + cb]     = sA;
    *(float4*)&s_part[wv * CDIM + cb + 4] = sB;
    __syncthreads();
    if (tid < 128) {
      float4 g = make_float4(0.f, 0.f, 0.f, 0.f);
      #pragma unroll
      for (int w2 = 0; w2 < 4; ++w2) {
        float4 pv = *(const float4*)&s_part[w2 * CDIM + tid * 4];
        g.x += pv.x; g.y += pv.y; g.z += pv.z; g.w += pv.w;
      }
      g.x /= (float)LV; g.y /= (float)LV; g.z /= (float)LV; g.w /= (float)LV;
      *(float4*)&s_glo[tid * 4] = g;
      red[tid] = g.x*g.x + g.y*g.y + g.z*g.z + g.w*g.w;
    }
    __syncthreads();
    for (int off = 64; off > 0; off >>= 1) {
      if (tid < off) red[tid] += red[tid + off];
      __syncthreads();
    }
    float inv = 1.f / fmaxf(sqrtf(red[0]), 1e-12f);
    if (tid < 128) {
      float4 g = *(const float4*)&s_glo[tid * 4];
      *(float4*)(ws + WS_IMGGLO + (size_t)v * CDIM + tid * 4) =
          make_float4(g.x*inv, g.y*inv, g.z*inv, g.w*inv);
    }
  }
}

// ---------------------------------------------------------------------------
// K2: MFMA MLP. grid (64 v, 7 segs of 28 tokens), 512 thr (8 waves).
// LDS [32][520] bf16 = 33,280 B -> full-GPU grid + multi-block/CU.
// ---------------------------------------------------------------------------
__global__ __launch_bounds__(512, 4) void k2_mlp(const float* __restrict__ img,
                                                 const float* __restrict__ gamma,
                                                 const float* __restrict__ beta,
                                                 const float* __restrict__ b1,
                                                 const float* __restrict__ b2,
                                                 float* __restrict__ ws) {
  __shared__ __align__(16) __hip_bfloat16 s_xn[32 * XN_STR];  // 33,280 B
  __hip_bfloat16* s_hb = s_xn;                                // overlay after GEMM1

  int v = blockIdx.x, seg = blockIdx.y;
  int l0 = seg * 28;
  int tid = threadIdx.x, wv = tid >> 6, lane = tid & 63;
  int quad = lane >> 4, l15 = lane & 15, koff = quad * 8;
  const __hip_bfloat16* W1T = (const __hip_bfloat16*)((const char*)ws + WS_W1T_B);
  const __hip_bfloat16* W2T = (const __hip_bfloat16*)((const char*)ws + WS_W2T_B);

  // ---- Phase A: LN -> xn bf16 (28 tokens) ----
  int cb = lane * 8;
  float4 g4a = *(const float4*)(gamma + cb);
  float4 g4b = *(const float4*)(gamma + cb + 4);
  float4 b4a = *(const float4*)(beta + cb);
  float4 b4b = *(const float4*)(beta + cb + 4);
  for (int tok = wv; tok < 28; tok += 8) {
    const float* p = img + ((size_t)v * LV + l0 + tok) * CDIM + cb;
    float4 xa = *(const float4*)p;
    float4 xb = *(const float4*)(p + 4);
    float s  = xa.x + xa.y + xa.z + xa.w + xb.x + xb.y + xb.z + xb.w;
    float sq = xa.x*xa.x + xa.y*xa.y + xa.z*xa.z + xa.w*xa.w
             + xb.x*xb.x + xb.y*xb.y + xb.z*xb.z + xb.w*xb.w;
    #pragma unroll
    for (int off = 32; off > 0; off >>= 1) { s += __shfl_xor(s, off, 64); sq += __shfl_xor(sq, off, 64); }
    float mean = s / (float)CDIM;
    float var = sq / (float)CDIM - mean * mean;
    float rstd = 1.f / sqrtf(var + LN_EPS_);
    if (lane == 0) ws[WS_INVN + (size_t)v * LV + l0 + tok] = 1.f / fmaxf(sqrtf(sq), 1e-12f);
    float f[8];
    f[0] = (xa.x - mean) * rstd * g4a.x + b4a.x;
    f[1] = (xa.y - mean) * rstd * g4a.y + b4a.y;
    f[2] = (xa.z - mean) * rstd * g4a.z + b4a.z;
    f[3] = (xa.w - mean) * rstd * g4a.w + b4a.w;
    f[4] = (xb.x - mean) * rstd * g4b.x + b4b.x;
    f[5] = (xb.y - mean) * rstd * g4b.y + b4b.y;
    f[6] = (xb.z - mean) * rstd * g4b.z + b4b.z;
    f[7] = (xb.w - mean) * rstd * g4b.w + b4b.w;
    uint4 u;
    u.x = (uint)bfb(f[0]) | ((uint)bfb(f[1]) << 16);
    u.y = (uint)bfb(f[2]) | ((uint)bfb(f[3]) << 16);
    u.z = (uint)bfb(f[4]) | ((uint)bfb(f[5]) << 16);
    u.w = (uint)bfb(f[6]) | ((uint)bfb(f[7]) << 16);
    *(uint4*)(s_xn + (size_t)tok * XN_STR + cb) = u;
  }
  __syncthreads();

  // ---- GEMM1: C[32 tok][112 h], 2x7 = 14 tiles over 8 waves ----
  v4f c1[2];
  int mt_[2], nt_[2];
  #pragma unroll
  for (int i = 0; i < 2; ++i) {
    int idx = wv + 8 * i; if (idx > 13) idx = 13;   // clamp: keep reads in-bounds
    mt_[i] = idx / 7; nt_[i] = idx % 7;
    c1[i] = (v4f){0.f, 0.f, 0.f, 0.f};
  }
  for (int ks = 0; ks < 16; ++ks) {
    #pragma unroll
    for (int i = 0; i < 2; ++i) {
      v8s a  = *(const v8s*)(s_xn + (size_t)(mt_[i] * 16 + l15) * XN_STR + ks * 32 + koff);
      v8s bb = *(const v8s*)(W1T + (size_t)(nt_[i] * 16 + l15) * 512 + ks * 32 + koff);
      c1[i] = MFMA16(a, bb, c1[i]);
    }
  }
  __syncthreads();   // all xn reads complete before hbuf overlay

  // ---- gelu + bias -> hbuf [32][136] ----
  #pragma unroll
  for (int i = 0; i < 2; ++i) {
    int idx = wv + 8 * i;
    if (idx < 14) {
      int h = nt_[i] * 16 + l15;
      float bias = (h < HID) ? b1[h] : 0.f;
      #pragma unroll
      for (int reg = 0; reg < 4; ++reg) {
        int row = mt_[i] * 16 + quad * 4 + reg;
        float x = c1[i][reg] + bias;
        float gl = (h < HID) ? 0.5f * x * (1.f + erff(x * 0.70710678118654752f)) : 0.f;
        s_hb[(size_t)row * HB_STR + h] = __float2bfloat16(gl);
      }
    }
  }
  for (int i = tid; i < 32 * 16; i += 512)   // zero cols 112..127 (K pad)
    s_hb[(size_t)(i >> 4) * HB_STR + 112 + (i & 15)] = __float2bfloat16(0.f);
  __syncthreads();

  // ---- GEMM2: C[32 tok][64 p], 2x4 = 8 tiles = 1/wave, K=128 ----
  int m2 = wv >> 2, n2 = wv & 3;
  v4f c2 = (v4f){0.f, 0.f, 0.f, 0.f};
  for (int ks = 0; ks < 4; ++ks) {
    v8s a  = *(const v8s*)(s_hb + (size_t)(m2 * 16 + l15) * HB_STR + ks * 32 + koff);
    v8s bb = *(const v8s*)(W2T + (size_t)(n2 * 16 + l15) * 128 + ks * 32 + koff);
    c2 = MFMA16(a, bb, c2);
  }
  {
    int p = n2 * 16 + l15;
    if (p < KEEPED) {
      float bias = b2[p];
      #pragma unroll
      for (int reg = 0; reg < 4; ++reg) {
        int tok = m2 * 16 + quad * 4 + reg;
        if (tok < 28)
          ws[WS_WLOG + ((size_t)v * LV + l0 + tok) * KEEPED + p] = c2[reg] + bias;
      }
    }
  }
}

// ---------------------------------------------------------------------------
// K3: scores. 512 threads (r7): queries split 8-way (q = qg + 8*qi, qi<5).
// ---------------------------------------------------------------------------
__global__ __launch_bounds__(512) void k3_score(const float* __restrict__ img,
                                                float* __restrict__ ws) {
  __shared__ float qt[33 * 64];
  __shared__ float xt[64 * 65];
  __shared__ float dself[64];
  int v = blockIdx.x;
  int t0 = blockIdx.y * 64;
  int tid = threadIdx.x;
  int tloc = tid & 63, qg = tid >> 6;   // qg 0..7
  float acc[5];
  #pragma unroll
  for (int i = 0; i < 5; ++i) acc[i] = 0.f;
  const float* capglo = ws + WS_CAPGLO;
  const float* imgglo = ws + WS_IMGGLO + (size_t)v * CDIM;

  for (int ct = 0; ct < 8; ++ct) {
    for (int i = tid; i < 33 * 64; i += 512) {
      int q = i >> 6, cc = i & 63;
      qt[i] = (q < 32) ? capglo[(size_t)q * CDIM + ct * 64 + cc] : imgglo[ct * 64 + cc];
    }
    for (int i = tid; i < 64 * 64; i += 512) {
      int tok = i >> 6, cc = i & 63;
      int l = t0 + tok;
      xt[tok * 65 + cc] = (l < LV) ? img[((size_t)v * LV + l) * CDIM + ct * 64 + cc] : 0.f;
    }
    __syncthreads();
    for (int cc = 0; cc < 64; ++cc) {
      float xv = xt[tloc * 65 + cc];
      #pragma unroll
      for (int qi = 0; qi < 5; ++qi) {
        int q = qg + 8 * qi;
        if (q < 33) acc[qi] += qt[q * 64 + cc] * xv;
      }
    }
    __syncthreads();
  }
  if (qg == 0) dself[tloc] = acc[4];    // q = 0 + 8*4 = 32 (self query)
  __syncthreads();
  int l = t0 + tloc;
  if (l < LV) {
    float invn = ws[WS_INVN + (size_t)v * LV + l];
    float ds = dself[tloc];
    #pragma unroll
    for (int qi = 0; qi < 5; ++qi) {
      int q = qg + 8 * qi;
      if (q < 32) ws[WS_SCORE + ((size_t)q * BV + v) * LV + l] = (acc[qi] + ds) * invn;
    }
  }
}

// ---------------------------------------------------------------------------
// K4 fallback (small ws): verbatim old template, only <0> instantiated.
// ---------------------------------------------------------------------------
template<int USE_IMGT>
__global__ __launch_bounds__(512, 2) void k4_main(const float* __restrict__ img,
                                                  const float* __restrict__ scale_p,
                                                  const float* __restrict__ ws,
                                                  float* __restrict__ out) {
  __shared__ float s_sc[LV];
  __shared__ int   s_kidx[NKEEP];
  __shared__ int   s_nidx[NNON];
  __shared__ int   s_cnt[2];
  __shared__ float s_wk[NNON];
  __shared__ float s_red[128];
  __shared__ float s_pool2[64];
  __shared__ float s_inv[64];
  __shared__ __align__(16) __hip_bfloat16 s_selh[64 * SEL_STR];
  __shared__ __align__(16) __hip_bfloat16 s_wa[64 * WA_STR];
  __shared__ __align__(16) __hip_bfloat16 s_dyn[512 * TOK_STR];

  float* s_w = (float*)s_dyn;
  __hip_bfloat16* s_tok = s_dyn;
  __hip_bfloat16* s_cap = s_dyn;
  float* s_sims = (float*)s_wa;
  float* s_G = (float*)((char*)s_wa + 8192);

  int b = blockIdx.x;
  int v = b >> 5, t = b & 31;
  int tid = threadIdx.x;
  int wv = tid >> 6, lane = tid & 63;
  int quad = lane >> 4, l15 = lane & 15;
  int koff = quad * 8;

  if (tid < 2) s_cnt[tid] = 0;
  if (tid < 64) s_pool2[tid] = 0.f;
  if (tid < LV) s_sc[tid] = ws[WS_SCORE + ((size_t)t * BV + v) * LV + tid];
  {
    uint* za = (uint*)s_wa;
    for (int i = tid; i < 64 * WA_STR / 2; i += 512) za[i] = 0u;
    uint* zs = (uint*)(s_selh + 50 * SEL_STR);
    for (int i = tid; i < 14 * SEL_STR / 2; i += 512) zs[i] = 0u;
  }
  __syncthreads();

  if (tid < LV) {
    float my = s_sc[tid];
    int cnt = 0;
    for (int j = 0; j < LV; ++j) {
      float sj = s_sc[j];
      cnt += (sj > my) || (sj == my && j < tid);
    }
    bool keep = cnt < NKEEP;
    out[BV * BT + ((size_t)t * BV + v) * LV + tid] = keep ? 1.f : 0.f;
    if (keep) { int p = atomicAdd(&s_cnt[0], 1); s_kidx[p] = tid; }
    else      { int p = atomicAdd(&s_cnt[1], 1); s_nidx[p] = tid; }
  }
  __syncthreads();

  if (tid < 128) s_red[tid] = (tid < NNON) ? s_sc[s_nidx[tid]] : -3.0e38f;
  __syncthreads();
  for (int off = 64; off > 0; off >>= 1) {
    if (tid < off) s_red[tid] = fmaxf(s_red[tid], s_red[tid + off]);
    __syncthreads();
  }
  float nm = s_red[0];
  __syncthreads();
  float e0 = 0.f;
  if (tid < NNON) e0 = expf(s_sc[s_nidx[tid]] - nm);
  if (tid < 128) s_red[tid] = (tid < NNON) ? e0 : 0.f;
  __syncthreads();
  for (int off = 64; off > 0; off >>= 1) {
    if (tid < off) s_red[tid] += s_red[tid + off];
    __syncthreads();
  }
  float nS = s_red[0];
  __syncthreads();
  if (tid < NNON) s_wk[tid] = e0 / nS;
  __syncthreads();

  float scale_val = scale_p[0];
  for (int i = tid; i < KEEPED * NKEEP; i += 512) {
    int k = i / KEEPED, p = i - k * KEEPED;
    s_w[p * NKEEP + k] = ws[WS_WLOG + ((size_t)v * LV + s_kidx[k]) * KEEPED + p] * scale_val;
  }
  __syncthreads();
  if (tid < KEEPED * 8) {
    int p = tid >> 3, g = tid & 7;
    float mm = -3e38f;
    for (int k = g; k < NKEEP; k += 8) mm = fmaxf(mm, s_w[p * NKEEP + k]);
    #pragma unroll
    for (int off = 4; off > 0; off >>= 1) mm = fmaxf(mm, __shfl_xor(mm, off, 8));
    float ss = 0.f;
    for (int k = g; k < NKEEP; k += 8) {
      float ee = expf(s_w[p * NKEEP + k] - mm);
      s_w[p * NKEEP + k] = ee;
      ss += ee;
    }
    #pragma unroll
    for (int off = 4; off > 0; off >>= 1) ss += __shfl_xor(ss, off, 8);
    float rs = 1.f / ss;
    for (int k = g; k < NKEEP; k += 8) s_w[p * NKEEP + k] *= rs;
  }
  __syncthreads();

  for (int i = tid; i < KEEPED * NKEEP; i += 512) {
    int p = i / NKEEP, r = i - p * NKEEP;
    s_wa[p * WA_STR + s_kidx[r]] = __float2bfloat16(s_w[p * NKEEP + r]);
  }
  if (tid < NNON) s_wa[49 * WA_STR + s_nidx[tid]] = __float2bfloat16(s_wk[tid]);
  __syncthreads();

  v4f acc[4][4];
  #pragma unroll
  for (int m = 0; m < 4; ++m)
    #pragma unroll
    for (int j = 0; j < 4; ++j) acc[m][j] = (v4f){0.f, 0.f, 0.f, 0.f};

  if (USE_IMGT) {
    const __hip_bfloat16* imgTv =
        (const __hip_bfloat16*)((const char*)ws + WS_IMGT_B) + (size_t)v * CDIM * TOKPAD;
    for (int ks = 0; ks < 7; ++ks) {
      v8s bfr[4];
      #pragma unroll
      for (int j = 0; j < 4; ++j)
        bfr[j] = *(const v8s*)(imgTv + (size_t)(wv * 64 + j * 16 + l15) * TOKPAD + ks * 32 + koff);
      #pragma unroll
      for (int m = 0; m < 4; ++m) {
        v8s af = *(const v8s*)(s_wa + (m * 16 + l15) * WA_STR + ks * 32 + koff);
        #pragma unroll
        for (int j = 0; j < 4; ++j) acc[m][j] = MFMA16(af, bfr[j], acc[m][j]);
      }
    }
  } else {
    for (int ks = 0; ks < 7; ++ks) {
      #pragma unroll
      for (int it = 0; it < 8; ++it) {
        int k0 = ks * 32 + it * 4;
        if (k0 < LV) {
          const float* gp = img + ((size_t)v * LV + k0) * CDIM + tid;
          float x0 = gp[0], x1 = gp[CDIM], x2 = gp[2 * CDIM], x3 = gp[3 * CDIM];
          union { __hip_bfloat16 h[4]; uint2 u; } pk;
          pk.h[0] = __float2bfloat16(x0); pk.h[1] = __float2bfloat16(x1);
          pk.h[2] = __float2bfloat16(x2); pk.h[3] = __float2bfloat16(x3);
          *(uint2*)(s_tok + tid * TOK_STR + it * 4) = pk.u;
        }
      }
      __syncthreads();
      v8s bfr[4];
      #pragma unroll
      for (int j = 0; j < 4; ++j)
        bfr[j] = *(const v8s*)(s_tok + (wv * 64 + j * 16 + l15) * TOK_STR + koff);
      #pragma unroll
      for (int m = 0; m < 4; ++m) {
        v8s af = *(const v8s*)(s_wa + (m * 16 + l15) * WA_STR + ks * 32 + koff);
        #pragma unroll
        for (int j = 0; j < 4; ++j) acc[m][j] = MFMA16(af, bfr[j], acc[m][j]);
      }
      __syncthreads();
    }
  }

  if (!USE_IMGT) __syncthreads();
  for (int i = tid; i < NW * 128; i += 512) {
    int w = i >> 7, cq = i & 127;
    const float4 xv = *(const float4*)(ws + WS_CAPNORM + ((size_t)t * NW + w) * CDIM + cq * 4);
    union { __hip_bfloat16 h[4]; uint2 u; } pk;
    pk.h[0] = __float2bfloat16(xv.x); pk.h[1] = __float2bfloat16(xv.y);
    pk.h[2] = __float2bfloat16(xv.z); pk.h[3] = __float2bfloat16(xv.w);
    *(uint2*)(s_cap + w * SEL_STR + cq * 4) = pk.u;
  }
  {
    uint* zc = (uint*)(s_cap + 24 * SEL_STR);
    for (int i = tid; i < 8 * SEL_STR / 2; i += 512) zc[i] = 0u;
  }
  #pragma unroll
  for (int m = 0; m < 4; ++m) {
    #pragma unroll
    for (int reg = 0; reg < 4; ++reg) {
      float ss = acc[m][0][reg] * acc[m][0][reg] + acc[m][1][reg] * acc[m][1][reg]
               + acc[m][2][reg] * acc[m][2][reg] + acc[m][3][reg] * acc[m][3][reg];
      #pragma unroll
      for (int off = 8; off > 0; off >>= 1) ss += __shfl_xor(ss, off, 64);
      if (l15 == 0) atomicAdd(&s_pool2[m * 16 + quad * 4 + reg], ss);
    }
  }
  __syncthreads();
  if (tid < 64) s_inv[tid] = 1.f / fmaxf(sqrtf(s_pool2[tid]), 1e-12f);
  __syncthreads();
  #pragma unroll
  for (int m = 0; m < 4; ++m) {
    #pragma unroll
    for (int reg = 0; reg < 4; ++reg) {
      int p = m * 16 + quad * 4 + reg;
      if (p < 50) {
        float iv = s_inv[p];
        #pragma unroll
        for (int j = 0; j < 4; ++j)
          s_selh[p * SEL_STR + wv * 64 + j * 16 + l15] = __float2bfloat16(acc[m][j][reg] * iv);
      }
    }
  }
  __syncthreads();

  {
    int mt = wv >> 2, nt = wv & 3;
    v4f sa = (v4f){0.f, 0.f, 0.f, 0.f};
    for (int ks = 0; ks < 16; ++ks) {
      v8s a = *(const v8s*)(s_cap + (mt * 16 + l15) * SEL_STR + ks * 32 + koff);
      v8s bb = *(const v8s*)(s_selh + (nt * 16 + l15) * SEL_STR + ks * 32 + koff);
      sa = MFMA16(a, bb, sa);
    }
    #pragma unroll
    for (int reg = 0; reg < 4; ++reg)
      s_sims[(mt * 16 + quad * 4 + reg) * 64 + nt * 16 + l15] = sa[reg];
  }
  __syncthreads();

  if (tid < NW * 8) {
    int w = tid >> 3, g = tid & 7;
    float* row = s_sims + w * 64;
    float mm = -3e38f;
    for (int p = g; p < 50; p += 8) mm = fmaxf(mm, row[p]);
    #pragma unroll
    for (int off = 4; off > 0; off >>= 1) mm = fmaxf(mm, __shfl_xor(mm, off, 8));
    float num = 0.f;
    for (int p = g; p < 64; p += 8) {
      if (p < 50) {
        float s = row[p];
        float ee = expf(LAMBDA_ * (s - mm));
        num += ee * s;
        row[p] = ee;
      } else row[p] = 0.f;
    }
    #pragma unroll
    for (int off = 4; off > 0; off >>= 1) num += __shfl_xor(num, off, 8);
    if (g == 0) s_red[w] = num;
  }
  __syncthreads();

  #pragma unroll
  for (int i2 = 0; i2 < 2; ++i2) {
    int idx = wv * 2 + i2;
    int gm = idx >> 2, gn = idx & 3;
    v4f ga = (v4f){0.f, 0.f, 0.f, 0.f};
    for (int ks = 0; ks < 16; ++ks) {
      v8s a = *(const v8s*)(s_selh + (gm * 16 + l15) * SEL_STR + ks * 32 + koff);
      v8s bb = *(const v8s*)(s_selh + (gn * 16 + l15) * SEL_STR + ks * 32 + koff);
      ga = MFMA16(a, bb, ga);
    }
    #pragma unroll
    for (int reg = 0; reg < 4; ++reg)
      s_G[(gm * 16 + quad * 4 + reg) * G_STR + gn * 16 + l15] = ga[reg];
  }
  __syncthreads();

  float wacc = 0.f;
  for (int w = wv; w < NW; w += 8) {
    const float* ev = s_sims + w * 64;
    float tl = 0.f;
    for (int q = 0; q < 50; ++q) tl += s_G[q * G_STR + lane] * ev[q];
    float ql = ev[lane] * tl;
    #pragma unroll
    for (int off = 32; off > 0; off >>= 1) ql += __shfl_xor(ql, off, 64);
    if (lane == 0) wacc += s_red[w] / fmaxf(sqrtf(ql), 1e-20f);
  }
  if (lane == 0) s_red[64 + wv] = wacc;
  __syncthreads();
  if (tid == 0) {
    float s = 0.f;
    #pragma unroll
    for (int i = 0; i < 8; ++i) s += s_red[64 + i];
    out[(size_t)v * BT + t] = s / (float)NW;
  }
}

// ---------------------------------------------------------------------------
// K4 big path (R15): R12 body (155 us measured) + XCD-aware block swizzle.
// Swizzle: newb = (b&7)*256 + b>>3 (bijective, 2048%8==0). Assuming XCD =
// blockIdx%8 round-robin, XCD r then owns v in [8r, 8r+8) -> its 8 imgT
// slices (1.8 MB) fit the 4 MB per-XCD L2 -> P5/P3 loads become L2 hits,
// FETCH_SIZE should drop 68 MB -> ~25-35 MB. Pure permutation: correctness
// unaffected regardless of actual XCD mapping.
// ---------------------------------------------------------------------------
__global__ __launch_bounds__(512, 4) void k4_big(const float* __restrict__ img,
                                                 const float* __restrict__ scale_p,
                                                 const float* __restrict__ ws,
                                                 float* __restrict__ out) {
  __shared__ __align__(16) char smem[K4_SMEM];
  __hip_bfloat16* s_sel = (__hip_bfloat16*)(smem + OFF_SEL);   // [64][136] quarter
  float*          s_w   = (float*)(smem + OFF_SEL);            // overlay, P3/P4 only
  __hip_bfloat16* s_wa  = (__hip_bfloat16*)(smem + OFF_WA);    // [64][232] P4->P5
  __hip_bfloat16* s_capq= (__hip_bfloat16*)(smem + OFF_CAPQ);  // [24][136] loop only
  float*          s_sims= (float*)(smem + OFF_SIMS);           // [32][64] after loop
  float*          s_G   = (float*)(smem + OFF_G);              // [64][66] after loop
  float* s_sc    = (float*)(smem + OFF_SC);
  int*   s_kidx  = (int*)(smem + OFF_KIDX);
  int*   s_nidx  = (int*)(smem + OFF_NIDX);
  int*   s_cnt   = (int*)(smem + OFF_CNT);
  float* s_wk    = (float*)(smem + OFF_WK);
  float* s_red   = (float*)(smem + OFF_RED);
  float* s_pool2 = (float*)(smem + OFF_POOL2);
  float* s_inv   = (float*)(smem + OFF_INV);

  int b0 = blockIdx.x;
  int b = ((b0 & 7) << 8) | (b0 >> 3);   // XCD swizzle: same-v blocks co-locate
  int v = b >> 5, t = b & 31;
  int tid = threadIdx.x;
  int wv = tid >> 6, lane = tid & 63;
  int quad = lane >> 4, l15 = lane & 15;
  int koff = quad * 8;

  // ---- P0: loads + zero-init ----
  if (tid < 2) s_cnt[tid] = 0;
  if (tid < 64) s_pool2[tid] = 0.f;
  if (tid < LV) s_sc[tid] = ws[WS_SCORE + ((size_t)t * BV + v) * LV + tid];
  {
    uint* za = (uint*)s_wa;
    for (int i = tid; i < 64 * WA_STR / 2; i += 512) za[i] = 0u;
  }
  __syncthreads();

  // ---- P1: rank & partition ----
  if (tid < LV) {
    float my = s_sc[tid];
    int cnt = 0;
    for (int j = 0; j < LV; ++j) {
      float sj = s_sc[j];
      cnt += (sj > my) || (sj == my && j < tid);
    }
    bool keep = cnt < NKEEP;
    out[BV * BT + ((size_t)t * BV + v) * LV + tid] = keep ? 1.f : 0.f;
    if (keep) { int p = atomicAdd(&s_cnt[0], 1); s_kidx[p] = tid; }
    else      { int p = atomicAdd(&s_cnt[1], 1); s_nidx[p] = tid; }
  }
  __syncthreads();

  // ---- P2: softmax over non-kept scores -> s_wk ----
  if (tid < 128) s_red[tid] = (tid < NNON) ? s_sc[s_nidx[tid]] : -3.0e38f;
  __syncthreads();
  for (int off = 64; off > 0; off >>= 1) {
    if (tid < off) s_red[tid] = fmaxf(s_red[tid], s_red[tid + off]);
    __syncthreads();
  }
  float nm = s_red[0];
  __syncthreads();
  float e0 = 0.f;
  if (tid < NNON) e0 = expf(s_sc[s_nidx[tid]] - nm);
  if (tid < 128) s_red[tid] = (tid < NNON) ? e0 : 0.f;
  __syncthreads();
  for (int off = 64; off > 0; off >>= 1) {
    if (tid < off) s_red[tid] += s_red[tid + off];
    __syncthreads();
  }
  float nS = s_red[0];
  __syncthreads();
  if (tid < NNON) s_wk[tid] = e0 / nS;
  __syncthreads();

  // ---- P3: wlog gather -> s_w[p][r] fp32 (overlays sel region), softmax ----
  float scale_val = scale_p[0];
  for (int i = tid; i < KEEPED * NKEEP; i += 512) {
    int k = i / KEEPED, p = i - k * KEEPED;
    s_w[p * NKEEP + k] = ws[WS_WLOG + ((size_t)v * LV + s_kidx[k]) * KEEPED + p] * scale_val;
  }
  __syncthreads();
  if (tid < KEEPED * 8) {
    int p = tid >> 3, g = tid & 7;
    float mm = -3e38f;
    for (int k = g; k < NKEEP; k += 8) mm = fmaxf(mm, s_w[p * NKEEP + k]);
    #pragma unroll
    for (int off = 4; off > 0; off >>= 1) mm = fmaxf(mm, __shfl_xor(mm, off, 8));
    float ss = 0.f;
    for (int k = g; k < NKEEP; k += 8) {
      float ee = expf(s_w[p * NKEEP + k] - mm);
      s_w[p * NKEEP + k] = ee;
      ss += ee;
    }
    #pragma unroll
    for (int off = 4; off > 0; off >>= 1) ss += __shfl_xor(ss, off, 8);
    float rs = 1.f / ss;
    for (int k = g; k < NKEEP; k += 8) s_w[p * NKEEP + k] *= rs;
  }
  __syncthreads();

  // ---- P4: scatter A = s_wa (bf16): kept weights + wk row 49 ----
  for (int i = tid; i < KEEPED * NKEEP; i += 512) {
    int p = i / NKEEP, r = i - p * NKEEP;
    s_wa[p * WA_STR + s_kidx[r]] = __float2bfloat16(s_w[p * NKEEP + r]);
  }
  if (tid < NNON) s_wa[49 * WA_STR + s_nidx[tid]] = __float2bfloat16(s_wk[tid]);
  __syncthreads();

  // zero sel-quarter rows 50..63 (s_w dead after the barrier above; rows stay
  // zero across all four quarters — nobody writes p >= 50)
  {
    uint* zq = (uint*)(s_sel + 50 * SELQ_STR);
    for (int i = tid; i < 14 * SELQ_STR / 2; i += 512) zq[i] = 0u;
  }

  // ---- P5: aggr GEMM, B from global imgT ----
  v4f acc[4][4];
  #pragma unroll
  for (int m = 0; m < 4; ++m)
    #pragma unroll
    for (int j = 0; j < 4; ++j) acc[m][j] = (v4f){0.f, 0.f, 0.f, 0.f};

  {
    const __hip_bfloat16* imgTv =
        (const __hip_bfloat16*)((const char*)ws + WS_IMGT_B) + (size_t)v * CDIM * TOKPAD;
    for (int ks = 0; ks < 7; ++ks) {
      v8s bfr[4];
      #pragma unroll
      for (int j = 0; j < 4; ++j)
        bfr[j] = *(const v8s*)(imgTv + (size_t)(wv * 64 + j * 16 + l15) * TOKPAD + ks * 32 + koff);
      #pragma unroll
      for (int m = 0; m < 4; ++m) {
        v8s af = *(const v8s*)(s_wa + (m * 16 + l15) * WA_STR + ks * 32 + koff);
        #pragma unroll
        for (int j = 0; j < 4; ++j) acc[m][j] = MFMA16(af, bfr[j], acc[m][j]);
      }
    }
  }

  // ---- P6: pool l2norm (atomics into zeroed s_pool2) ----
  #pragma unroll
  for (int m = 0; m < 4; ++m) {
    #pragma unroll
    for (int reg = 0; reg < 4; ++reg) {
      float ss = acc[m][0][reg] * acc[m][0][reg] + acc[m][1][reg] * acc[m][1][reg]
               + acc[m][2][reg] * acc[m][2][reg] + acc[m][3][reg] * acc[m][3][reg];
      #pragma unroll
      for (int off = 8; off > 0; off >>= 1) ss += __shfl_xor(ss, off, 64);
      if (l15 == 0) atomicAdd(&s_pool2[m * 16 + quad * 4 + reg], ss);
    }
  }
  __syncthreads();
  if (tid < 64) s_inv[tid] = 1.f / fmaxf(sqrtf(s_pool2[tid]), 1e-12f);
  __syncthreads();

  // ---- pack normalized sel fragments: 64 f32 -> 32 uints (bf16 pairs) ----
  uint pk[4][4][2];
  #pragma unroll
  for (int m = 0; m < 4; ++m) {
    #pragma unroll
    for (int rp = 0; rp < 2; ++rp) {
      int p0 = m * 16 + quad * 4 + rp * 2;
      float iv0 = s_inv[p0], iv1 = s_inv[p0 + 1];
      #pragma unroll
      for (int j = 0; j < 4; ++j)
        pk[m][j][rp] = (uint)bfb(acc[m][j][2 * rp] * iv0)
                     | ((uint)bfb(acc[m][j][2 * rp + 1] * iv1) << 16);
    }
  }

  // ---- quarter loop: stage sel cols [q*128, q*128+128) (waves 2q,2q+1) and
  // cap quarter [24][128] (other 6 waves) in LDS; accumulate P7+P9.
  // capq garbage rows 24..31 (stale wa bf16, finite) feed sims rows 24..31,
  // which are never read (P8/P10 use w < 24 only).
  v4f sa = (v4f){0.f, 0.f, 0.f, 0.f};
  v4f ga[2];
  ga[0] = (v4f){0.f, 0.f, 0.f, 0.f};
  ga[1] = (v4f){0.f, 0.f, 0.f, 0.f};
  ushort* selw = (ushort*)s_sel;
  int mt = wv >> 2, nt = wv & 3;
  for (int q = 0; q < 4; ++q) {
    if ((wv >> 1) == q) {               // waves 2q, 2q+1 own cols q*128..+127
      int base = (wv & 1) * 64;
      #pragma unroll
      for (int m = 0; m < 4; ++m) {
        #pragma unroll
        for (int reg = 0; reg < 4; ++reg) {
          int p = m * 16 + quad * 4 + reg;
          if (p < 50) {
            #pragma unroll
            for (int j = 0; j < 4; ++j) {
              uint u = pk[m][j][reg >> 1];
              ushort val = (reg & 1) ? (ushort)(u >> 16) : (ushort)(u & 0xffffu);
              selw[p * SELQ_STR + base + j * 16 + l15] = val;
            }
          }
        }
      }
    } else {
      int rank = wv - (wv > 2 * q + 1 ? 2 : 0);   // 0..5 among 6 staging waves
      int lt = rank * 64 + lane;                  // 0..383
      for (int i = lt; i < NW * 32; i += 384) {
        int w = i >> 5, c4 = i & 31;
        float4 xv = *(const float4*)(ws + WS_CAPNORM + ((size_t)t * NW + w) * CDIM
                                     + q * 128 + c4 * 4);
        union { __hip_bfloat16 hh[4]; uint2 u; } pc;
        pc.hh[0] = __float2bfloat16(xv.x); pc.hh[1] = __float2bfloat16(xv.y);
        pc.hh[2] = __float2bfloat16(xv.z); pc.hh[3] = __float2bfloat16(xv.w);
        *(uint2*)(s_capq + w * CAPQ_STR + c4 * 4) = pc.u;
      }
    }
    __syncthreads();
    // P7 partial: sims += cap_quarter . sel_quarter^T
    #pragma unroll
    for (int ks = 0; ks < 4; ++ks) {
      v8s a  = *(const v8s*)(s_capq + (mt * 16 + l15) * CAPQ_STR + ks * 32 + koff);
      v8s bb = *(const v8s*)(s_sel + (nt * 16 + l15) * SELQ_STR + ks * 32 + koff);
      sa = MFMA16(a, bb, sa);
    }
    // P9 partial: G += sel_quarter . sel_quarter^T
    #pragma unroll
    for (int i2 = 0; i2 < 2; ++i2) {
      int idx = wv * 2 + i2;
      int gm = idx >> 2, gn = idx & 3;
      #pragma unroll
      for (int ks = 0; ks < 4; ++ks) {
        v8s a  = *(const v8s*)(s_sel + (gm * 16 + l15) * SELQ_STR + ks * 32 + koff);
        v8s bb = *(const v8s*)(s_sel + (gn * 16 + l15) * SELQ_STR + ks * 32 + koff);
        ga[i2] = MFMA16(a, bb, ga[i2]);
      }
    }
    __syncthreads();
  }

  // ---- write sims + G (overwrites capq/wa region, both dead now) ----
  #pragma unroll
  for (int reg = 0; reg < 4; ++reg)
    s_sims[(mt * 16 + quad * 4 + reg) * 64 + nt * 16 + l15] = sa[reg];
  #pragma unroll
  for (int i2 = 0; i2 < 2; ++i2) {
    int idx = wv * 2 + i2;
    int gm = idx >> 2, gn = idx & 3;
    #pragma unroll
    for (int reg = 0; reg < 4; ++reg)
      s_G[(gm * 16 + quad * 4 + reg) * G_STR + gn * 16 + l15] = ga[i2][reg];
  }
  __syncthreads();

  // ---- P8: per-word softmax (unnormalized e) + num = sum e*s ----
  if (tid < NW * 8) {
    int w = tid >> 3, g = tid & 7;
    float* row = s_sims + w * 64;
    float mm = -3e38f;
    for (int p = g; p < 50; p += 8) mm = fmaxf(mm, row[p]);
    #pragma unroll
    for (int off = 4; off > 0; off >>= 1) mm = fmaxf(mm, __shfl_xor(mm, off, 8));
    float num = 0.f;
    for (int p = g; p < 64; p += 8) {
      if (p < 50) {
        float s = row[p];
        float ee = expf(LAMBDA_ * (s - mm));
        num += ee * s;
        row[p] = ee;
      } else row[p] = 0.f;
    }
    #pragma unroll
    for (int off = 4; off > 0; off >>= 1) num += __shfl_xor(num, off, 8);
    if (g == 0) s_red[w] = num;
  }
  __syncthreads();

  // ---- P10: word_sim = num / sqrt(e^T G e); mean over words ----
  float wacc = 0.f;
  for (int w = wv; w < NW; w += 8) {
    const float* ev = s_sims + w * 64;
    float tl = 0.f;
    for (int q = 0; q < 50; ++q) tl += s_G[q * G_STR + lane] * ev[q];
    float ql = ev[lane] * tl;
    #pragma unroll
    for (int off = 32; off > 0; off >>= 1) ql += __shfl_xor(ql, off, 64);
    if (lane == 0) wacc += s_red[w] / fmaxf(sqrtf(ql), 1e-20f);
  }
  if (lane == 0) s_red[64 + wv] = wacc;
  __syncthreads();
  if (tid == 0) {
    float s = 0.f;
    #pragma unroll
    for (int i = 0; i < 8; ++i) s += s_red[64 + i];
    out[(size_t)v * BT + t] = s / (float)NW;
  }
}

// ---------------------------------------------------------------------------
extern "C" void kernel_launch(void* const* d_in, const int* in_sizes, int n_in,
                              void* d_out, int out_size, void* d_ws, size_t ws_size,
                              hipStream_t stream) {
  const float* img   = (const float*)d_in[0];
  const float* cap   = (const float*)d_in[1];
  // d_in[2] = cap_lens (unused by forward)
  const float* gamma = (const float*)d_in[3];
  const float* beta  = (const float*)d_in[4];
  const float* W1    = (const float*)d_in[5];
  const float* b1    = (const float*)d_in[6];
  const float* W2    = (const float*)d_in[7];
  const float* b2    = (const float*)d_in[8];
  const float* scale = (const float*)d_in[9];
  float* ws  = (float*)d_ws;
  float* out = (float*)d_out;

  const bool big = (ws_size >= WS_NEED_B);   // constant across calls -> graph-safe

  if (big) k0_prep<<<dim3(BV, 8), dim3(512), 0, stream>>>(img, W1, W2, ws);
  else     k5_prep<<<dim3(176), dim3(512), 0, stream>>>(W1, W2, ws);
  k1_glo <<<dim3(BT + BV), dim3(256), 0, stream>>>(img, cap, ws);
  k2_mlp <<<dim3(BV, 7), dim3(512), 0, stream>>>(img, gamma, beta, b1, b2, ws);
  k3_score<<<dim3(BV, 4), dim3(512), 0, stream>>>(img, ws);
  if (big) k4_big<<<dim3(BV * BT), dim3(512), 0, stream>>>(img, scale, ws, out);
  else     k4_main<0><<<dim3(BV * BT), dim3(512), 0, stream>>>(img, scale, ws, out);
}

// Round 9
// 303.223 us; speedup vs baseline: 1.5211x; 1.1445x over previous
//
#include <hip/hip_runtime.h>
#include <hip/hip_bf16.h>
#include <math.h>

#define CDIM 512
#define LV 196
#define BV 64
#define BT 32
#define NW 24
#define NKEEP 98
#define NNON 98      // LV - NKEEP
#define KEEPED 49
#define HID 102
#define LAMBDA_ 4.0f
#define LN_EPS_ 1e-5f

// ws layout (float offsets)
#define WS_CAPNORM 0
#define WS_CAPGLO  (WS_CAPNORM + BT*NW*CDIM)     // 393216
#define WS_IMGGLO  (WS_CAPGLO + BT*CDIM)         // +16384
#define WS_INVN    (WS_IMGGLO + BV*CDIM)         // +32768
#define WS_WLOG    (WS_INVN + BV*LV)             // +12544
#define WS_SCORE   (WS_WLOG + BV*LV*KEEPED)      // +614656
#define WS_END     (WS_SCORE + BT*BV*LV)         // 1470976 floats = 5.88 MB
// imgT (big path only): bf16 [64][512][224] appended after WS_END
#define WS_IMGT_B  ((size_t)WS_END * 4)          // byte offset 5883904
#define TOKPAD 224
#define WS_NEED_B  (WS_IMGT_B + (size_t)BV * CDIM * TOKPAD * 2)   // 20563968 B
// W1T/W2T (bf16) live in the WS_SCORE region: written by k0 plane 7 (big) or
// k5_prep (small), read by k2, then SCORE is overwritten by k3.
#define WS_W1T_B   ((size_t)WS_SCORE * 4)
#define WS_W2T_B   (WS_W1T_B + (size_t)112 * 512 * 2)
// img column partial sums (big path): [7 planes][64 v][512 c] f32 = 229,376
// floats, staged in the WS_WLOG region (dead until k2; k1 consumes before k2).
#define WS_IPART   WS_WLOG

typedef short v8s __attribute__((ext_vector_type(8)));   // 8 bf16 (4 VGPR)
typedef float v4f __attribute__((ext_vector_type(4)));
#define MFMA16(a, b, c) __builtin_amdgcn_mfma_f32_16x16x32_bf16((a), (b), (c), 0, 0, 0)

// LDS strides (elements), padded for bank behavior + alignment:
#define WA_STR 232    // A matrix rows (464 B, 16-aligned, 2-way banks)
#define TOK_STR 40    // token K-tile rows (80 B, 16-aligned)
#define SEL_STR 520   // sel rows (1040 B, 16-aligned, 2-way banks) [fallback k4]
#define G_STR 66      // Gram rows (f32)
#define XN_STR 520    // k2 xn rows (bf16)
#define HB_STR 136    // k2 hbuf rows (bf16; 136=2-way banks, not pow2)

// k4_big LDS plan (R12/r5, total 51968 B; measured 150-155 us, VGPR 64):
// R2 [0, 19216): s_w fp32 19208 (P3->P4) THEN sel quarter bf16 [64][136]=17408
// R1 [19216, 48912): wa bf16 [64][232]=29696 (P4->P5);
//   THEN cap quarter bf16 [24][136]=6528 (quarter loop)
//   THEN sims f32 [32][64]=8192 + G f32 [64][66]=16896 (after quarter loop)
// Occupancy: unified VGPR+AGPR file -> 64 VGPR + 64 AGPR acc = 128 regs =
// 2 blocks/CU (settled; (512,6) spills r3/r4, P5-fusion r6 regressed).
#define SELQ_STR 136  // 272 B rows
#define CAPQ_STR 136
#define K4_SMEM   51968
#define OFF_SEL   0
#define OFF_WA    19216
#define OFF_CAPQ  19216
#define OFF_SIMS  19216
#define OFF_G     27408    // ends 44304 (<= 48912)
#define OFF_SC    48912
#define OFF_KIDX  49696
#define OFF_NIDX  50088
#define OFF_CNT   50480
#define OFF_WK    50496
#define OFF_RED   50896
#define OFF_POOL2 51408
#define OFF_INV   51664    // ends 51920

__device__ __forceinline__ ushort bfb(float f) {
  __hip_bfloat16 h = __float2bfloat16(f);
  union { __hip_bfloat16 h; ushort u; } cv; cv.h = h; return cv.u;
}

// ---------------------------------------------------------------------------
// K0 (big path only): grid (BV, 8).
// planes 0..6: imgT[v][c][tok] bf16 (tok padded 196->224 with zeros) + R16:
//   per-plane img column partial sums -> WS_IPART[kt][v][c] (dead wlog region,
//   no atomics; k1 folds them -> img pass removed from k1).
// plane 7: W1T/W2T transpose (v<56: W1T rows 2v,2v+1; v>=56: W2T).
// ---------------------------------------------------------------------------
__global__ __launch_bounds__(512) void k0_prep(const float* __restrict__ img,
                                               const float* __restrict__ W1,
                                               const float* __restrict__ W2,
                                               float* __restrict__ ws) {
  int v = blockIdx.x, kt = blockIdx.y, c = threadIdx.x;
  if (kt == 7) {
    if (v < 56) {
      #pragma unroll
      for (int r = 0; r < 2; ++r) {
        int h = v * 2 + r;
        float val = (h < HID) ? W1[(size_t)c * HID + h] : 0.f;
        ((ushort*)((char*)ws + WS_W1T_B))[(size_t)h * 512 + c] = bfb(val);
      }
    } else {
      for (int e = c; e < 1024; e += 512) {
        int idx = (v - 56) * 1024 + e;
        int p = idx >> 7, h = idx & 127;
        float val = (p < KEEPED && h < HID) ? W2[(size_t)h * KEEPED + p] : 0.f;
        ((ushort*)((char*)ws + WS_W2T_B))[(size_t)p * 128 + h] = bfb(val);
      }
    }
    return;
  }
  float x[32];
  #pragma unroll
  for (int kk = 0; kk < 32; ++kk) {
    int tok = kt * 32 + kk;
    x[kk] = (tok < LV) ? img[((size_t)v * LV + tok) * CDIM + c] : 0.f;
  }
  // column partial sum for img_glo (tok >= LV contributed 0)
  {
    float s = 0.f;
    #pragma unroll
    for (int kk = 0; kk < 32; ++kk) s += x[kk];
    ws[WS_IPART + ((size_t)kt * BV + v) * CDIM + c] = s;
  }
  __hip_bfloat16* imgT = (__hip_bfloat16*)((char*)ws + WS_IMGT_B);
  uint* dst = (uint*)(imgT + ((size_t)v * CDIM + c) * TOKPAD + kt * 32);
  #pragma unroll
  for (int g = 0; g < 4; ++g) {
    uint4 u;
    u.x = (uint)bfb(x[g*8+0]) | ((uint)bfb(x[g*8+1]) << 16);
    u.y = (uint)bfb(x[g*8+2]) | ((uint)bfb(x[g*8+3]) << 16);
    u.z = (uint)bfb(x[g*8+4]) | ((uint)bfb(x[g*8+5]) << 16);
    u.w = (uint)bfb(x[g*8+6]) | ((uint)bfb(x[g*8+7]) << 16);
    *(uint4*)(dst + g * 4) = u;
  }
}

// ---------------------------------------------------------------------------
// K5 (small path only): transpose W1 -> W1T, W2 -> W2T.
// ---------------------------------------------------------------------------
__global__ __launch_bounds__(512) void k5_prep(const float* __restrict__ W1,
                                               const float* __restrict__ W2,
                                               float* __restrict__ ws) {
  int b = blockIdx.x, tid = threadIdx.x;
  if (b < 112) {
    int h = b;
    float val = (h < HID) ? W1[(size_t)tid * HID + h] : 0.f;
    ((ushort*)((char*)ws + WS_W1T_B))[(size_t)h * 512 + tid] = bfb(val);
  } else {
    int p = b - 112;
    if (tid < 128) {
      int h = tid;
      float val = (p < KEEPED && h < HID) ? W2[(size_t)h * KEEPED + p] : 0.f;
      ((ushort*)((char*)ws + WS_W2T_B))[(size_t)p * 128 + h] = bfb(val);
    }
  }
}

// ---------------------------------------------------------------------------
// K1: cap_norm + cap_glo (blocks 0..31), img_glo (blocks 32..95). 256 thr.
// BIG==1 (R16): img branch folds k0's 7 column-partials (896 KB) instead of
// re-reading 25.7 MB of img. BIG==0: r7 wave-sliced full read.
// ---------------------------------------------------------------------------
template<int BIG>
__global__ __launch_bounds__(256) void k1_glo(const float* __restrict__ img,
                                              const float* __restrict__ cap,
                                              float* __restrict__ ws) {
  __shared__ float red[256];
  __shared__ float s_part[4 * CDIM];   // per-wave raw-sum partials
  __shared__ float s_glo[CDIM];
  int b = blockIdx.x, tid = threadIdx.x;
  if (b < BT) {
    int t = b;
    int wv = tid >> 6, lane = tid & 63;
    int cb = lane * 8;
    float4 sA = make_float4(0.f,0.f,0.f,0.f), sB = make_float4(0.f,0.f,0.f,0.f);
    for (int w = wv; w < NW; w += 4) {
      const float* p = cap + ((size_t)t * NW + w) * CDIM + cb;
      float4 xa = *(const float4*)p;
      float4 xb = *(const float4*)(p + 4);
      float ss = xa.x*xa.x + xa.y*xa.y + xa.z*xa.z + xa.w*xa.w
               + xb.x*xb.x + xb.y*xb.y + xb.z*xb.z + xb.w*xb.w;
      #pragma unroll
      for (int off = 32; off > 0; off >>= 1) ss += __shfl_xor(ss, off, 64);
      float inv = 1.f / fmaxf(sqrtf(ss), 1e-12f);
      float* q = ws + WS_CAPNORM + ((size_t)t * NW + w) * CDIM + cb;
      *(float4*)q       = make_float4(xa.x*inv, xa.y*inv, xa.z*inv, xa.w*inv);
      *(float4*)(q + 4) = make_float4(xb.x*inv, xb.y*inv, xb.z*inv, xb.w*inv);
      sA.x += xa.x; sA.y += xa.y; sA.z += xa.z; sA.w += xa.w;
      sB.x += xb.x; sB.y += xb.y; sB.z += xb.z; sB.w += xb.w;
    }
    *(float4*)&s_part[wv * CDIM + cb]     = sA;
    *(float4*)&s_part[wv * CDIM + cb + 4] = sB;
    __syncthreads();
    if (tid < 128) {
      float4 g = make_float4(0.f, 0.f, 0.f, 0.f);
      #pragma unroll
      for (int w2 = 0; w2 < 4; ++w2) {
        float4 pv = *(const float4*)&s_part[w2 * CDIM + tid * 4];
        g.x += pv.x; g.y += pv.y; g.z += pv.z; g.w += pv.w;
      }
      g.x /= (float)NW; g.y /= (float)NW; g.z /= (float)NW; g.w /= (float)NW;
      *(float4*)&s_glo[tid * 4] = g;
      red[tid] = g.x*g.x + g.y*g.y + g.z*g.z + g.w*g.w;
    }
    __syncthreads();
    for (int off = 64; off > 0; off >>= 1) {
      if (tid < off) red[tid] += red[tid + off];
      __syncthreads();
    }
    float inv = 1.f / fmaxf(sqrtf(red[0]), 1e-12f);
    if (tid < 128) {
      float4 g = *(const float4*)&s_glo[tid * 4];
      *(float4*)(ws + WS_CAPGLO + (size_t)t * CDIM + tid * 4) =
          make_float4(g.x*inv, g.y*inv, g.z*inv, g.w*inv);
    }
  } else if (BIG) {
    int v = b - BT;
    int c0 = tid, c1 = tid + 256;
    float s0 = 0.f, s1 = 0.f;
    #pragma unroll
    for (int kt = 0; kt < 7; ++kt) {
      s0 += ws[WS_IPART + ((size_t)kt * BV + v) * CDIM + c0];
      s1 += ws[WS_IPART + ((size_t)kt * BV + v) * CDIM + c1];
    }
    float g0 = s0 / (float)LV, g1 = s1 / (float)LV;
    red[tid] = g0 * g0 + g1 * g1;
    __syncthreads();
    for (int off = 128; off > 0; off >>= 1) {
      if (tid < off) red[tid] += red[tid + off];
      __syncthreads();
    }
    float inv = 1.f / fmaxf(sqrtf(red[0]), 1e-12f);
    float* q = ws + WS_IMGGLO + (size_t)v * CDIM;
    q[c0] = g0 * inv; q[c1] = g1 * inv;
  } else {
    int v = b - BT;
    int wv = tid >> 6, lane = tid & 63;
    int cb = lane * 8;
    const float* base = img + (size_t)v * LV * CDIM;
    float4 sA = make_float4(0.f,0.f,0.f,0.f), sB = make_float4(0.f,0.f,0.f,0.f);
    int l0 = wv * 49;                         // 4 waves x 49 rows = 196
    for (int l = l0; l < l0 + 49; ++l) {
      const float* p = base + (size_t)l * CDIM + cb;
      float4 xa = *(const float4*)p;
      float4 xb = *(const float4*)(p + 4);
      sA.x += xa.x; sA.y += xa.y; sA.z += xa.z; sA.w += xa.w;
      sB.x += xb.x; sB.y += xb.y; sB.z += xb.z; sB.w += xb.w;
    }
    *(float4*)&s_part[wv * CDIM + cb]     = sA;
    *(float4*)&s_part[wv * CDIM + cb + 4] = sB;
    __syncthreads();
    if (tid < 128) {
      float4 g = make_float4(0.f, 0.f, 0.f, 0.f);
      #pragma unroll
      for (int w2 = 0; w2 < 4; ++w2) {
        float4 pv = *(const float4*)&s_part[w2 * CDIM + tid * 4];
        g.x += pv.x; g.y += pv.y; g.z += pv.z; g.w += pv.w;
      }
      g.x /= (float)LV; g.y /= (float)LV; g.z /= (float)LV; g.w /= (float)LV;
      *(float4*)&s_glo[tid * 4] = g;
      red[tid] = g.x*g.x + g.y*g.y + g.z*g.z + g.w*g.w;
    }
    __syncthreads();
    for (int off = 64; off > 0; off >>= 1) {
      if (tid < off) red[tid] += red[tid + off];
      __syncthreads();
    }
    float inv = 1.f / fmaxf(sqrtf(red[0]), 1e-12f);
    if (tid < 128) {
      float4 g = *(const float4*)&s_glo[tid * 4];
      *(float4*)(ws + WS_IMGGLO + (size_t)v * CDIM + tid * 4) =
          make_float4(g.x*inv, g.y*inv, g.z*inv, g.w*inv);
    }
  }
}

// ---------------------------------------------------------------------------
// K2: MFMA MLP. grid (64 v, 7 segs of 28 tokens), 512 thr (8 waves).
// LDS [32][520] bf16 = 33,280 B -> full-GPU grid + multi-block/CU.
// ---------------------------------------------------------------------------
__global__ __launch_bounds__(512, 4) void k2_mlp(const float* __restrict__ img,
                                                 const float* __restrict__ gamma,
                                                 const float* __restrict__ beta,
                                                 const float* __restrict__ b1,
                                                 const float* __restrict__ b2,
                                                 float* __restrict__ ws) {
  __shared__ __align__(16) __hip_bfloat16 s_xn[32 * XN_STR];  // 33,280 B
  __hip_bfloat16* s_hb = s_xn;                                // overlay after GEMM1

  int v = blockIdx.x, seg = blockIdx.y;
  int l0 = seg * 28;
  int tid = threadIdx.x, wv = tid >> 6, lane = tid & 63;
  int quad = lane >> 4, l15 = lane & 15, koff = quad * 8;
  const __hip_bfloat16* W1T = (const __hip_bfloat16*)((const char*)ws + WS_W1T_B);
  const __hip_bfloat16* W2T = (const __hip_bfloat16*)((const char*)ws + WS_W2T_B);

  // ---- Phase A: LN -> xn bf16 (28 tokens) ----
  int cb = lane * 8;
  float4 g4a = *(const float4*)(gamma + cb);
  float4 g4b = *(const float4*)(gamma + cb + 4);
  float4 b4a = *(const float4*)(beta + cb);
  float4 b4b = *(const float4*)(beta + cb + 4);
  for (int tok = wv; tok < 28; tok += 8) {
    const float* p = img + ((size_t)v * LV + l0 + tok) * CDIM + cb;
    float4 xa = *(const float4*)p;
    float4 xb = *(const float4*)(p + 4);
    float s  = xa.x + xa.y + xa.z + xa.w + xb.x + xb.y + xb.z + xb.w;
    float sq = xa.x*xa.x + xa.y*xa.y + xa.z*xa.z + xa.w*xa.w
             + xb.x*xb.x + xb.y*xb.y + xb.z*xb.z + xb.w*xb.w;
    #pragma unroll
    for (int off = 32; off > 0; off >>= 1) { s += __shfl_xor(s, off, 64); sq += __shfl_xor(sq, off, 64); }
    float mean = s / (float)CDIM;
    float var = sq / (float)CDIM - mean * mean;
    float rstd = 1.f / sqrtf(var + LN_EPS_);
    if (lane == 0) ws[WS_INVN + (size_t)v * LV + l0 + tok] = 1.f / fmaxf(sqrtf(sq), 1e-12f);
    float f[8];
    f[0] = (xa.x - mean) * rstd * g4a.x + b4a.x;
    f[1] = (xa.y - mean) * rstd * g4a.y + b4a.y;
    f[2] = (xa.z - mean) * rstd * g4a.z + b4a.z;
    f[3] = (xa.w - mean) * rstd * g4a.w + b4a.w;
    f[4] = (xb.x - mean) * rstd * g4b.x + b4b.x;
    f[5] = (xb.y - mean) * rstd * g4b.y + b4b.y;
    f[6] = (xb.z - mean) * rstd * g4b.z + b4b.z;
    f[7] = (xb.w - mean) * rstd * g4b.w + b4b.w;
    uint4 u;
    u.x = (uint)bfb(f[0]) | ((uint)bfb(f[1]) << 16);
    u.y = (uint)bfb(f[2]) | ((uint)bfb(f[3]) << 16);
    u.z = (uint)bfb(f[4]) | ((uint)bfb(f[5]) << 16);
    u.w = (uint)bfb(f[6]) | ((uint)bfb(f[7]) << 16);
    *(uint4*)(s_xn + (size_t)tok * XN_STR + cb) = u;
  }
  __syncthreads();

  // ---- GEMM1: C[32 tok][112 h], 2x7 = 14 tiles over 8 waves ----
  v4f c1[2];
  int mt_[2], nt_[2];
  #pragma unroll
  for (int i = 0; i < 2; ++i) {
    int idx = wv + 8 * i; if (idx > 13) idx = 13;   // clamp: keep reads in-bounds
    mt_[i] = idx / 7; nt_[i] = idx % 7;
    c1[i] = (v4f){0.f, 0.f, 0.f, 0.f};
  }
  for (int ks = 0; ks < 16; ++ks) {
    #pragma unroll
    for (int i = 0; i < 2; ++i) {
      v8s a  = *(const v8s*)(s_xn + (size_t)(mt_[i] * 16 + l15) * XN_STR + ks * 32 + koff);
      v8s bb = *(const v8s*)(W1T + (size_t)(nt_[i] * 16 + l15) * 512 + ks * 32 + koff);
      c1[i] = MFMA16(a, bb, c1[i]);
    }
  }
  __syncthreads();   // all xn reads complete before hbuf overlay

  // ---- gelu + bias -> hbuf [32][136] ----
  #pragma unroll
  for (int i = 0; i < 2; ++i) {
    int idx = wv + 8 * i;
    if (idx < 14) {
      int h = nt_[i] * 16 + l15;
      float bias = (h < HID) ? b1[h] : 0.f;
      #pragma unroll
      for (int reg = 0; reg < 4; ++reg) {
        int row = mt_[i] * 16 + quad * 4 + reg;
        float x = c1[i][reg] + bias;
        float gl = (h < HID) ? 0.5f * x * (1.f + erff(x * 0.70710678118654752f)) : 0.f;
        s_hb[(size_t)row * HB_STR + h] = __float2bfloat16(gl);
      }
    }
  }
  for (int i = tid; i < 32 * 16; i += 512)   // zero cols 112..127 (K pad)
    s_hb[(size_t)(i >> 4) * HB_STR + 112 + (i & 15)] = __float2bfloat16(0.f);
  __syncthreads();

  // ---- GEMM2: C[32 tok][64 p], 2x4 = 8 tiles = 1/wave, K=128 ----
  int m2 = wv >> 2, n2 = wv & 3;
  v4f c2 = (v4f){0.f, 0.f, 0.f, 0.f};
  for (int ks = 0; ks < 4; ++ks) {
    v8s a  = *(const v8s*)(s_hb + (size_t)(m2 * 16 + l15) * HB_STR + ks * 32 + koff);
    v8s bb = *(const v8s*)(W2T + (size_t)(n2 * 16 + l15) * 128 + ks * 32 + koff);
    c2 = MFMA16(a, bb, c2);
  }
  {
    int p = n2 * 16 + l15;
    if (p < KEEPED) {
      float bias = b2[p];
      #pragma unroll
      for (int reg = 0; reg < 4; ++reg) {
        int tok = m2 * 16 + quad * 4 + reg;
        if (tok < 28)
          ws[WS_WLOG + ((size_t)v * LV + l0 + tok) * KEEPED + p] = c2[reg] + bias;
      }
    }
  }
}

// ---------------------------------------------------------------------------
// K3: scores. 512 threads; R16: float2 LDS reads (xt stride 66 — 8B aligned,
// 2-way-free; qt reads are wave-broadcast). Per-acc accumulation order
// unchanged (cc ascending, .x then .y) -> bitwise-identical scores.
// ---------------------------------------------------------------------------
__global__ __launch_bounds__(512) void k3_score(const float* __restrict__ img,
                                                float* __restrict__ ws) {
  __shared__ __align__(16) float qt[33 * 64];
  __shared__ __align__(16) float xt[64 * 66];
  __shared__ float dself[64];
  int v = blockIdx.x;
  int t0 = blockIdx.y * 64;
  int tid = threadIdx.x;
  int tloc = tid & 63, qg = tid >> 6;   // qg 0..7
  float acc[5];
  #pragma unroll
  for (int i = 0; i < 5; ++i) acc[i] = 0.f;
  const float* capglo = ws + WS_CAPGLO;
  const float* imgglo = ws + WS_IMGGLO + (size_t)v * CDIM;

  for (int ct = 0; ct < 8; ++ct) {
    for (int i = tid; i < 33 * 64; i += 512) {
      int q = i >> 6, cc = i & 63;
      qt[i] = (q < 32) ? capglo[(size_t)q * CDIM + ct * 64 + cc] : imgglo[ct * 64 + cc];
    }
    for (int i = tid; i < 64 * 64; i += 512) {
      int tok = i >> 6, cc = i & 63;
      int l = t0 + tok;
      xt[tok * 66 + cc] = (l < LV) ? img[((size_t)v * LV + l) * CDIM + ct * 64 + cc] : 0.f;
    }
    __syncthreads();
    for (int cc2 = 0; cc2 < 32; ++cc2) {
      float2 xv = *(const float2*)&xt[tloc * 66 + cc2 * 2];
      #pragma unroll
      for (int qi = 0; qi < 5; ++qi) {
        int q = qg + 8 * qi;
        if (q < 33) {
          float2 qv = *(const float2*)&qt[q * 64 + cc2 * 2];
          acc[qi] += qv.x * xv.x;
          acc[qi] += qv.y * xv.y;
        }
      }
    }
    __syncthreads();
  }
  if (qg == 0) dself[tloc] = acc[4];    // q = 0 + 8*4 = 32 (self query)
  __syncthreads();
  int l = t0 + tloc;
  if (l < LV) {
    float invn = ws[WS_INVN + (size_t)v * LV + l];
    float ds = dself[tloc];
    #pragma unroll
    for (int qi = 0; qi < 5; ++qi) {
      int q = qg + 8 * qi;
      if (q < 32) ws[WS_SCORE + ((size_t)q * BV + v) * LV + l] = (acc[qi] + ds) * invn;
    }
  }
}

// ---------------------------------------------------------------------------
// K4 fallback (small ws): verbatim old template, only <0> instantiated.
// ---------------------------------------------------------------------------
template<int USE_IMGT>
__global__ __launch_bounds__(512, 2) void k4_main(const float* __restrict__ img,
                                                  const float* __restrict__ scale_p,
                                                  const float* __restrict__ ws,
                                                  float* __restrict__ out) {
  __shared__ float s_sc[LV];
  __shared__ int   s_kidx[NKEEP];
  __shared__ int   s_nidx[NNON];
  __shared__ int   s_cnt[2];
  __shared__ float s_wk[NNON];
  __shared__ float s_red[128];
  __shared__ float s_pool2[64];
  __shared__ float s_inv[64];
  __shared__ __align__(16) __hip_bfloat16 s_selh[64 * SEL_STR];
  __shared__ __align__(16) __hip_bfloat16 s_wa[64 * WA_STR];
  __shared__ __align__(16) __hip_bfloat16 s_dyn[512 * TOK_STR];

  float* s_w = (float*)s_dyn;
  __hip_bfloat16* s_tok = s_dyn;
  __hip_bfloat16* s_cap = s_dyn;
  float* s_sims = (float*)s_wa;
  float* s_G = (float*)((char*)s_wa + 8192);

  int b = blockIdx.x;
  int v = b >> 5, t = b & 31;
  int tid = threadIdx.x;
  int wv = tid >> 6, lane = tid & 63;
  int quad = lane >> 4, l15 = lane & 15;
  int koff = quad * 8;

  if (tid < 2) s_cnt[tid] = 0;
  if (tid < 64) s_pool2[tid] = 0.f;
  if (tid < LV) s_sc[tid] = ws[WS_SCORE + ((size_t)t * BV + v) * LV + tid];
  {
    uint* za = (uint*)s_wa;
    for (int i = tid; i < 64 * WA_STR / 2; i += 512) za[i] = 0u;
    uint* zs = (uint*)(s_selh + 50 * SEL_STR);
    for (int i = tid; i < 14 * SEL_STR / 2; i += 512) zs[i] = 0u;
  }
  __syncthreads();

  if (tid < LV) {
    float my = s_sc[tid];
    int cnt = 0;
    for (int j = 0; j < LV; ++j) {
      float sj = s_sc[j];
      cnt += (sj > my) || (sj == my && j < tid);
    }
    bool keep = cnt < NKEEP;
    out[BV * BT + ((size_t)t * BV + v) * LV + tid] = keep ? 1.f : 0.f;
    if (keep) { int p = atomicAdd(&s_cnt[0], 1); s_kidx[p] = tid; }
    else      { int p = atomicAdd(&s_cnt[1], 1); s_nidx[p] = tid; }
  }
  __syncthreads();

  if (tid < 128) s_red[tid] = (tid < NNON) ? s_sc[s_nidx[tid]] : -3.0e38f;
  __syncthreads();
  for (int off = 64; off > 0; off >>= 1) {
    if (tid < off) s_red[tid] = fmaxf(s_red[tid], s_red[tid + off]);
    __syncthreads();
  }
  float nm = s_red[0];
  __syncthreads();
  float e0 = 0.f;
  if (tid < NNON) e0 = expf(s_sc[s_nidx[tid]] - nm);
  if (tid < 128) s_red[tid] = (tid < NNON) ? e0 : 0.f;
  __syncthreads();
  for (int off = 64; off > 0; off >>= 1) {
    if (tid < off) s_red[tid] += s_red[tid + off];
    __syncthreads();
  }
  float nS = s_red[0];
  __syncthreads();
  if (tid < NNON) s_wk[tid] = e0 / nS;
  __syncthreads();

  float scale_val = scale_p[0];
  for (int i = tid; i < KEEPED * NKEEP; i += 512) {
    int k = i / KEEPED, p = i - k * KEEPED;
    s_w[p * NKEEP + k] = ws[WS_WLOG + ((size_t)v * LV + s_kidx[k]) * KEEPED + p] * scale_val;
  }
  __syncthreads();
  if (tid < KEEPED * 8) {
    int p = tid >> 3, g = tid & 7;
    float mm = -3e38f;
    for (int k = g; k < NKEEP; k += 8) mm = fmaxf(mm, s_w[p * NKEEP + k]);
    #pragma unroll
    for (int off = 4; off > 0; off >>= 1) mm = fmaxf(mm, __shfl_xor(mm, off, 8));
    float ss = 0.f;
    for (int k = g; k < NKEEP; k += 8) {
      float ee = expf(s_w[p * NKEEP + k] - mm);
      s_w[p * NKEEP + k] = ee;
      ss += ee;
    }
    #pragma unroll
    for (int off = 4; off > 0; off >>= 1) ss += __shfl_xor(ss, off, 8);
    float rs = 1.f / ss;
    for (int k = g; k < NKEEP; k += 8) s_w[p * NKEEP + k] *= rs;
  }
  __syncthreads();

  for (int i = tid; i < KEEPED * NKEEP; i += 512) {
    int p = i / NKEEP, r = i - p * NKEEP;
    s_wa[p * WA_STR + s_kidx[r]] = __float2bfloat16(s_w[p * NKEEP + r]);
  }
  if (tid < NNON) s_wa[49 * WA_STR + s_nidx[tid]] = __float2bfloat16(s_wk[tid]);
  __syncthreads();

  v4f acc[4][4];
  #pragma unroll
  for (int m = 0; m < 4; ++m)
    #pragma unroll
    for (int j = 0; j < 4; ++j) acc[m][j] = (v4f){0.f, 0.f, 0.f, 0.f};

  if (USE_IMGT) {
    const __hip_bfloat16* imgTv =
        (const __hip_bfloat16*)((const char*)ws + WS_IMGT_B) + (size_t)v * CDIM * TOKPAD;
    for (int ks = 0; ks < 7; ++ks) {
      v8s bfr[4];
      #pragma unroll
      for (int j = 0; j < 4; ++j)
        bfr[j] = *(const v8s*)(imgTv + (size_t)(wv * 64 + j * 16 + l15) * TOKPAD + ks * 32 + koff);
      #pragma unroll
      for (int m = 0; m < 4; ++m) {
        v8s af = *(const v8s*)(s_wa + (m * 16 + l15) * WA_STR + ks * 32 + koff);
        #pragma unroll
        for (int j = 0; j < 4; ++j) acc[m][j] = MFMA16(af, bfr[j], acc[m][j]);
      }
    }
  } else {
    for (int ks = 0; ks < 7; ++ks) {
      #pragma unroll
      for (int it = 0; it < 8; ++it) {
        int k0 = ks * 32 + it * 4;
        if (k0 < LV) {
          const float* gp = img + ((size_t)v * LV + k0) * CDIM + tid;
          float x0 = gp[0], x1 = gp[CDIM], x2 = gp[2 * CDIM], x3 = gp[3 * CDIM];
          union { __hip_bfloat16 h[4]; uint2 u; } pk;
          pk.h[0] = __float2bfloat16(x0); pk.h[1] = __float2bfloat16(x1);
          pk.h[2] = __float2bfloat16(x2); pk.h[3] = __float2bfloat16(x3);
          *(uint2*)(s_tok + tid * TOK_STR + it * 4) = pk.u;
        }
      }
      __syncthreads();
      v8s bfr[4];
      #pragma unroll
      for (int j = 0; j < 4; ++j)
        bfr[j] = *(const v8s*)(s_tok + (wv * 64 + j * 16 + l15) * TOK_STR + koff);
      #pragma unroll
      for (int m = 0; m < 4; ++m) {
        v8s af = *(const v8s*)(s_wa + (m * 16 + l15) * WA_STR + ks * 32 + koff);
        #pragma unroll
        for (int j = 0; j < 4; ++j) acc[m][j] = MFMA16(af, bfr[j], acc[m][j]);
      }
      __syncthreads();
    }
  }

  if (!USE_IMGT) __syncthreads();
  for (int i = tid; i < NW * 128; i += 512) {
    int w = i >> 7, cq = i & 127;
    const float4 xv = *(const float4*)(ws + WS_CAPNORM + ((size_t)t * NW + w) * CDIM + cq * 4);
    union { __hip_bfloat16 h[4]; uint2 u; } pk;
    pk.h[0] = __float2bfloat16(xv.x); pk.h[1] = __float2bfloat16(xv.y);
    pk.h[2] = __float2bfloat16(xv.z); pk.h[3] = __float2bfloat16(xv.w);
    *(uint2*)(s_cap + w * SEL_STR + cq * 4) = pk.u;
  }
  {
    uint* zc = (uint*)(s_cap + 24 * SEL_STR);
    for (int i = tid; i < 8 * SEL_STR / 2; i += 512) zc[i] = 0u;
  }
  #pragma unroll
  for (int m = 0; m < 4; ++m) {
    #pragma unroll
    for (int reg = 0; reg < 4; ++reg) {
      float ss = acc[m][0][reg] * acc[m][0][reg] + acc[m][1][reg] * acc[m][1][reg]
               + acc[m][2][reg] * acc[m][2][reg] + acc[m][3][reg] * acc[m][3][reg];
      #pragma unroll
      for (int off = 8; off > 0; off >>= 1) ss += __shfl_xor(ss, off, 64);
      if (l15 == 0) atomicAdd(&s_pool2[m * 16 + quad * 4 + reg], ss);
    }
  }
  __syncthreads();
  if (tid < 64) s_inv[tid] = 1.f / fmaxf(sqrtf(s_pool2[tid]), 1e-12f);
  __syncthreads();
  #pragma unroll
  for (int m = 0; m < 4; ++m) {
    #pragma unroll
    for (int reg = 0; reg < 4; ++reg) {
      int p = m * 16 + quad * 4 + reg;
      if (p < 50) {
        float iv = s_inv[p];
        #pragma unroll
        for (int j = 0; j < 4; ++j)
          s_selh[p * SEL_STR + wv * 64 + j * 16 + l15] = __float2bfloat16(acc[m][j][reg] * iv);
      }
    }
  }
  __syncthreads();

  {
    int mt = wv >> 2, nt = wv & 3;
    v4f sa = (v4f){0.f, 0.f, 0.f, 0.f};
    for (int ks = 0; ks < 16; ++ks) {
      v8s a = *(const v8s*)(s_cap + (mt * 16 + l15) * SEL_STR + ks * 32 + koff);
      v8s bb = *(const v8s*)(s_selh + (nt * 16 + l15) * SEL_STR + ks * 32 + koff);
      sa = MFMA16(a, bb, sa);
    }
    #pragma unroll
    for (int reg = 0; reg < 4; ++reg)
      s_sims[(mt * 16 + quad * 4 + reg) * 64 + nt * 16 + l15] = sa[reg];
  }
  __syncthreads();

  if (tid < NW * 8) {
    int w = tid >> 3, g = tid & 7;
    float* row = s_sims + w * 64;
    float mm = -3e38f;
    for (int p = g; p < 50; p += 8) mm = fmaxf(mm, row[p]);
    #pragma unroll
    for (int off = 4; off > 0; off >>= 1) mm = fmaxf(mm, __shfl_xor(mm, off, 8));
    float num = 0.f;
    for (int p = g; p < 64; p += 8) {
      if (p < 50) {
        float s = row[p];
        float ee = expf(LAMBDA_ * (s - mm));
        num += ee * s;
        row[p] = ee;
      } else row[p] = 0.f;
    }
    #pragma unroll
    for (int off = 4; off > 0; off >>= 1) num += __shfl_xor(num, off, 8);
    if (g == 0) s_red[w] = num;
  }
  __syncthreads();

  #pragma unroll
  for (int i2 = 0; i2 < 2; ++i2) {
    int idx = wv * 2 + i2;
    int gm = idx >> 2, gn = idx & 3;
    v4f ga = (v4f){0.f, 0.f, 0.f, 0.f};
    for (int ks = 0; ks < 16; ++ks) {
      v8s a = *(const v8s*)(s_selh + (gm * 16 + l15) * SEL_STR + ks * 32 + koff);
      v8s bb = *(const v8s*)(s_selh + (gn * 16 + l15) * SEL_STR + ks * 32 + koff);
      ga = MFMA16(a, bb, ga);
    }
    #pragma unroll
    for (int reg = 0; reg < 4; ++reg)
      s_G[(gm * 16 + quad * 4 + reg) * G_STR + gn * 16 + l15] = ga[reg];
  }
  __syncthreads();

  float wacc = 0.f;
  for (int w = wv; w < NW; w += 8) {
    const float* ev = s_sims + w * 64;
    float tl = 0.f;
    for (int q = 0; q < 50; ++q) tl += s_G[q * G_STR + lane] * ev[q];
    float ql = ev[lane] * tl;
    #pragma unroll
    for (int off = 32; off > 0; off >>= 1) ql += __shfl_xor(ql, off, 64);
    if (lane == 0) wacc += s_red[w] / fmaxf(sqrtf(ql), 1e-20f);
  }
  if (lane == 0) s_red[64 + wv] = wacc;
  __syncthreads();
  if (tid == 0) {
    float s = 0.f;
    #pragma unroll
    for (int i = 0; i < 8; ++i) s += s_red[64 + i];
    out[(size_t)v * BT + t] = s / (float)NW;
  }
}

// ---------------------------------------------------------------------------
// K4 big path (R16): R15 body (150.5 us, XCD swizzle) + P2 rewritten with
// per-wave shuffle reductions (16 barriers -> 3). Max is order-invariant;
// sum regroup Δ~1e-7 (not selection-critical).
// ---------------------------------------------------------------------------
__global__ __launch_bounds__(512, 4) void k4_big(const float* __restrict__ img,
                                                 const float* __restrict__ scale_p,
                                                 const float* __restrict__ ws,
                                                 float* __restrict__ out) {
  __shared__ __align__(16) char smem[K4_SMEM];
  __hip_bfloat16* s_sel = (__hip_bfloat16*)(smem + OFF_SEL);   // [64][136] quarter
  float*          s_w   = (float*)(smem + OFF_SEL);            // overlay, P3/P4 only
  __hip_bfloat16* s_wa  = (__hip_bfloat16*)(smem + OFF_WA);    // [64][232] P4->P5
  __hip_bfloat16* s_capq= (__hip_bfloat16*)(smem + OFF_CAPQ);  // [24][136] loop only
  float*          s_sims= (float*)(smem + OFF_SIMS);           // [32][64] after loop
  float*          s_G   = (float*)(smem + OFF_G);              // [64][66] after loop
  float* s_sc    = (float*)(smem + OFF_SC);
  int*   s_kidx  = (int*)(smem + OFF_KIDX);
  int*   s_nidx  = (int*)(smem + OFF_NIDX);
  int*   s_cnt   = (int*)(smem + OFF_CNT);
  float* s_wk    = (float*)(smem + OFF_WK);
  float* s_red   = (float*)(smem + OFF_RED);
  float* s_pool2 = (float*)(smem + OFF_POOL2);
  float* s_inv   = (float*)(smem + OFF_INV);

  int b0 = blockIdx.x;
  int b = ((b0 & 7) << 8) | (b0 >> 3);   // XCD swizzle: same-v blocks co-locate
  int v = b >> 5, t = b & 31;
  int tid = threadIdx.x;
  int wv = tid >> 6, lane = tid & 63;
  int quad = lane >> 4, l15 = lane & 15;
  int koff = quad * 8;

  // ---- P0: loads + zero-init ----
  if (tid < 2) s_cnt[tid] = 0;
  if (tid < 64) s_pool2[tid] = 0.f;
  if (tid < LV) s_sc[tid] = ws[WS_SCORE + ((size_t)t * BV + v) * LV + tid];
  {
    uint* za = (uint*)s_wa;
    for (int i = tid; i < 64 * WA_STR / 2; i += 512) za[i] = 0u;
  }
  __syncthreads();

  // ---- P1: rank & partition ----
  if (tid < LV) {
    float my = s_sc[tid];
    int cnt = 0;
    for (int j = 0; j < LV; ++j) {
      float sj = s_sc[j];
      cnt += (sj > my) || (sj == my && j < tid);
    }
    bool keep = cnt < NKEEP;
    out[BV * BT + ((size_t)t * BV + v) * LV + tid] = keep ? 1.f : 0.f;
    if (keep) { int p = atomicAdd(&s_cnt[0], 1); s_kidx[p] = tid; }
    else      { int p = atomicAdd(&s_cnt[1], 1); s_nidx[p] = tid; }
  }
  __syncthreads();

  // ---- P2 (R16): softmax over non-kept scores -> s_wk, wave-shuffle form ----
  if (tid < 128) {
    float vmax = (tid < NNON) ? s_sc[s_nidx[tid]] : -3.0e38f;
    #pragma unroll
    for (int off = 32; off > 0; off >>= 1) vmax = fmaxf(vmax, __shfl_xor(vmax, off, 64));
    if ((tid & 63) == 0) s_red[tid >> 6] = vmax;
  }
  __syncthreads();
  float nm = fmaxf(s_red[0], s_red[1]);
  float e0 = 0.f;
  if (tid < 128) {
    float vs = 0.f;
    if (tid < NNON) { e0 = expf(s_sc[s_nidx[tid]] - nm); vs = e0; }
    #pragma unroll
    for (int off = 32; off > 0; off >>= 1) vs += __shfl_xor(vs, off, 64);
    if ((tid & 63) == 0) s_red[2 + (tid >> 6)] = vs;
  }
  __syncthreads();
  float nS = s_red[2] + s_red[3];
  if (tid < NNON) s_wk[tid] = e0 / nS;
  __syncthreads();

  // ---- P3: wlog gather -> s_w[p][r] fp32 (overlays sel region), softmax ----
  float scale_val = scale_p[0];
  for (int i = tid; i < KEEPED * NKEEP; i += 512) {
    int k = i / KEEPED, p = i - k * KEEPED;
    s_w[p * NKEEP + k] = ws[WS_WLOG + ((size_t)v * LV + s_kidx[k]) * KEEPED + p] * scale_val;
  }
  __syncthreads();
  if (tid < KEEPED * 8) {
    int p = tid >> 3, g = tid & 7;
    float mm = -3e38f;
    for (int k = g; k < NKEEP; k += 8) mm = fmaxf(mm, s_w[p * NKEEP + k]);
    #pragma unroll
    for (int off = 4; off > 0; off >>= 1) mm = fmaxf(mm, __shfl_xor(mm, off, 8));
    float ss = 0.f;
    for (int k = g; k < NKEEP; k += 8) {
      float ee = expf(s_w[p * NKEEP + k] - mm);
      s_w[p * NKEEP + k] = ee;
      ss += ee;
    }
    #pragma unroll
    for (int off = 4; off > 0; off >>= 1) ss += __shfl_xor(ss, off, 8);
    float rs = 1.f / ss;
    for (int k = g; k < NKEEP; k += 8) s_w[p * NKEEP + k] *= rs;
  }
  __syncthreads();

  // ---- P4: scatter A = s_wa (bf16): kept weights + wk row 49 ----
  for (int i = tid; i < KEEPED * NKEEP; i += 512) {
    int p = i / NKEEP, r = i - p * NKEEP;
    s_wa[p * WA_STR + s_kidx[r]] = __float2bfloat16(s_w[p * NKEEP + r]);
  }
  if (tid < NNON) s_wa[49 * WA_STR + s_nidx[tid]] = __float2bfloat16(s_wk[tid]);
  __syncthreads();

  // zero sel-quarter rows 50..63 (s_w dead after the barrier above; rows stay
  // zero across all four quarters — nobody writes p >= 50)
  {
    uint* zq = (uint*)(s_sel + 50 * SELQ_STR);
    for (int i = tid; i < 14 * SELQ_STR / 2; i += 512) zq[i] = 0u;
  }

  // ---- P5: aggr GEMM, B from global imgT ----
  v4f acc[4][4];
  #pragma unroll
  for (int m = 0; m < 4; ++m)
    #pragma unroll
    for (int j = 0; j < 4; ++j) acc[m][j] = (v4f){0.f, 0.f, 0.f, 0.f};

  {
    const __hip_bfloat16* imgTv =
        (const __hip_bfloat16*)((const char*)ws + WS_IMGT_B) + (size_t)v * CDIM * TOKPAD;
    for (int ks = 0; ks < 7; ++ks) {
      v8s bfr[4];
      #pragma unroll
      for (int j = 0; j < 4; ++j)
        bfr[j] = *(const v8s*)(imgTv + (size_t)(wv * 64 + j * 16 + l15) * TOKPAD + ks * 32 + koff);
      #pragma unroll
      for (int m = 0; m < 4; ++m) {
        v8s af = *(const v8s*)(s_wa + (m * 16 + l15) * WA_STR + ks * 32 + koff);
        #pragma unroll
        for (int j = 0; j < 4; ++j) acc[m][j] = MFMA16(af, bfr[j], acc[m][j]);
      }
    }
  }

  // ---- P6: pool l2norm (atomics into zeroed s_pool2) ----
  #pragma unroll
  for (int m = 0; m < 4; ++m) {
    #pragma unroll
    for (int reg = 0; reg < 4; ++reg) {
      float ss = acc[m][0][reg] * acc[m][0][reg] + acc[m][1][reg] * acc[m][1][reg]
               + acc[m][2][reg] * acc[m][2][reg] + acc[m][3][reg] * acc[m][3][reg];
      #pragma unroll
      for (int off = 8; off > 0; off >>= 1) ss += __shfl_xor(ss, off, 64);
      if (l15 == 0) atomicAdd(&s_pool2[m * 16 + quad * 4 + reg], ss);
    }
  }
  __syncthreads();
  if (tid < 64) s_inv[tid] = 1.f / fmaxf(sqrtf(s_pool2[tid]), 1e-12f);
  __syncthreads();

  // ---- pack normalized sel fragments: 64 f32 -> 32 uints (bf16 pairs) ----
  uint pk[4][4][2];
  #pragma unroll
  for (int m = 0; m < 4; ++m) {
    #pragma unroll
    for (int rp = 0; rp < 2; ++rp) {
      int p0 = m * 16 + quad * 4 + rp * 2;
      float iv0 = s_inv[p0], iv1 = s_inv[p0 + 1];
      #pragma unroll
      for (int j = 0; j < 4; ++j)
        pk[m][j][rp] = (uint)bfb(acc[m][j][2 * rp] * iv0)
                     | ((uint)bfb(acc[m][j][2 * rp + 1] * iv1) << 16);
    }
  }

  // ---- quarter loop: stage sel cols [q*128, q*128+128) (waves 2q,2q+1) and
  // cap quarter [24][128] (other 6 waves) in LDS; accumulate P7+P9.
  // capq garbage rows 24..31 (stale wa bf16, finite) feed sims rows 24..31,
  // which are never read (P8/P10 use w < 24 only).
  v4f sa = (v4f){0.f, 0.f, 0.f, 0.f};
  v4f ga[2];
  ga[0] = (v4f){0.f, 0.f, 0.f, 0.f};
  ga[1] = (v4f){0.f, 0.f, 0.f, 0.f};
  ushort* selw = (ushort*)s_sel;
  int mt = wv >> 2, nt = wv & 3;
  for (int q = 0; q < 4; ++q) {
    if ((wv >> 1) == q) {               // waves 2q, 2q+1 own cols q*128..+127
      int base = (wv & 1) * 64;
      #pragma unroll
      for (int m = 0; m < 4; ++m) {
        #pragma unroll
        for (int reg = 0; reg < 4; ++reg) {
          int p = m * 16 + quad * 4 + reg;
          if (p < 50) {
            #pragma unroll
            for (int j = 0; j < 4; ++j) {
              uint u = pk[m][j][reg >> 1];
              ushort val = (reg & 1) ? (ushort)(u >> 16) : (ushort)(u & 0xffffu);
              selw[p * SELQ_STR + base + j * 16 + l15] = val;
            }
          }
        }
      }
    } else {
      int rank = wv - (wv > 2 * q + 1 ? 2 : 0);   // 0..5 among 6 staging waves
      int lt = rank * 64 + lane;                  // 0..383
      for (int i = lt; i < NW * 32; i += 384) {
        int w = i >> 5, c4 = i & 31;
        float4 xv = *(const float4*)(ws + WS_CAPNORM + ((size_t)t * NW + w) * CDIM
                                     + q * 128 + c4 * 4);
        union { __hip_bfloat16 hh[4]; uint2 u; } pc;
        pc.hh[0] = __float2bfloat16(xv.x); pc.hh[1] = __float2bfloat16(xv.y);
        pc.hh[2] = __float2bfloat16(xv.z); pc.hh[3] = __float2bfloat16(xv.w);
        *(uint2*)(s_capq + w * CAPQ_STR + c4 * 4) = pc.u;
      }
    }
    __syncthreads();
    // P7 partial: sims += cap_quarter . sel_quarter^T
    #pragma unroll
    for (int ks = 0; ks < 4; ++ks) {
      v8s a  = *(const v8s*)(s_capq + (mt * 16 + l15) * CAPQ_STR + ks * 32 + koff);
      v8s bb = *(const v8s*)(s_sel + (nt * 16 + l15) * SELQ_STR + ks * 32 + koff);
      sa = MFMA16(a, bb, sa);
    }
    // P9 partial: G += sel_quarter . sel_quarter^T
    #pragma unroll
    for (int i2 = 0; i2 < 2; ++i2) {
      int idx = wv * 2 + i2;
      int gm = idx >> 2, gn = idx & 3;
      #pragma unroll
      for (int ks = 0; ks < 4; ++ks) {
        v8s a  = *(const v8s*)(s_sel + (gm * 16 + l15) * SELQ_STR + ks * 32 + koff);
        v8s bb = *(const v8s*)(s_sel + (gn * 16 + l15) * SELQ_STR + ks * 32 + koff);
        ga[i2] = MFMA16(a, bb, ga[i2]);
      }
    }
    __syncthreads();
  }

  // ---- write sims + G (overwrites capq/wa region, both dead now) ----
  #pragma unroll
  for (int reg = 0; reg < 4; ++reg)
    s_sims[(mt * 16 + quad * 4 + reg) * 64 + nt * 16 + l15] = sa[reg];
  #pragma unroll
  for (int i2 = 0; i2 < 2; ++i2) {
    int idx = wv * 2 + i2;
    int gm = idx >> 2, gn = idx & 3;
    #pragma unroll
    for (int reg = 0; reg < 4; ++reg)
      s_G[(gm * 16 + quad * 4 + reg) * G_STR + gn * 16 + l15] = ga[i2][reg];
  }
  __syncthreads();

  // ---- P8: per-word softmax (unnormalized e) + num = sum e*s ----
  if (tid < NW * 8) {
    int w = tid >> 3, g = tid & 7;
    float* row = s_sims + w * 64;
    float mm = -3e38f;
    for (int p = g; p < 50; p += 8) mm = fmaxf(mm, row[p]);
    #pragma unroll
    for (int off = 4; off > 0; off >>= 1) mm = fmaxf(mm, __shfl_xor(mm, off, 8));
    float num = 0.f;
    for (int p = g; p < 64; p += 8) {
      if (p < 50) {
        float s = row[p];
        float ee = expf(LAMBDA_ * (s - mm));
        num += ee * s;
        row[p] = ee;
      } else row[p] = 0.f;
    }
    #pragma unroll
    for (int off = 4; off > 0; off >>= 1) num += __shfl_xor(num, off, 8);
    if (g == 0) s_red[w] = num;
  }
  __syncthreads();

  // ---- P10: word_sim = num / sqrt(e^T G e); mean over words ----
  float wacc = 0.f;
  for (int w = wv; w < NW; w += 8) {
    const float* ev = s_sims + w * 64;
    float tl = 0.f;
    for (int q = 0; q < 50; ++q) tl += s_G[q * G_STR + lane] * ev[q];
    float ql = ev[lane] * tl;
    #pragma unroll
    for (int off = 32; off > 0; off >>= 1) ql += __shfl_xor(ql, off, 64);
    if (lane == 0) wacc += s_red[w] / fmaxf(sqrtf(ql), 1e-20f);
  }
  if (lane == 0) s_red[64 + wv] = wacc;
  __syncthreads();
  if (tid == 0) {
    float s = 0.f;
    #pragma unroll
    for (int i = 0; i < 8; ++i) s += s_red[64 + i];
    out[(size_t)v * BT + t] = s / (float)NW;
  }
}

// ---------------------------------------------------------------------------
extern "C" void kernel_launch(void* const* d_in, const int* in_sizes, int n_in,
                              void* d_out, int out_size, void* d_ws, size_t ws_size,
                              hipStream_t stream) {
  const float* img   = (const float*)d_in[0];
  const float* cap   = (const float*)d_in[1];
  // d_in[2] = cap_lens (unused by forward)
  const float* gamma = (const float*)d_in[3];
  const float* beta  = (const float*)d_in[4];
  const float* W1    = (const float*)d_in[5];
  const float* b1    = (const float*)d_in[6];
  const float* W2    = (const float*)d_in[7];
  const float* b2    = (const float*)d_in[8];
  const float* scale = (const float*)d_in[9];
  float* ws  = (float*)d_ws;
  float* out = (float*)d_out;

  const bool big = (ws_size >= WS_NEED_B);   // constant across calls -> graph-safe

  if (big) {
    k0_prep<<<dim3(BV, 8), dim3(512), 0, stream>>>(img, W1, W2, ws);
    k1_glo<1><<<dim3(BT + BV), dim3(256), 0, stream>>>(img, cap, ws);
  } else {
    k5_prep<<<dim3(176), dim3(512), 0, stream>>>(W1, W2, ws);
    k1_glo<0><<<dim3(BT + BV), dim3(256), 0, stream>>>(img, cap, ws);
  }
  k2_mlp <<<dim3(BV, 7), dim3(512), 0, stream>>>(img, gamma, beta, b1, b2, ws);
  k3_score<<<dim3(BV, 4), dim3(512), 0, stream>>>(img, ws);
  if (big) k4_big<<<dim3(BV * BT), dim3(512), 0, stream>>>(img, scale, ws, out);
  else     k4_main<0><<<dim3(BV * BT), dim3(512), 0, stream>>>(img, scale, ws, out);
}

// Round 10
// 286.639 us; speedup vs baseline: 1.6091x; 1.0579x over previous
//
#include <hip/hip_runtime.h>
#include <hip/hip_bf16.h>
#include <math.h>

#define CDIM 512
#define LV 196
#define BV 64
#define BT 32
#define NW 24
#define NKEEP 98
#define NNON 98      // LV - NKEEP
#define KEEPED 49
#define HID 102
#define LAMBDA_ 4.0f
#define LN_EPS_ 1e-5f

// ws layout (float offsets)
#define WS_CAPNORM 0
#define WS_CAPGLO  (WS_CAPNORM + BT*NW*CDIM)     // 393216
#define WS_IMGGLO  (WS_CAPGLO + BT*CDIM)         // +16384
#define WS_INVN    (WS_IMGGLO + BV*CDIM)         // +32768
#define WS_WLOG    (WS_INVN + BV*LV)             // +12544
#define WS_SCORE   (WS_WLOG + BV*LV*KEEPED)      // +614656
#define WS_END     (WS_SCORE + BT*BV*LV)         // 1470976 floats = 5.88 MB
// imgT (big path only): bf16 [64][512][224] appended after WS_END
#define WS_IMGT_B  ((size_t)WS_END * 4)          // byte offset 5883904
#define TOKPAD 224
#define WS_NEED_B  (WS_IMGT_B + (size_t)BV * CDIM * TOKPAD * 2)   // 20563968 B
// W1T/W2T (bf16) live at the base of the WS_SCORE region (32,768 floats);
// IPART (img column partial sums, [7][64][512] f32 = 229,376 floats) lives at
// WS_SCORE+40960 (ends 270,336 <= 401,408). Written by k0, read by k2 seg 7,
// then the whole SCORE region is overwritten by k3 (stream-ordered). IPART
// must NOT alias WLOG: k2 main blocks write WLOG concurrently with seg 7.
#define WS_W1T_B   ((size_t)WS_SCORE * 4)
#define WS_W2T_B   (WS_W1T_B + (size_t)112 * 512 * 2)
#define WS_IPART   (WS_SCORE + 40960)

typedef short v8s __attribute__((ext_vector_type(8)));   // 8 bf16 (4 VGPR)
typedef float v4f __attribute__((ext_vector_type(4)));
#define MFMA16(a, b, c) __builtin_amdgcn_mfma_f32_16x16x32_bf16((a), (b), (c), 0, 0, 0)

// LDS strides (elements), padded for bank behavior + alignment:
#define WA_STR 232    // A matrix rows (464 B, 16-aligned, 2-way banks)
#define TOK_STR 40    // token K-tile rows (80 B, 16-aligned)
#define SEL_STR 520   // sel rows (1040 B, 16-aligned, 2-way banks) [fallback k4]
#define G_STR 66      // Gram rows (f32)
#define XN_STR 520    // k2 xn rows (bf16)
#define HB_STR 136    // k2 hbuf rows (bf16; 136=2-way banks, not pow2)

// k4_big LDS plan (R12/r5, total 51968 B; measured 148-150 us, VGPR 64):
// R2 [0, 19216): s_w fp32 19208 (P3->P4) THEN sel quarter bf16 [64][136]=17408
// R1 [19216, 48912): wa bf16 [64][232]=29696 (P4->P5);
//   THEN cap quarter bf16 [24][136]=6528 (quarter loop)
//   THEN sims f32 [32][64]=8192 + G f32 [64][66]=16896 (after quarter loop)
// Occupancy: unified VGPR+AGPR file -> 64 VGPR + 64 AGPR acc = 128 regs =
// 2 blocks/CU (settled; (512,6) spills r3/r4, P5-fusion r6 regressed).
#define SELQ_STR 136  // 272 B rows
#define CAPQ_STR 136
#define K4_SMEM   51968
#define OFF_SEL   0
#define OFF_WA    19216
#define OFF_CAPQ  19216
#define OFF_SIMS  19216
#define OFF_G     27408    // ends 44304 (<= 48912)
#define OFF_SC    48912
#define OFF_KIDX  49696
#define OFF_NIDX  50088
#define OFF_CNT   50480
#define OFF_WK    50496
#define OFF_RED   50896
#define OFF_POOL2 51408
#define OFF_INV   51664    // ends 51920

__device__ __forceinline__ ushort bfb(float f) {
  __hip_bfloat16 h = __float2bfloat16(f);
  union { __hip_bfloat16 h; ushort u; } cv; cv.h = h; return cv.u;
}

// ---------------------------------------------------------------------------
// K0 (big path only): grid (BV, 9).
// planes 0..6: imgT[v][c][tok] bf16 (tok padded 196->224) + img column
//   partial sums -> WS_IPART[kt][v][c] (consumed by k2 seg 7).
// plane 7: W1T/W2T transpose (v<56: W1T rows 2v,2v+1; v>=56: W2T).
// plane 8 (R17): cap_norm + cap_glo (v<32; folded from k1 -> one fewer launch).
// ---------------------------------------------------------------------------
__global__ __launch_bounds__(512) void k0_prep(const float* __restrict__ img,
                                               const float* __restrict__ cap,
                                               const float* __restrict__ W1,
                                               const float* __restrict__ W2,
                                               float* __restrict__ ws) {
  __shared__ float s_part[8 * CDIM];
  __shared__ float s_glo[CDIM];
  __shared__ float red[128];
  int v = blockIdx.x, kt = blockIdx.y, c = threadIdx.x;
  if (kt == 8) {
    if (v >= BT) return;
    int t = v;
    int wv = c >> 6, lane = c & 63;
    int cb = lane * 8;
    float4 sA = make_float4(0.f,0.f,0.f,0.f), sB = make_float4(0.f,0.f,0.f,0.f);
    for (int w = wv; w < NW; w += 8) {
      const float* p = cap + ((size_t)t * NW + w) * CDIM + cb;
      float4 xa = *(const float4*)p;
      float4 xb = *(const float4*)(p + 4);
      float ss = xa.x*xa.x + xa.y*xa.y + xa.z*xa.z + xa.w*xa.w
               + xb.x*xb.x + xb.y*xb.y + xb.z*xb.z + xb.w*xb.w;
      #pragma unroll
      for (int off = 32; off > 0; off >>= 1) ss += __shfl_xor(ss, off, 64);
      float inv = 1.f / fmaxf(sqrtf(ss), 1e-12f);
      float* q = ws + WS_CAPNORM + ((size_t)t * NW + w) * CDIM + cb;
      *(float4*)q       = make_float4(xa.x*inv, xa.y*inv, xa.z*inv, xa.w*inv);
      *(float4*)(q + 4) = make_float4(xb.x*inv, xb.y*inv, xb.z*inv, xb.w*inv);
      sA.x += xa.x; sA.y += xa.y; sA.z += xa.z; sA.w += xa.w;
      sB.x += xb.x; sB.y += xb.y; sB.z += xb.z; sB.w += xb.w;
    }
    *(float4*)&s_part[wv * CDIM + cb]     = sA;
    *(float4*)&s_part[wv * CDIM + cb + 4] = sB;
    __syncthreads();
    if (c < 128) {
      float4 g = make_float4(0.f, 0.f, 0.f, 0.f);
      #pragma unroll
      for (int w2 = 0; w2 < 8; ++w2) {
        float4 pv = *(const float4*)&s_part[w2 * CDIM + c * 4];
        g.x += pv.x; g.y += pv.y; g.z += pv.z; g.w += pv.w;
      }
      g.x /= (float)NW; g.y /= (float)NW; g.z /= (float)NW; g.w /= (float)NW;
      *(float4*)&s_glo[c * 4] = g;
      red[c] = g.x*g.x + g.y*g.y + g.z*g.z + g.w*g.w;
    }
    __syncthreads();
    for (int off = 64; off > 0; off >>= 1) {
      if (c < off) red[c] += red[c + off];
      __syncthreads();
    }
    float inv = 1.f / fmaxf(sqrtf(red[0]), 1e-12f);
    if (c < 128) {
      float4 g = *(const float4*)&s_glo[c * 4];
      *(float4*)(ws + WS_CAPGLO + (size_t)t * CDIM + c * 4) =
          make_float4(g.x*inv, g.y*inv, g.z*inv, g.w*inv);
    }
    return;
  }
  if (kt == 7) {
    if (v < 56) {
      #pragma unroll
      for (int r = 0; r < 2; ++r) {
        int h = v * 2 + r;
        float val = (h < HID) ? W1[(size_t)c * HID + h] : 0.f;
        ((ushort*)((char*)ws + WS_W1T_B))[(size_t)h * 512 + c] = bfb(val);
      }
    } else {
      for (int e = c; e < 1024; e += 512) {
        int idx = (v - 56) * 1024 + e;
        int p = idx >> 7, h = idx & 127;
        float val = (p < KEEPED && h < HID) ? W2[(size_t)h * KEEPED + p] : 0.f;
        ((ushort*)((char*)ws + WS_W2T_B))[(size_t)p * 128 + h] = bfb(val);
      }
    }
    return;
  }
  float x[32];
  #pragma unroll
  for (int kk = 0; kk < 32; ++kk) {
    int tok = kt * 32 + kk;
    x[kk] = (tok < LV) ? img[((size_t)v * LV + tok) * CDIM + c] : 0.f;
  }
  // column partial sum for img_glo (tok >= LV contributed 0)
  {
    float s = 0.f;
    #pragma unroll
    for (int kk = 0; kk < 32; ++kk) s += x[kk];
    ws[WS_IPART + ((size_t)kt * BV + v) * CDIM + c] = s;
  }
  __hip_bfloat16* imgT = (__hip_bfloat16*)((char*)ws + WS_IMGT_B);
  uint* dst = (uint*)(imgT + ((size_t)v * CDIM + c) * TOKPAD + kt * 32);
  #pragma unroll
  for (int g = 0; g < 4; ++g) {
    uint4 u;
    u.x = (uint)bfb(x[g*8+0]) | ((uint)bfb(x[g*8+1]) << 16);
    u.y = (uint)bfb(x[g*8+2]) | ((uint)bfb(x[g*8+3]) << 16);
    u.z = (uint)bfb(x[g*8+4]) | ((uint)bfb(x[g*8+5]) << 16);
    u.w = (uint)bfb(x[g*8+6]) | ((uint)bfb(x[g*8+7]) << 16);
    *(uint4*)(dst + g * 4) = u;
  }
}

// ---------------------------------------------------------------------------
// K5 (small path only): transpose W1 -> W1T, W2 -> W2T.
// ---------------------------------------------------------------------------
__global__ __launch_bounds__(512) void k5_prep(const float* __restrict__ W1,
                                               const float* __restrict__ W2,
                                               float* __restrict__ ws) {
  int b = blockIdx.x, tid = threadIdx.x;
  if (b < 112) {
    int h = b;
    float val = (h < HID) ? W1[(size_t)tid * HID + h] : 0.f;
    ((ushort*)((char*)ws + WS_W1T_B))[(size_t)h * 512 + tid] = bfb(val);
  } else {
    int p = b - 112;
    if (tid < 128) {
      int h = tid;
      float val = (p < KEEPED && h < HID) ? W2[(size_t)h * KEEPED + p] : 0.f;
      ((ushort*)((char*)ws + WS_W2T_B))[(size_t)p * 128 + h] = bfb(val);
    }
  }
}

// ---------------------------------------------------------------------------
// K1 (small path only): cap_norm + cap_glo (blocks 0..31), img_glo (32..95).
// ---------------------------------------------------------------------------
__global__ __launch_bounds__(256) void k1_glo(const float* __restrict__ img,
                                              const float* __restrict__ cap,
                                              float* __restrict__ ws) {
  __shared__ float red[256];
  __shared__ float s_part[4 * CDIM];
  __shared__ float s_glo[CDIM];
  int b = blockIdx.x, tid = threadIdx.x;
  if (b < BT) {
    int t = b;
    int wv = tid >> 6, lane = tid & 63;
    int cb = lane * 8;
    float4 sA = make_float4(0.f,0.f,0.f,0.f), sB = make_float4(0.f,0.f,0.f,0.f);
    for (int w = wv; w < NW; w += 4) {
      const float* p = cap + ((size_t)t * NW + w) * CDIM + cb;
      float4 xa = *(const float4*)p;
      float4 xb = *(const float4*)(p + 4);
      float ss = xa.x*xa.x + xa.y*xa.y + xa.z*xa.z + xa.w*xa.w
               + xb.x*xb.x + xb.y*xb.y + xb.z*xb.z + xb.w*xb.w;
      #pragma unroll
      for (int off = 32; off > 0; off >>= 1) ss += __shfl_xor(ss, off, 64);
      float inv = 1.f / fmaxf(sqrtf(ss), 1e-12f);
      float* q = ws + WS_CAPNORM + ((size_t)t * NW + w) * CDIM + cb;
      *(float4*)q       = make_float4(xa.x*inv, xa.y*inv, xa.z*inv, xa.w*inv);
      *(float4*)(q + 4) = make_float4(xb.x*inv, xb.y*inv, xb.z*inv, xb.w*inv);
      sA.x += xa.x; sA.y += xa.y; sA.z += xa.z; sA.w += xa.w;
      sB.x += xb.x; sB.y += xb.y; sB.z += xb.z; sB.w += xb.w;
    }
    *(float4*)&s_part[wv * CDIM + cb]     = sA;
    *(float4*)&s_part[wv * CDIM + cb + 4] = sB;
    __syncthreads();
    if (tid < 128) {
      float4 g = make_float4(0.f, 0.f, 0.f, 0.f);
      #pragma unroll
      for (int w2 = 0; w2 < 4; ++w2) {
        float4 pv = *(const float4*)&s_part[w2 * CDIM + tid * 4];
        g.x += pv.x; g.y += pv.y; g.z += pv.z; g.w += pv.w;
      }
      g.x /= (float)NW; g.y /= (float)NW; g.z /= (float)NW; g.w /= (float)NW;
      *(float4*)&s_glo[tid * 4] = g;
      red[tid] = g.x*g.x + g.y*g.y + g.z*g.z + g.w*g.w;
    }
    __syncthreads();
    for (int off = 64; off > 0; off >>= 1) {
      if (tid < off) red[tid] += red[tid + off];
      __syncthreads();
    }
    float inv = 1.f / fmaxf(sqrtf(red[0]), 1e-12f);
    if (tid < 128) {
      float4 g = *(const float4*)&s_glo[tid * 4];
      *(float4*)(ws + WS_CAPGLO + (size_t)t * CDIM + tid * 4) =
          make_float4(g.x*inv, g.y*inv, g.z*inv, g.w*inv);
    }
  } else {
    int v = b - BT;
    int wv = tid >> 6, lane = tid & 63;
    int cb = lane * 8;
    const float* base = img + (size_t)v * LV * CDIM;
    float4 sA = make_float4(0.f,0.f,0.f,0.f), sB = make_float4(0.f,0.f,0.f,0.f);
    int l0 = wv * 49;                         // 4 waves x 49 rows = 196
    for (int l = l0; l < l0 + 49; ++l) {
      const float* p = base + (size_t)l * CDIM + cb;
      float4 xa = *(const float4*)p;
      float4 xb = *(const float4*)(p + 4);
      sA.x += xa.x; sA.y += xa.y; sA.z += xa.z; sA.w += xa.w;
      sB.x += xb.x; sB.y += xb.y; sB.z += xb.z; sB.w += xb.w;
    }
    *(float4*)&s_part[wv * CDIM + cb]     = sA;
    *(float4*)&s_part[wv * CDIM + cb + 4] = sB;
    __syncthreads();
    if (tid < 128) {
      float4 g = make_float4(0.f, 0.f, 0.f, 0.f);
      #pragma unroll
      for (int w2 = 0; w2 < 4; ++w2) {
        float4 pv = *(const float4*)&s_part[w2 * CDIM + tid * 4];
        g.x += pv.x; g.y += pv.y; g.z += pv.z; g.w += pv.w;
      }
      g.x /= (float)LV; g.y /= (float)LV; g.z /= (float)LV; g.w /= (float)LV;
      *(float4*)&s_glo[tid * 4] = g;
      red[tid] = g.x*g.x + g.y*g.y + g.z*g.z + g.w*g.w;
    }
    __syncthreads();
    for (int off = 64; off > 0; off >>= 1) {
      if (tid < off) red[tid] += red[tid + off];
      __syncthreads();
    }
    float inv = 1.f / fmaxf(sqrtf(red[0]), 1e-12f);
    if (tid < 128) {
      float4 g = *(const float4*)&s_glo[tid * 4];
      *(float4*)(ws + WS_IMGGLO + (size_t)v * CDIM + tid * 4) =
          make_float4(g.x*inv, g.y*inv, g.z*inv, g.w*inv);
    }
  }
}

// ---------------------------------------------------------------------------
// K2: MFMA MLP. grid (64 v, 7 segs of 28 tokens [+ seg 7 on big path]).
// seg 7 (R17, big only): img_glo fold from WS_IPART (written by k0; IPART is
// in the SCORE region so it does NOT race with main blocks' WLOG writes).
// ---------------------------------------------------------------------------
__global__ __launch_bounds__(512, 4) void k2_mlp(const float* __restrict__ img,
                                                 const float* __restrict__ gamma,
                                                 const float* __restrict__ beta,
                                                 const float* __restrict__ b1,
                                                 const float* __restrict__ b2,
                                                 float* __restrict__ ws) {
  __shared__ __align__(16) __hip_bfloat16 s_xn[32 * XN_STR];  // 33,280 B
  __hip_bfloat16* s_hb = s_xn;                                // overlay after GEMM1

  int v = blockIdx.x, seg = blockIdx.y;
  int tid = threadIdx.x, wv = tid >> 6, lane = tid & 63;

  if (seg == 7) {
    // img_glo fold: 512 threads, one column each.
    float* sc = (float*)s_xn;     // 9 floats scratch
    float s0 = 0.f;
    #pragma unroll
    for (int kt = 0; kt < 7; ++kt)
      s0 += ws[WS_IPART + ((size_t)kt * BV + v) * CDIM + tid];
    float g = s0 / (float)LV;
    float ss = g * g;
    #pragma unroll
    for (int off = 32; off > 0; off >>= 1) ss += __shfl_xor(ss, off, 64);
    if (lane == 0) sc[wv] = ss;
    __syncthreads();
    if (tid == 0) {
      float tot = 0.f;
      #pragma unroll
      for (int i = 0; i < 8; ++i) tot += sc[i];
      sc[8] = 1.f / fmaxf(sqrtf(tot), 1e-12f);
    }
    __syncthreads();
    ws[WS_IMGGLO + (size_t)v * CDIM + tid] = g * sc[8];
    return;
  }

  int l0 = seg * 28;
  int quad = lane >> 4, l15 = lane & 15, koff = quad * 8;
  const __hip_bfloat16* W1T = (const __hip_bfloat16*)((const char*)ws + WS_W1T_B);
  const __hip_bfloat16* W2T = (const __hip_bfloat16*)((const char*)ws + WS_W2T_B);

  // ---- Phase A: LN -> xn bf16 (28 tokens) ----
  int cb = lane * 8;
  float4 g4a = *(const float4*)(gamma + cb);
  float4 g4b = *(const float4*)(gamma + cb + 4);
  float4 b4a = *(const float4*)(beta + cb);
  float4 b4b = *(const float4*)(beta + cb + 4);
  for (int tok = wv; tok < 28; tok += 8) {
    const float* p = img + ((size_t)v * LV + l0 + tok) * CDIM + cb;
    float4 xa = *(const float4*)p;
    float4 xb = *(const float4*)(p + 4);
    float s  = xa.x + xa.y + xa.z + xa.w + xb.x + xb.y + xb.z + xb.w;
    float sq = xa.x*xa.x + xa.y*xa.y + xa.z*xa.z + xa.w*xa.w
             + xb.x*xb.x + xb.y*xb.y + xb.z*xb.z + xb.w*xb.w;
    #pragma unroll
    for (int off = 32; off > 0; off >>= 1) { s += __shfl_xor(s, off, 64); sq += __shfl_xor(sq, off, 64); }
    float mean = s / (float)CDIM;
    float var = sq / (float)CDIM - mean * mean;
    float rstd = 1.f / sqrtf(var + LN_EPS_);
    if (lane == 0) ws[WS_INVN + (size_t)v * LV + l0 + tok] = 1.f / fmaxf(sqrtf(sq), 1e-12f);
    float f[8];
    f[0] = (xa.x - mean) * rstd * g4a.x + b4a.x;
    f[1] = (xa.y - mean) * rstd * g4a.y + b4a.y;
    f[2] = (xa.z - mean) * rstd * g4a.z + b4a.z;
    f[3] = (xa.w - mean) * rstd * g4a.w + b4a.w;
    f[4] = (xb.x - mean) * rstd * g4b.x + b4b.x;
    f[5] = (xb.y - mean) * rstd * g4b.y + b4b.y;
    f[6] = (xb.z - mean) * rstd * g4b.z + b4b.z;
    f[7] = (xb.w - mean) * rstd * g4b.w + b4b.w;
    uint4 u;
    u.x = (uint)bfb(f[0]) | ((uint)bfb(f[1]) << 16);
    u.y = (uint)bfb(f[2]) | ((uint)bfb(f[3]) << 16);
    u.z = (uint)bfb(f[4]) | ((uint)bfb(f[5]) << 16);
    u.w = (uint)bfb(f[6]) | ((uint)bfb(f[7]) << 16);
    *(uint4*)(s_xn + (size_t)tok * XN_STR + cb) = u;
  }
  __syncthreads();

  // ---- GEMM1: C[32 tok][112 h], 2x7 = 14 tiles over 8 waves ----
  v4f c1[2];
  int mt_[2], nt_[2];
  #pragma unroll
  for (int i = 0; i < 2; ++i) {
    int idx = wv + 8 * i; if (idx > 13) idx = 13;   // clamp: keep reads in-bounds
    mt_[i] = idx / 7; nt_[i] = idx % 7;
    c1[i] = (v4f){0.f, 0.f, 0.f, 0.f};
  }
  for (int ks = 0; ks < 16; ++ks) {
    #pragma unroll
    for (int i = 0; i < 2; ++i) {
      v8s a  = *(const v8s*)(s_xn + (size_t)(mt_[i] * 16 + l15) * XN_STR + ks * 32 + koff);
      v8s bb = *(const v8s*)(W1T + (size_t)(nt_[i] * 16 + l15) * 512 + ks * 32 + koff);
      c1[i] = MFMA16(a, bb, c1[i]);
    }
  }
  __syncthreads();   // all xn reads complete before hbuf overlay

  // ---- gelu + bias -> hbuf [32][136] ----
  #pragma unroll
  for (int i = 0; i < 2; ++i) {
    int idx = wv + 8 * i;
    if (idx < 14) {
      int h = nt_[i] * 16 + l15;
      float bias = (h < HID) ? b1[h] : 0.f;
      #pragma unroll
      for (int reg = 0; reg < 4; ++reg) {
        int row = mt_[i] * 16 + quad * 4 + reg;
        float x = c1[i][reg] + bias;
        float gl = (h < HID) ? 0.5f * x * (1.f + erff(x * 0.70710678118654752f)) : 0.f;
        s_hb[(size_t)row * HB_STR + h] = __float2bfloat16(gl);
      }
    }
  }
  for (int i = tid; i < 32 * 16; i += 512)   // zero cols 112..127 (K pad)
    s_hb[(size_t)(i >> 4) * HB_STR + 112 + (i & 15)] = __float2bfloat16(0.f);
  __syncthreads();

  // ---- GEMM2: C[32 tok][64 p], 2x4 = 8 tiles = 1/wave, K=128 ----
  int m2 = wv >> 2, n2 = wv & 3;
  v4f c2 = (v4f){0.f, 0.f, 0.f, 0.f};
  for (int ks = 0; ks < 4; ++ks) {
    v8s a  = *(const v8s*)(s_hb + (size_t)(m2 * 16 + l15) * HB_STR + ks * 32 + koff);
    v8s bb = *(const v8s*)(W2T + (size_t)(n2 * 16 + l15) * 128 + ks * 32 + koff);
    c2 = MFMA16(a, bb, c2);
  }
  {
    int p = n2 * 16 + l15;
    if (p < KEEPED) {
      float bias = b2[p];
      #pragma unroll
      for (int reg = 0; reg < 4; ++reg) {
        int tok = m2 * 16 + quad * 4 + reg;
        if (tok < 28)
          ws[WS_WLOG + ((size_t)v * LV + l0 + tok) * KEEPED + p] = c2[reg] + bias;
      }
    }
  }
}

// ---------------------------------------------------------------------------
// K3: scores. R17: 1024 threads — queries split 16-way (q = qg + 16*qi,
// qi<3); per-(q,l) accumulation order unchanged -> bitwise-identical scores.
// float2 LDS reads (xt stride 66).
// ---------------------------------------------------------------------------
__global__ __launch_bounds__(1024) void k3_score(const float* __restrict__ img,
                                                 float* __restrict__ ws) {
  __shared__ __align__(16) float qt[33 * 64];
  __shared__ __align__(16) float xt[64 * 66];
  __shared__ float dself[64];
  int v = blockIdx.x;
  int t0 = blockIdx.y * 64;
  int tid = threadIdx.x;
  int tloc = tid & 63, qg = tid >> 6;   // qg 0..15
  float acc[3];
  #pragma unroll
  for (int i = 0; i < 3; ++i) acc[i] = 0.f;
  const float* capglo = ws + WS_CAPGLO;
  const float* imgglo = ws + WS_IMGGLO + (size_t)v * CDIM;

  for (int ct = 0; ct < 8; ++ct) {
    for (int i = tid; i < 33 * 64; i += 1024) {
      int q = i >> 6, cc = i & 63;
      qt[i] = (q < 32) ? capglo[(size_t)q * CDIM + ct * 64 + cc] : imgglo[ct * 64 + cc];
    }
    for (int i = tid; i < 64 * 64; i += 1024) {
      int tok = i >> 6, cc = i & 63;
      int l = t0 + tok;
      xt[tok * 66 + cc] = (l < LV) ? img[((size_t)v * LV + l) * CDIM + ct * 64 + cc] : 0.f;
    }
    __syncthreads();
    for (int cc2 = 0; cc2 < 32; ++cc2) {
      float2 xv = *(const float2*)&xt[tloc * 66 + cc2 * 2];
      #pragma unroll
      for (int qi = 0; qi < 3; ++qi) {
        int q = qg + 16 * qi;
        if (q < 33) {
          float2 qv = *(const float2*)&qt[q * 64 + cc2 * 2];
          acc[qi] += qv.x * xv.x;
          acc[qi] += qv.y * xv.y;
        }
      }
    }
    __syncthreads();
  }
  if (qg == 0) dself[tloc] = acc[2];    // q = 0 + 16*2 = 32 (self query)
  __syncthreads();
  int l = t0 + tloc;
  if (l < LV) {
    float invn = ws[WS_INVN + (size_t)v * LV + l];
    float ds = dself[tloc];
    #pragma unroll
    for (int qi = 0; qi < 3; ++qi) {
      int q = qg + 16 * qi;
      if (q < 32) ws[WS_SCORE + ((size_t)q * BV + v) * LV + l] = (acc[qi] + ds) * invn;
    }
  }
}

// ---------------------------------------------------------------------------
// K4 fallback (small ws): verbatim old template, only <0> instantiated.
// ---------------------------------------------------------------------------
template<int USE_IMGT>
__global__ __launch_bounds__(512, 2) void k4_main(const float* __restrict__ img,
                                                  const float* __restrict__ scale_p,
                                                  const float* __restrict__ ws,
                                                  float* __restrict__ out) {
  __shared__ float s_sc[LV];
  __shared__ int   s_kidx[NKEEP];
  __shared__ int   s_nidx[NNON];
  __shared__ int   s_cnt[2];
  __shared__ float s_wk[NNON];
  __shared__ float s_red[128];
  __shared__ float s_pool2[64];
  __shared__ float s_inv[64];
  __shared__ __align__(16) __hip_bfloat16 s_selh[64 * SEL_STR];
  __shared__ __align__(16) __hip_bfloat16 s_wa[64 * WA_STR];
  __shared__ __align__(16) __hip_bfloat16 s_dyn[512 * TOK_STR];

  float* s_w = (float*)s_dyn;
  __hip_bfloat16* s_tok = s_dyn;
  __hip_bfloat16* s_cap = s_dyn;
  float* s_sims = (float*)s_wa;
  float* s_G = (float*)((char*)s_wa + 8192);

  int b = blockIdx.x;
  int v = b >> 5, t = b & 31;
  int tid = threadIdx.x;
  int wv = tid >> 6, lane = tid & 63;
  int quad = lane >> 4, l15 = lane & 15;
  int koff = quad * 8;

  if (tid < 2) s_cnt[tid] = 0;
  if (tid < 64) s_pool2[tid] = 0.f;
  if (tid < LV) s_sc[tid] = ws[WS_SCORE + ((size_t)t * BV + v) * LV + tid];
  {
    uint* za = (uint*)s_wa;
    for (int i = tid; i < 64 * WA_STR / 2; i += 512) za[i] = 0u;
    uint* zs = (uint*)(s_selh + 50 * SEL_STR);
    for (int i = tid; i < 14 * SEL_STR / 2; i += 512) zs[i] = 0u;
  }
  __syncthreads();

  if (tid < LV) {
    float my = s_sc[tid];
    int cnt = 0;
    for (int j = 0; j < LV; ++j) {
      float sj = s_sc[j];
      cnt += (sj > my) || (sj == my && j < tid);
    }
    bool keep = cnt < NKEEP;
    out[BV * BT + ((size_t)t * BV + v) * LV + tid] = keep ? 1.f : 0.f;
    if (keep) { int p = atomicAdd(&s_cnt[0], 1); s_kidx[p] = tid; }
    else      { int p = atomicAdd(&s_cnt[1], 1); s_nidx[p] = tid; }
  }
  __syncthreads();

  if (tid < 128) s_red[tid] = (tid < NNON) ? s_sc[s_nidx[tid]] : -3.0e38f;
  __syncthreads();
  for (int off = 64; off > 0; off >>= 1) {
    if (tid < off) s_red[tid] = fmaxf(s_red[tid], s_red[tid + off]);
    __syncthreads();
  }
  float nm = s_red[0];
  __syncthreads();
  float e0 = 0.f;
  if (tid < NNON) e0 = expf(s_sc[s_nidx[tid]] - nm);
  if (tid < 128) s_red[tid] = (tid < NNON) ? e0 : 0.f;
  __syncthreads();
  for (int off = 64; off > 0; off >>= 1) {
    if (tid < off) s_red[tid] += s_red[tid + off];
    __syncthreads();
  }
  float nS = s_red[0];
  __syncthreads();
  if (tid < NNON) s_wk[tid] = e0 / nS;
  __syncthreads();

  float scale_val = scale_p[0];
  for (int i = tid; i < KEEPED * NKEEP; i += 512) {
    int k = i / KEEPED, p = i - k * KEEPED;
    s_w[p * NKEEP + k] = ws[WS_WLOG + ((size_t)v * LV + s_kidx[k]) * KEEPED + p] * scale_val;
  }
  __syncthreads();
  if (tid < KEEPED * 8) {
    int p = tid >> 3, g = tid & 7;
    float mm = -3e38f;
    for (int k = g; k < NKEEP; k += 8) mm = fmaxf(mm, s_w[p * NKEEP + k]);
    #pragma unroll
    for (int off = 4; off > 0; off >>= 1) mm = fmaxf(mm, __shfl_xor(mm, off, 8));
    float ss = 0.f;
    for (int k = g; k < NKEEP; k += 8) {
      float ee = expf(s_w[p * NKEEP + k] - mm);
      s_w[p * NKEEP + k] = ee;
      ss += ee;
    }
    #pragma unroll
    for (int off = 4; off > 0; off >>= 1) ss += __shfl_xor(ss, off, 8);
    float rs = 1.f / ss;
    for (int k = g; k < NKEEP; k += 8) s_w[p * NKEEP + k] *= rs;
  }
  __syncthreads();

  for (int i = tid; i < KEEPED * NKEEP; i += 512) {
    int p = i / NKEEP, r = i - p * NKEEP;
    s_wa[p * WA_STR + s_kidx[r]] = __float2bfloat16(s_w[p * NKEEP + r]);
  }
  if (tid < NNON) s_wa[49 * WA_STR + s_nidx[tid]] = __float2bfloat16(s_wk[tid]);
  __syncthreads();

  v4f acc[4][4];
  #pragma unroll
  for (int m = 0; m < 4; ++m)
    #pragma unroll
    for (int j = 0; j < 4; ++j) acc[m][j] = (v4f){0.f, 0.f, 0.f, 0.f};

  if (USE_IMGT) {
    const __hip_bfloat16* imgTv =
        (const __hip_bfloat16*)((const char*)ws + WS_IMGT_B) + (size_t)v * CDIM * TOKPAD;
    for (int ks = 0; ks < 7; ++ks) {
      v8s bfr[4];
      #pragma unroll
      for (int j = 0; j < 4; ++j)
        bfr[j] = *(const v8s*)(imgTv + (size_t)(wv * 64 + j * 16 + l15) * TOKPAD + ks * 32 + koff);
      #pragma unroll
      for (int m = 0; m < 4; ++m) {
        v8s af = *(const v8s*)(s_wa + (m * 16 + l15) * WA_STR + ks * 32 + koff);
        #pragma unroll
        for (int j = 0; j < 4; ++j) acc[m][j] = MFMA16(af, bfr[j], acc[m][j]);
      }
    }
  } else {
    for (int ks = 0; ks < 7; ++ks) {
      #pragma unroll
      for (int it = 0; it < 8; ++it) {
        int k0 = ks * 32 + it * 4;
        if (k0 < LV) {
          const float* gp = img + ((size_t)v * LV + k0) * CDIM + tid;
          float x0 = gp[0], x1 = gp[CDIM], x2 = gp[2 * CDIM], x3 = gp[3 * CDIM];
          union { __hip_bfloat16 h[4]; uint2 u; } pk;
          pk.h[0] = __float2bfloat16(x0); pk.h[1] = __float2bfloat16(x1);
          pk.h[2] = __float2bfloat16(x2); pk.h[3] = __float2bfloat16(x3);
          *(uint2*)(s_tok + tid * TOK_STR + it * 4) = pk.u;
        }
      }
      __syncthreads();
      v8s bfr[4];
      #pragma unroll
      for (int j = 0; j < 4; ++j)
        bfr[j] = *(const v8s*)(s_tok + (wv * 64 + j * 16 + l15) * TOK_STR + koff);
      #pragma unroll
      for (int m = 0; m < 4; ++m) {
        v8s af = *(const v8s*)(s_wa + (m * 16 + l15) * WA_STR + ks * 32 + koff);
        #pragma unroll
        for (int j = 0; j < 4; ++j) acc[m][j] = MFMA16(af, bfr[j], acc[m][j]);
      }
      __syncthreads();
    }
  }

  if (!USE_IMGT) __syncthreads();
  for (int i = tid; i < NW * 128; i += 512) {
    int w = i >> 7, cq = i & 127;
    const float4 xv = *(const float4*)(ws + WS_CAPNORM + ((size_t)t * NW + w) * CDIM + cq * 4);
    union { __hip_bfloat16 h[4]; uint2 u; } pk;
    pk.h[0] = __float2bfloat16(xv.x); pk.h[1] = __float2bfloat16(xv.y);
    pk.h[2] = __float2bfloat16(xv.z); pk.h[3] = __float2bfloat16(xv.w);
    *(uint2*)(s_cap + w * SEL_STR + cq * 4) = pk.u;
  }
  {
    uint* zc = (uint*)(s_cap + 24 * SEL_STR);
    for (int i = tid; i < 8 * SEL_STR / 2; i += 512) zc[i] = 0u;
  }
  #pragma unroll
  for (int m = 0; m < 4; ++m) {
    #pragma unroll
    for (int reg = 0; reg < 4; ++reg) {
      float ss = acc[m][0][reg] * acc[m][0][reg] + acc[m][1][reg] * acc[m][1][reg]
               + acc[m][2][reg] * acc[m][2][reg] + acc[m][3][reg] * acc[m][3][reg];
      #pragma unroll
      for (int off = 8; off > 0; off >>= 1) ss += __shfl_xor(ss, off, 64);
      if (l15 == 0) atomicAdd(&s_pool2[m * 16 + quad * 4 + reg], ss);
    }
  }
  __syncthreads();
  if (tid < 64) s_inv[tid] = 1.f / fmaxf(sqrtf(s_pool2[tid]), 1e-12f);
  __syncthreads();
  #pragma unroll
  for (int m = 0; m < 4; ++m) {
    #pragma unroll
    for (int reg = 0; reg < 4; ++reg) {
      int p = m * 16 + quad * 4 + reg;
      if (p < 50) {
        float iv = s_inv[p];
        #pragma unroll
        for (int j = 0; j < 4; ++j)
          s_selh[p * SEL_STR + wv * 64 + j * 16 + l15] = __float2bfloat16(acc[m][j][reg] * iv);
      }
    }
  }
  __syncthreads();

  {
    int mt = wv >> 2, nt = wv & 3;
    v4f sa = (v4f){0.f, 0.f, 0.f, 0.f};
    for (int ks = 0; ks < 16; ++ks) {
      v8s a = *(const v8s*)(s_cap + (mt * 16 + l15) * SEL_STR + ks * 32 + koff);
      v8s bb = *(const v8s*)(s_selh + (nt * 16 + l15) * SEL_STR + ks * 32 + koff);
      sa = MFMA16(a, bb, sa);
    }
    #pragma unroll
    for (int reg = 0; reg < 4; ++reg)
      s_sims[(mt * 16 + quad * 4 + reg) * 64 + nt * 16 + l15] = sa[reg];
  }
  __syncthreads();

  if (tid < NW * 8) {
    int w = tid >> 3, g = tid & 7;
    float* row = s_sims + w * 64;
    float mm = -3e38f;
    for (int p = g; p < 50; p += 8) mm = fmaxf(mm, row[p]);
    #pragma unroll
    for (int off = 4; off > 0; off >>= 1) mm = fmaxf(mm, __shfl_xor(mm, off, 8));
    float num = 0.f;
    for (int p = g; p < 64; p += 8) {
      if (p < 50) {
        float s = row[p];
        float ee = expf(LAMBDA_ * (s - mm));
        num += ee * s;
        row[p] = ee;
      } else row[p] = 0.f;
    }
    #pragma unroll
    for (int off = 4; off > 0; off >>= 1) num += __shfl_xor(num, off, 8);
    if (g == 0) s_red[w] = num;
  }
  __syncthreads();

  #pragma unroll
  for (int i2 = 0; i2 < 2; ++i2) {
    int idx = wv * 2 + i2;
    int gm = idx >> 2, gn = idx & 3;
    v4f ga = (v4f){0.f, 0.f, 0.f, 0.f};
    for (int ks = 0; ks < 16; ++ks) {
      v8s a = *(const v8s*)(s_selh + (gm * 16 + l15) * SEL_STR + ks * 32 + koff);
      v8s bb = *(const v8s*)(s_selh + (gn * 16 + l15) * SEL_STR + ks * 32 + koff);
      ga = MFMA16(a, bb, ga);
    }
    #pragma unroll
    for (int reg = 0; reg < 4; ++reg)
      s_G[(gm * 16 + quad * 4 + reg) * G_STR + gn * 16 + l15] = ga[reg];
  }
  __syncthreads();

  float wacc = 0.f;
  for (int w = wv; w < NW; w += 8) {
    const float* ev = s_sims + w * 64;
    float tl = 0.f;
    for (int q = 0; q < 50; ++q) tl += s_G[q * G_STR + lane] * ev[q];
    float ql = ev[lane] * tl;
    #pragma unroll
    for (int off = 32; off > 0; off >>= 1) ql += __shfl_xor(ql, off, 64);
    if (lane == 0) wacc += s_red[w] / fmaxf(sqrtf(ql), 1e-20f);
  }
  if (lane == 0) s_red[64 + wv] = wacc;
  __syncthreads();
  if (tid == 0) {
    float s = 0.f;
    #pragma unroll
    for (int i = 0; i < 8; ++i) s += s_red[64 + i];
    out[(size_t)v * BT + t] = s / (float)NW;
  }
}

// ---------------------------------------------------------------------------
// K4 big path (R16, unchanged from r9: 148.6 us): XCD swizzle + shuffle P2.
// ---------------------------------------------------------------------------
__global__ __launch_bounds__(512, 4) void k4_big(const float* __restrict__ img,
                                                 const float* __restrict__ scale_p,
                                                 const float* __restrict__ ws,
                                                 float* __restrict__ out) {
  __shared__ __align__(16) char smem[K4_SMEM];
  __hip_bfloat16* s_sel = (__hip_bfloat16*)(smem + OFF_SEL);   // [64][136] quarter
  float*          s_w   = (float*)(smem + OFF_SEL);            // overlay, P3/P4 only
  __hip_bfloat16* s_wa  = (__hip_bfloat16*)(smem + OFF_WA);    // [64][232] P4->P5
  __hip_bfloat16* s_capq= (__hip_bfloat16*)(smem + OFF_CAPQ);  // [24][136] loop only
  float*          s_sims= (float*)(smem + OFF_SIMS);           // [32][64] after loop
  float*          s_G   = (float*)(smem + OFF_G);              // [64][66] after loop
  float* s_sc    = (float*)(smem + OFF_SC);
  int*   s_kidx  = (int*)(smem + OFF_KIDX);
  int*   s_nidx  = (int*)(smem + OFF_NIDX);
  int*   s_cnt   = (int*)(smem + OFF_CNT);
  float* s_wk    = (float*)(smem + OFF_WK);
  float* s_red   = (float*)(smem + OFF_RED);
  float* s_pool2 = (float*)(smem + OFF_POOL2);
  float* s_inv   = (float*)(smem + OFF_INV);

  int b0 = blockIdx.x;
  int b = ((b0 & 7) << 8) | (b0 >> 3);   // XCD swizzle: same-v blocks co-locate
  int v = b >> 5, t = b & 31;
  int tid = threadIdx.x;
  int wv = tid >> 6, lane = tid & 63;
  int quad = lane >> 4, l15 = lane & 15;
  int koff = quad * 8;

  // ---- P0: loads + zero-init ----
  if (tid < 2) s_cnt[tid] = 0;
  if (tid < 64) s_pool2[tid] = 0.f;
  if (tid < LV) s_sc[tid] = ws[WS_SCORE + ((size_t)t * BV + v) * LV + tid];
  {
    uint* za = (uint*)s_wa;
    for (int i = tid; i < 64 * WA_STR / 2; i += 512) za[i] = 0u;
  }
  __syncthreads();

  // ---- P1: rank & partition ----
  if (tid < LV) {
    float my = s_sc[tid];
    int cnt = 0;
    for (int j = 0; j < LV; ++j) {
      float sj = s_sc[j];
      cnt += (sj > my) || (sj == my && j < tid);
    }
    bool keep = cnt < NKEEP;
    out[BV * BT + ((size_t)t * BV + v) * LV + tid] = keep ? 1.f : 0.f;
    if (keep) { int p = atomicAdd(&s_cnt[0], 1); s_kidx[p] = tid; }
    else      { int p = atomicAdd(&s_cnt[1], 1); s_nidx[p] = tid; }
  }
  __syncthreads();

  // ---- P2: softmax over non-kept scores -> s_wk, wave-shuffle form ----
  if (tid < 128) {
    float vmax = (tid < NNON) ? s_sc[s_nidx[tid]] : -3.0e38f;
    #pragma unroll
    for (int off = 32; off > 0; off >>= 1) vmax = fmaxf(vmax, __shfl_xor(vmax, off, 64));
    if ((tid & 63) == 0) s_red[tid >> 6] = vmax;
  }
  __syncthreads();
  float nm = fmaxf(s_red[0], s_red[1]);
  float e0 = 0.f;
  if (tid < 128) {
    float vs = 0.f;
    if (tid < NNON) { e0 = expf(s_sc[s_nidx[tid]] - nm); vs = e0; }
    #pragma unroll
    for (int off = 32; off > 0; off >>= 1) vs += __shfl_xor(vs, off, 64);
    if ((tid & 63) == 0) s_red[2 + (tid >> 6)] = vs;
  }
  __syncthreads();
  float nS = s_red[2] + s_red[3];
  if (tid < NNON) s_wk[tid] = e0 / nS;
  __syncthreads();

  // ---- P3: wlog gather -> s_w[p][r] fp32 (overlays sel region), softmax ----
  float scale_val = scale_p[0];
  for (int i = tid; i < KEEPED * NKEEP; i += 512) {
    int k = i / KEEPED, p = i - k * KEEPED;
    s_w[p * NKEEP + k] = ws[WS_WLOG + ((size_t)v * LV + s_kidx[k]) * KEEPED + p] * scale_val;
  }
  __syncthreads();
  if (tid < KEEPED * 8) {
    int p = tid >> 3, g = tid & 7;
    float mm = -3e38f;
    for (int k = g; k < NKEEP; k += 8) mm = fmaxf(mm, s_w[p * NKEEP + k]);
    #pragma unroll
    for (int off = 4; off > 0; off >>= 1) mm = fmaxf(mm, __shfl_xor(mm, off, 8));
    float ss = 0.f;
    for (int k = g; k < NKEEP; k += 8) {
      float ee = expf(s_w[p * NKEEP + k] - mm);
      s_w[p * NKEEP + k] = ee;
      ss += ee;
    }
    #pragma unroll
    for (int off = 4; off > 0; off >>= 1) ss += __shfl_xor(ss, off, 8);
    float rs = 1.f / ss;
    for (int k = g; k < NKEEP; k += 8) s_w[p * NKEEP + k] *= rs;
  }
  __syncthreads();

  // ---- P4: scatter A = s_wa (bf16): kept weights + wk row 49 ----
  for (int i = tid; i < KEEPED * NKEEP; i += 512) {
    int p = i / NKEEP, r = i - p * NKEEP;
    s_wa[p * WA_STR + s_kidx[r]] = __float2bfloat16(s_w[p * NKEEP + r]);
  }
  if (tid < NNON) s_wa[49 * WA_STR + s_nidx[tid]] = __float2bfloat16(s_wk[tid]);
  __syncthreads();

  // zero sel-quarter rows 50..63 (s_w dead after the barrier above; rows stay
  // zero across all four quarters — nobody writes p >= 50)
  {
    uint* zq = (uint*)(s_sel + 50 * SELQ_STR);
    for (int i = tid; i < 14 * SELQ_STR / 2; i += 512) zq[i] = 0u;
  }

  // ---- P5: aggr GEMM, B from global imgT ----
  v4f acc[4][4];
  #pragma unroll
  for (int m = 0; m < 4; ++m)
    #pragma unroll
    for (int j = 0; j < 4; ++j) acc[m][j] = (v4f){0.f, 0.f, 0.f, 0.f};

  {
    const __hip_bfloat16* imgTv =
        (const __hip_bfloat16*)((const char*)ws + WS_IMGT_B) + (size_t)v * CDIM * TOKPAD;
    for (int ks = 0; ks < 7; ++ks) {
      v8s bfr[4];
      #pragma unroll
      for (int j = 0; j < 4; ++j)
        bfr[j] = *(const v8s*)(imgTv + (size_t)(wv * 64 + j * 16 + l15) * TOKPAD + ks * 32 + koff);
      #pragma unroll
      for (int m = 0; m < 4; ++m) {
        v8s af = *(const v8s*)(s_wa + (m * 16 + l15) * WA_STR + ks * 32 + koff);
        #pragma unroll
        for (int j = 0; j < 4; ++j) acc[m][j] = MFMA16(af, bfr[j], acc[m][j]);
      }
    }
  }

  // ---- P6: pool l2norm (atomics into zeroed s_pool2) ----
  #pragma unroll
  for (int m = 0; m < 4; ++m) {
    #pragma unroll
    for (int reg = 0; reg < 4; ++reg) {
      float ss = acc[m][0][reg] * acc[m][0][reg] + acc[m][1][reg] * acc[m][1][reg]
               + acc[m][2][reg] * acc[m][2][reg] + acc[m][3][reg] * acc[m][3][reg];
      #pragma unroll
      for (int off = 8; off > 0; off >>= 1) ss += __shfl_xor(ss, off, 64);
      if (l15 == 0) atomicAdd(&s_pool2[m * 16 + quad * 4 + reg], ss);
    }
  }
  __syncthreads();
  if (tid < 64) s_inv[tid] = 1.f / fmaxf(sqrtf(s_pool2[tid]), 1e-12f);
  __syncthreads();

  // ---- pack normalized sel fragments: 64 f32 -> 32 uints (bf16 pairs) ----
  uint pk[4][4][2];
  #pragma unroll
  for (int m = 0; m < 4; ++m) {
    #pragma unroll
    for (int rp = 0; rp < 2; ++rp) {
      int p0 = m * 16 + quad * 4 + rp * 2;
      float iv0 = s_inv[p0], iv1 = s_inv[p0 + 1];
      #pragma unroll
      for (int j = 0; j < 4; ++j)
        pk[m][j][rp] = (uint)bfb(acc[m][j][2 * rp] * iv0)
                     | ((uint)bfb(acc[m][j][2 * rp + 1] * iv1) << 16);
    }
  }

  // ---- quarter loop: stage sel cols [q*128, q*128+128) (waves 2q,2q+1) and
  // cap quarter [24][128] (other 6 waves) in LDS; accumulate P7+P9.
  v4f sa = (v4f){0.f, 0.f, 0.f, 0.f};
  v4f ga[2];
  ga[0] = (v4f){0.f, 0.f, 0.f, 0.f};
  ga[1] = (v4f){0.f, 0.f, 0.f, 0.f};
  ushort* selw = (ushort*)s_sel;
  int mt = wv >> 2, nt = wv & 3;
  for (int q = 0; q < 4; ++q) {
    if ((wv >> 1) == q) {               // waves 2q, 2q+1 own cols q*128..+127
      int base = (wv & 1) * 64;
      #pragma unroll
      for (int m = 0; m < 4; ++m) {
        #pragma unroll
        for (int reg = 0; reg < 4; ++reg) {
          int p = m * 16 + quad * 4 + reg;
          if (p < 50) {
            #pragma unroll
            for (int j = 0; j < 4; ++j) {
              uint u = pk[m][j][reg >> 1];
              ushort val = (reg & 1) ? (ushort)(u >> 16) : (ushort)(u & 0xffffu);
              selw[p * SELQ_STR + base + j * 16 + l15] = val;
            }
          }
        }
      }
    } else {
      int rank = wv - (wv > 2 * q + 1 ? 2 : 0);   // 0..5 among 6 staging waves
      int lt = rank * 64 + lane;                  // 0..383
      for (int i = lt; i < NW * 32; i += 384) {
        int w = i >> 5, c4 = i & 31;
        float4 xv = *(const float4*)(ws + WS_CAPNORM + ((size_t)t * NW + w) * CDIM
                                     + q * 128 + c4 * 4);
        union { __hip_bfloat16 hh[4]; uint2 u; } pc;
        pc.hh[0] = __float2bfloat16(xv.x); pc.hh[1] = __float2bfloat16(xv.y);
        pc.hh[2] = __float2bfloat16(xv.z); pc.hh[3] = __float2bfloat16(xv.w);
        *(uint2*)(s_capq + w * CAPQ_STR + c4 * 4) = pc.u;
      }
    }
    __syncthreads();
    // P7 partial: sims += cap_quarter . sel_quarter^T
    #pragma unroll
    for (int ks = 0; ks < 4; ++ks) {
      v8s a  = *(const v8s*)(s_capq + (mt * 16 + l15) * CAPQ_STR + ks * 32 + koff);
      v8s bb = *(const v8s*)(s_sel + (nt * 16 + l15) * SELQ_STR + ks * 32 + koff);
      sa = MFMA16(a, bb, sa);
    }
    // P9 partial: G += sel_quarter . sel_quarter^T
    #pragma unroll
    for (int i2 = 0; i2 < 2; ++i2) {
      int idx = wv * 2 + i2;
      int gm = idx >> 2, gn = idx & 3;
      #pragma unroll
      for (int ks = 0; ks < 4; ++ks) {
        v8s a  = *(const v8s*)(s_sel + (gm * 16 + l15) * SELQ_STR + ks * 32 + koff);
        v8s bb = *(const v8s*)(s_sel + (gn * 16 + l15) * SELQ_STR + ks * 32 + koff);
        ga[i2] = MFMA16(a, bb, ga[i2]);
      }
    }
    __syncthreads();
  }

  // ---- write sims + G (overwrites capq/wa region, both dead now) ----
  #pragma unroll
  for (int reg = 0; reg < 4; ++reg)
    s_sims[(mt * 16 + quad * 4 + reg) * 64 + nt * 16 + l15] = sa[reg];
  #pragma unroll
  for (int i2 = 0; i2 < 2; ++i2) {
    int idx = wv * 2 + i2;
    int gm = idx >> 2, gn = idx & 3;
    #pragma unroll
    for (int reg = 0; reg < 4; ++reg)
      s_G[(gm * 16 + quad * 4 + reg) * G_STR + gn * 16 + l15] = ga[i2][reg];
  }
  __syncthreads();

  // ---- P8: per-word softmax (unnormalized e) + num = sum e*s ----
  if (tid < NW * 8) {
    int w = tid >> 3, g = tid & 7;
    float* row = s_sims + w * 64;
    float mm = -3e38f;
    for (int p = g; p < 50; p += 8) mm = fmaxf(mm, row[p]);
    #pragma unroll
    for (int off = 4; off > 0; off >>= 1) mm = fmaxf(mm, __shfl_xor(mm, off, 8));
    float num = 0.f;
    for (int p = g; p < 64; p += 8) {
      if (p < 50) {
        float s = row[p];
        float ee = expf(LAMBDA_ * (s - mm));
        num += ee * s;
        row[p] = ee;
      } else row[p] = 0.f;
    }
    #pragma unroll
    for (int off = 4; off > 0; off >>= 1) num += __shfl_xor(num, off, 8);
    if (g == 0) s_red[w] = num;
  }
  __syncthreads();

  // ---- P10: word_sim = num / sqrt(e^T G e); mean over words ----
  float wacc = 0.f;
  for (int w = wv; w < NW; w += 8) {
    const float* ev = s_sims + w * 64;
    float tl = 0.f;
    for (int q = 0; q < 50; ++q) tl += s_G[q * G_STR + lane] * ev[q];
    float ql = ev[lane] * tl;
    #pragma unroll
    for (int off = 32; off > 0; off >>= 1) ql += __shfl_xor(ql, off, 64);
    if (lane == 0) wacc += s_red[w] / fmaxf(sqrtf(ql), 1e-20f);
  }
  if (lane == 0) s_red[64 + wv] = wacc;
  __syncthreads();
  if (tid == 0) {
    float s = 0.f;
    #pragma unroll
    for (int i = 0; i < 8; ++i) s += s_red[64 + i];
    out[(size_t)v * BT + t] = s / (float)NW;
  }
}

// ---------------------------------------------------------------------------
extern "C" void kernel_launch(void* const* d_in, const int* in_sizes, int n_in,
                              void* d_out, int out_size, void* d_ws, size_t ws_size,
                              hipStream_t stream) {
  const float* img   = (const float*)d_in[0];
  const float* cap   = (const float*)d_in[1];
  // d_in[2] = cap_lens (unused by forward)
  const float* gamma = (const float*)d_in[3];
  const float* beta  = (const float*)d_in[4];
  const float* W1    = (const float*)d_in[5];
  const float* b1    = (const float*)d_in[6];
  const float* W2    = (const float*)d_in[7];
  const float* b2    = (const float*)d_in[8];
  const float* scale = (const float*)d_in[9];
  float* ws  = (float*)d_ws;
  float* out = (float*)d_out;

  const bool big = (ws_size >= WS_NEED_B);   // constant across calls -> graph-safe

  if (big) {
    k0_prep<<<dim3(BV, 9), dim3(512), 0, stream>>>(img, cap, W1, W2, ws);
    k2_mlp <<<dim3(BV, 8), dim3(512), 0, stream>>>(img, gamma, beta, b1, b2, ws);
  } else {
    k5_prep<<<dim3(176), dim3(512), 0, stream>>>(W1, W2, ws);
    k1_glo <<<dim3(BT + BV), dim3(256), 0, stream>>>(img, cap, ws);
    k2_mlp <<<dim3(BV, 7), dim3(512), 0, stream>>>(img, gamma, beta, b1, b2, ws);
  }
  k3_score<<<dim3(BV, 4), dim3(1024), 0, stream>>>(img, ws);
  if (big) k4_big<<<dim3(BV * BT), dim3(512), 0, stream>>>(img, scale, ws, out);
  else     k4_main<0><<<dim3(BV * BT), dim3(512), 0, stream>>>(img, scale, ws, out);
}